// Round 2
// baseline (614.302 us; speedup 1.0000x reference)
//
#include <hip/hip_runtime.h>
#include <cmath>

#define U16 unsigned short

typedef __bf16 bf16x8_t __attribute__((ext_vector_type(8)));
typedef float f32x4_t __attribute__((ext_vector_type(4)));

union Frag { uint4 u4; bf16x8_t b8; U16 s[8]; };

__device__ __forceinline__ float b2f(U16 u) {
  union { unsigned int i; float f; } x; x.i = ((unsigned int)u) << 16; return x.f;
}
__device__ __forceinline__ U16 f2b(float f) {
  union { float f; unsigned int i; } x; x.f = f;
  unsigned int r = x.i + 0x7FFFu + ((x.i >> 16) & 1u);
  return (U16)(r >> 16);
}

// ---------------- weight transpose + fp32->bf16: in[R,C] fp32 -> out[C,R] bf16 ----------------
__global__ __launch_bounds__(256) void transpose_f2b(const float* __restrict__ in,
                                                     U16* __restrict__ out, int R, int C) {
  __shared__ float tile[32][33];
  int c0 = blockIdx.x * 32, r0 = blockIdx.y * 32;
  int tx = threadIdx.x & 31, ty = threadIdx.x >> 5;
#pragma unroll
  for (int yy = 0; yy < 4; ++yy)
    tile[ty + yy * 8][tx] = in[(size_t)(r0 + ty + yy * 8) * C + c0 + tx];
  __syncthreads();
#pragma unroll
  for (int yy = 0; yy < 4; ++yy)
    out[(size_t)(c0 + ty + yy * 8) * R + r0 + tx] = f2b(tile[tx][ty + yy * 8]);
}

// rb_w2 fp32 [768,12] -> padded bf16 transpose [16,768] (rows 12..15 zero)
__global__ __launch_bounds__(256) void w2pad_kernel(const float* __restrict__ w2,
                                                    U16* __restrict__ w2T) {
  int idx = blockIdx.x * 256 + threadIdx.x;
  if (idx < 16 * 768) {
    int n = idx / 768, k = idx % 768;
    w2T[idx] = (n < 12) ? f2b(w2[k * 12 + n]) : (U16)0;
  }
}

// ---------------- layernorm over D=768 (fp32 in, bf16 out), one block per row ----------------
__global__ __launch_bounds__(256) void ln_kernel(const float* __restrict__ X,
                                                 const float* __restrict__ gam,
                                                 const float* __restrict__ bet,
                                                 U16* __restrict__ Y) {
  int row = blockIdx.x, tid = threadIdx.x;
  __shared__ float r1[256], r2[256];
  float v[3];
#pragma unroll
  for (int j = 0; j < 3; ++j) v[j] = X[(size_t)row * 768 + tid + j * 256];
  r1[tid] = v[0] + v[1] + v[2];
  r2[tid] = v[0] * v[0] + v[1] * v[1] + v[2] * v[2];
  __syncthreads();
  for (int s = 128; s > 0; s >>= 1) {
    if (tid < s) { r1[tid] += r1[tid + s]; r2[tid] += r2[tid + s]; }
    __syncthreads();
  }
  float mean = r1[0] * (1.f / 768.f);
  float var = r2[0] * (1.f / 768.f) - mean * mean;
  float rstd = rsqrtf(var + 1e-5f);
#pragma unroll
  for (int j = 0; j < 3; ++j) {
    int c = tid + j * 256;
    Y[(size_t)row * 768 + c] = f2b((v[j] - mean) * rstd * gam[c] + bet[c]);
  }
}

// ---------------- generic bf16-MFMA GEMM: C = epi(A[M,K] @ B + bias) ----------------
// A, BT bf16; bias fp32; other fp32. BT is B transposed [N,K]. 128x128 tile, BK=32.
// EPI: 0=none 1=silu 2=gelu(exact) 3=sigmoid(z)*other 4=z+other
#define LDP 40
template <int EPI, bool OUTF32>
__global__ __launch_bounds__(256) void gemm_bt(const U16* __restrict__ A,
                                               const U16* __restrict__ BT,
                                               const float* __restrict__ bias,
                                               const float* __restrict__ other,
                                               void* __restrict__ Cout,
                                               int M, int N, int K) {
  __shared__ __align__(16) U16 sA[128 * LDP];
  __shared__ __align__(16) U16 sB[128 * LDP];
  int tid = threadIdx.x;
  int lane = tid & 63, wave = tid >> 6;
  int m0 = blockIdx.y * 128, n0 = blockIdx.x * 128;
  int wm = (wave >> 1) * 64, wn = (wave & 1) * 64;
  int lm = lane & 15, lq = lane >> 4;
  int srow = tid >> 1;
  int scol = (tid & 1) * 16;
  f32x4_t acc[4][4] = {};
  for (int k0 = 0; k0 < K; k0 += 32) {
    __syncthreads();
    const U16* ag = A + (size_t)(m0 + srow) * K + k0 + scol;
    const U16* bg = BT + (size_t)(n0 + srow) * K + k0 + scol;
    uint4 a0 = *(const uint4*)ag;
    uint4 a1 = *(const uint4*)(ag + 8);
    uint4 b0 = *(const uint4*)bg;
    uint4 b1 = *(const uint4*)(bg + 8);
    *(uint4*)&sA[srow * LDP + scol] = a0;
    *(uint4*)&sA[srow * LDP + scol + 8] = a1;
    *(uint4*)&sB[srow * LDP + scol] = b0;
    *(uint4*)&sB[srow * LDP + scol + 8] = b1;
    __syncthreads();
    Frag af[4], bf[4];
#pragma unroll
    for (int mt = 0; mt < 4; ++mt)
      af[mt].u4 = *(const uint4*)&sA[(wm + mt * 16 + lm) * LDP + lq * 8];
#pragma unroll
    for (int nt = 0; nt < 4; ++nt)
      bf[nt].u4 = *(const uint4*)&sB[(wn + nt * 16 + lm) * LDP + lq * 8];
#pragma unroll
    for (int mt = 0; mt < 4; ++mt)
#pragma unroll
      for (int nt = 0; nt < 4; ++nt)
        acc[mt][nt] = __builtin_amdgcn_mfma_f32_16x16x32_bf16(af[mt].b8, bf[nt].b8,
                                                              acc[mt][nt], 0, 0, 0);
  }
#pragma unroll
  for (int nt = 0; nt < 4; ++nt) {
    int gc = n0 + wn + nt * 16 + lm;
    float bz = bias[gc];
#pragma unroll
    for (int mt = 0; mt < 4; ++mt) {
#pragma unroll
      for (int r = 0; r < 4; ++r) {
        int gr = m0 + wm + mt * 16 + lq * 4 + r;
        size_t idx = (size_t)gr * N + gc;
        float z = acc[mt][nt][r] + bz;
        float o;
        if (EPI == 0) o = z;
        else if (EPI == 1) o = z / (1.f + expf(-z));
        else if (EPI == 2) o = 0.5f * z * (1.f + erff(z * 0.70710678118f));
        else if (EPI == 3) o = other[idx] / (1.f + expf(-z));
        else o = z + other[idx];
        if (OUTF32) ((float*)Cout)[idx] = o;
        else ((U16*)Cout)[idx] = f2b(o);
      }
    }
  }
}

// ---------------- fused relative-bias MLP ----------------
// bias[b,h,i,j] = silu(dist[(b,i,j),:64] @ w1 + b1) @ w2 + b2; dist fp32, weights bf16.
__global__ __launch_bounds__(256) void rb_kernel(const float* __restrict__ dist,  // [262144,64]
                                                 const U16* __restrict__ w1T,     // [768,64] bf16
                                                 const float* __restrict__ b1,    // [768]
                                                 const U16* __restrict__ w2T,     // [16,768] bf16 padded
                                                 const float* __restrict__ b2,    // [12]
                                                 float* __restrict__ biasOut) {   // [4,12,256,256]
  int tid = threadIdx.x;
  int lane = tid & 63, wave = tid >> 6;
  int lm = lane & 15, lq = lane >> 4;
  int r0 = blockIdx.x * 64;
  __shared__ __align__(16) U16 sW1[32 * 64];
  __shared__ __align__(16) U16 sW2[16 * 32];
  __shared__ __align__(16) U16 st[4][16 * 32];
  Frag af0, af1;
  const float* ap = dist + (size_t)(r0 + wave * 16 + lm) * 64 + lq * 8;
#pragma unroll
  for (int j = 0; j < 8; ++j) { af0.s[j] = f2b(ap[j]); af1.s[j] = f2b(ap[j + 32]); }
  f32x4_t bacc = {0.f, 0.f, 0.f, 0.f};
  for (int pp = 0; pp < 24; ++pp) {
    __syncthreads();
    {
      int nl = tid >> 3, ch = tid & 7;
      *(uint4*)&sW1[nl * 64 + ch * 8] =
          *(const uint4*)&w1T[(size_t)(pp * 32 + nl) * 64 + ch * 8];
      if (tid < 64) {
        int n = tid >> 2, c2 = tid & 3;
        *(uint4*)&sW2[n * 32 + c2 * 8] =
            *(const uint4*)&w2T[(size_t)n * 768 + pp * 32 + c2 * 8];
      }
    }
    __syncthreads();
#pragma unroll
    for (int tt = 0; tt < 2; ++tt) {
      int nt = pp * 2 + tt;
      Frag bf0, bf1;
      bf0.u4 = *(const uint4*)&sW1[(tt * 16 + lm) * 64 + lq * 8];
      bf1.u4 = *(const uint4*)&sW1[(tt * 16 + lm) * 64 + 32 + lq * 8];
      f32x4_t z4 = {0.f, 0.f, 0.f, 0.f};
      z4 = __builtin_amdgcn_mfma_f32_16x16x32_bf16(af0.b8, bf0.b8, z4, 0, 0, 0);
      z4 = __builtin_amdgcn_mfma_f32_16x16x32_bf16(af1.b8, bf1.b8, z4, 0, 0, 0);
      float bb = b1[nt * 16 + lm];
#pragma unroll
      for (int r = 0; r < 4; ++r) {
        float z = z4[r] + bb;
        st[wave][(lq * 4 + r) * 32 + tt * 16 + lm] = f2b(z / (1.f + expf(-z)));
      }
    }
    __syncthreads();
    Frag a2, b2f_;
    a2.u4 = *(const uint4*)&st[wave][lm * 32 + lq * 8];
    b2f_.u4 = *(const uint4*)&sW2[lm * 32 + lq * 8];
    bacc = __builtin_amdgcn_mfma_f32_16x16x32_bf16(a2.b8, b2f_.b8, bacc, 0, 0, 0);
  }
  int h = lm;
  if (h < 12) {
    float hb = b2[h];
#pragma unroll
    for (int r = 0; r < 4; ++r) {
      int gr = r0 + wave * 16 + lq * 4 + r;  // flat (b,i,j)
      int b = gr >> 16, rem = gr & 65535, i = rem >> 8, j = rem & 255;
      biasOut[(((size_t)b * 12 + h) * 256 + i) * 256 + j] = bacc[r] + hb;
    }
  }
}

// ---------------- attention: one block per (b,h,i) query row (fp32 throughout) ----------------
__global__ __launch_bounds__(256) void attn_kernel(const float* __restrict__ qkv,   // [1024,2304]
                                                   const float* __restrict__ biasB, // [4,12,256,256]
                                                   const int* __restrict__ mask,    // [4,256,256]
                                                   float* __restrict__ ctx) {       // [1024,768]
  int i = blockIdx.x, h = blockIdx.y, b = blockIdx.z;
  int tid = threadIdx.x;
  __shared__ float qs[64];
  __shared__ float red[256];
  __shared__ float p[256];
  __shared__ float csum[256];
  if (tid < 64) qs[tid] = qkv[((size_t)(b * 256 + i)) * 2304 + h * 64 + tid];
  __syncthreads();
  const float* kp = qkv + ((size_t)(b * 256 + tid)) * 2304 + 768 + h * 64;
  float acc = 0.f;
#pragma unroll
  for (int c = 0; c < 16; ++c) {
    float4 kv = ((const float4*)kp)[c];
    acc += qs[c * 4 + 0] * kv.x + qs[c * 4 + 1] * kv.y + qs[c * 4 + 2] * kv.z +
           qs[c * 4 + 3] * kv.w;
  }
  float logit = acc * 0.125f + biasB[(((size_t)b * 12 + h) * 256 + i) * 256 + tid];
  if (!mask[((size_t)b * 256 + i) * 256 + tid]) logit = -1e30f;
  red[tid] = logit;
  __syncthreads();
  for (int s = 128; s > 0; s >>= 1) {
    if (tid < s) red[tid] = fmaxf(red[tid], red[tid + s]);
    __syncthreads();
  }
  float mx = red[0];
  __syncthreads();
  float e = expf(logit - mx);
  red[tid] = e;
  __syncthreads();
  for (int s = 128; s > 0; s >>= 1) {
    if (tid < s) red[tid] += red[tid + s];
    __syncthreads();
  }
  float inv = 1.f / red[0];
  p[tid] = e * inv;
  __syncthreads();
  int d = tid & 63, chunk = tid >> 6;
  const float* vp = qkv + ((size_t)(b * 256 + chunk * 64)) * 2304 + 1536 + h * 64 + d;
  float ca = 0.f;
#pragma unroll 8
  for (int jj = 0; jj < 64; ++jj) ca += p[chunk * 64 + jj] * vp[(size_t)jj * 2304];
  csum[tid] = ca;
  __syncthreads();
  if (tid < 64) {
    float o = csum[tid] + csum[64 + tid] + csum[128 + tid] + csum[192 + tid];
    ctx[((size_t)(b * 256 + i)) * 768 + h * 64 + tid] = o;
  }
}

// ---------------- launcher ----------------
extern "C" void kernel_launch(void* const* d_in, const int* in_sizes, int n_in,
                              void* d_out, int out_size, void* d_ws, size_t ws_size,
                              hipStream_t stream) {
  const float* x       = (const float*)d_in[0];
  const float* dist    = (const float*)d_in[1];
  const int* mask      = (const int*)d_in[2];
  const float* qkv_w   = (const float*)d_in[3];
  const float* qkv_b   = (const float*)d_in[4];
  const float* out_w   = (const float*)d_in[5];
  const float* out_b   = (const float*)d_in[6];
  const float* rb_w1   = (const float*)d_in[7];
  const float* rb_b1   = (const float*)d_in[8];
  const float* rb_w2   = (const float*)d_in[9];
  const float* rb_b2   = (const float*)d_in[10];
  const float* gate_w1 = (const float*)d_in[11];
  const float* gate_b1 = (const float*)d_in[12];
  const float* gate_w2 = (const float*)d_in[13];
  const float* gate_b2 = (const float*)d_in[14];
  const float* ff_w1   = (const float*)d_in[15];
  const float* ff_b1   = (const float*)d_in[16];
  const float* ff_w2   = (const float*)d_in[17];
  const float* ff_b2   = (const float*)d_in[18];
  const float* ln1_g   = (const float*)d_in[19];
  const float* ln1_b   = (const float*)d_in[20];
  const float* ln2_g   = (const float*)d_in[21];
  const float* ln2_b   = (const float*)d_in[22];

  char* w = (char*)d_ws;
  auto alloc = [&](size_t bytes) {
    char* p = w;
    w += (bytes + 255) & ~(size_t)255;
    return p;
  };
  U16* xn      = (U16*)alloc(1024 * 768 * 2);
  float* qkvb  = (float*)alloc((size_t)1024 * 2304 * 4);
  U16* qkv_wT  = (U16*)alloc(2304 * 768 * 2);
  U16* out_wT  = (U16*)alloc(768 * 768 * 2);
  U16* g1wT    = (U16*)alloc(768 * 768 * 2);
  U16* g2wT    = (U16*)alloc(768 * 768 * 2);
  U16* ff1wT   = (U16*)alloc(1536 * 768 * 2);
  U16* ff2wT   = (U16*)alloc(768 * 1536 * 2);
  U16* rb1wT   = (U16*)alloc(768 * 64 * 2);
  U16* rb2wT   = (U16*)alloc(16 * 768 * 2);
  float* biasB = (float*)alloc((size_t)4 * 12 * 256 * 256 * 4);
  float* ctx   = (float*)alloc(1024 * 768 * 4);
  U16* g1      = (U16*)alloc(1024 * 768 * 2);
  U16* cg      = (U16*)alloc(1024 * 768 * 2);
  float* x2    = (float*)alloc(1024 * 768 * 4);
  U16* y       = (U16*)alloc(1024 * 768 * 2);
  U16* f1      = (U16*)alloc(1024 * 1536 * 2);
  (void)ws_size; (void)in_sizes; (void)n_in; (void)out_size;

  // weight transposes (fp32 -> bf16)
  transpose_f2b<<<dim3(2304 / 32, 768 / 32), 256, 0, stream>>>(qkv_w, qkv_wT, 768, 2304);
  transpose_f2b<<<dim3(768 / 32, 768 / 32), 256, 0, stream>>>(out_w, out_wT, 768, 768);
  transpose_f2b<<<dim3(768 / 32, 768 / 32), 256, 0, stream>>>(gate_w1, g1wT, 768, 768);
  transpose_f2b<<<dim3(768 / 32, 768 / 32), 256, 0, stream>>>(gate_w2, g2wT, 768, 768);
  transpose_f2b<<<dim3(1536 / 32, 768 / 32), 256, 0, stream>>>(ff_w1, ff1wT, 768, 1536);
  transpose_f2b<<<dim3(768 / 32, 1536 / 32), 256, 0, stream>>>(ff_w2, ff2wT, 1536, 768);
  transpose_f2b<<<dim3(768 / 32, 64 / 32), 256, 0, stream>>>(rb_w1, rb1wT, 64, 768);
  w2pad_kernel<<<48, 256, 0, stream>>>(rb_w2, rb2wT);

  // LN1 -> xn (bf16)
  ln_kernel<<<1024, 256, 0, stream>>>(x, ln1_g, ln1_b, xn);
  // qkv projection -> fp32
  gemm_bt<0, true><<<dim3(18, 8), 256, 0, stream>>>(xn, qkv_wT, qkv_b, nullptr, qkvb,
                                                    1024, 2304, 768);
  // relative bias MLP (fused)
  rb_kernel<<<4096, 256, 0, stream>>>(dist, rb1wT, rb_b1, rb2wT, rb_b2, biasB);
  // attention -> ctx fp32
  attn_kernel<<<dim3(256, 12, 4), 256, 0, stream>>>(qkvb, biasB, mask, ctx);
  // gate MLP
  gemm_bt<1, false><<<dim3(6, 8), 256, 0, stream>>>(xn, g1wT, gate_b1, nullptr, g1,
                                                    1024, 768, 768);
  gemm_bt<3, false><<<dim3(6, 8), 256, 0, stream>>>(g1, g2wT, gate_b2, ctx, cg,
                                                    1024, 768, 768);
  // out projection + residual -> x2 (fp32)
  gemm_bt<4, true><<<dim3(6, 8), 256, 0, stream>>>(cg, out_wT, out_b, x, x2,
                                                   1024, 768, 768);
  // LN2 -> y (bf16)
  ln_kernel<<<1024, 256, 0, stream>>>(x2, ln2_g, ln2_b, y);
  // FF
  gemm_bt<2, false><<<dim3(12, 8), 256, 0, stream>>>(y, ff1wT, ff_b1, nullptr, f1,
                                                     1024, 1536, 768);
  gemm_bt<4, true><<<dim3(6, 8), 256, 0, stream>>>(f1, ff2wT, ff_b2, x2, (float*)d_out,
                                                   1024, 768, 1536);
}

// Round 3
// 510.876 us; speedup vs baseline: 1.2024x; 1.2024x over previous
//
#include <hip/hip_runtime.h>
#include <cmath>

#define U16 unsigned short

typedef __bf16 bf16x8_t __attribute__((ext_vector_type(8)));
typedef float f32x4_t __attribute__((ext_vector_type(4)));

union Frag { uint4 u4; bf16x8_t b8; U16 s[8]; };

__device__ __forceinline__ float b2f(U16 u) {
  union { unsigned int i; float f; } x; x.i = ((unsigned int)u) << 16; return x.f;
}
__device__ __forceinline__ U16 f2b(float f) {
  union { float f; unsigned int i; } x; x.f = f;
  unsigned int r = x.i + 0x7FFFu + ((x.i >> 16) & 1u);
  return (U16)(r >> 16);
}

// ---------------- weight transpose + fp32->bf16: in[R,C] fp32 -> out[C,R] bf16 ----------------
__global__ __launch_bounds__(256) void transpose_f2b(const float* __restrict__ in,
                                                     U16* __restrict__ out, int R, int C) {
  __shared__ float tile[32][33];
  int c0 = blockIdx.x * 32, r0 = blockIdx.y * 32;
  int tx = threadIdx.x & 31, ty = threadIdx.x >> 5;
#pragma unroll
  for (int yy = 0; yy < 4; ++yy)
    tile[ty + yy * 8][tx] = in[(size_t)(r0 + ty + yy * 8) * C + c0 + tx];
  __syncthreads();
#pragma unroll
  for (int yy = 0; yy < 4; ++yy)
    out[(size_t)(c0 + ty + yy * 8) * R + r0 + tx] = f2b(tile[tx][ty + yy * 8]);
}

// rb_w2 fp32 [768,12] -> padded bf16 transpose [16,768] (rows 12..15 zero)
__global__ __launch_bounds__(256) void w2pad_kernel(const float* __restrict__ w2,
                                                    U16* __restrict__ w2T) {
  int idx = blockIdx.x * 256 + threadIdx.x;
  if (idx < 16 * 768) {
    int n = idx / 768, k = idx % 768;
    w2T[idx] = (n < 12) ? f2b(w2[k * 12 + n]) : (U16)0;
  }
}

// ---------------- layernorm over D=768 (fp32 in, bf16 out), one block per row ----------------
__global__ __launch_bounds__(256) void ln_kernel(const float* __restrict__ X,
                                                 const float* __restrict__ gam,
                                                 const float* __restrict__ bet,
                                                 U16* __restrict__ Y) {
  int row = blockIdx.x, tid = threadIdx.x;
  __shared__ float r1[256], r2[256];
  float v[3];
#pragma unroll
  for (int j = 0; j < 3; ++j) v[j] = X[(size_t)row * 768 + tid + j * 256];
  r1[tid] = v[0] + v[1] + v[2];
  r2[tid] = v[0] * v[0] + v[1] * v[1] + v[2] * v[2];
  __syncthreads();
  for (int s = 128; s > 0; s >>= 1) {
    if (tid < s) { r1[tid] += r1[tid + s]; r2[tid] += r2[tid + s]; }
    __syncthreads();
  }
  float mean = r1[0] * (1.f / 768.f);
  float var = r2[0] * (1.f / 768.f) - mean * mean;
  float rstd = rsqrtf(var + 1e-5f);
#pragma unroll
  for (int j = 0; j < 3; ++j) {
    int c = tid + j * 256;
    Y[(size_t)row * 768 + c] = f2b((v[j] - mean) * rstd * gam[c] + bet[c]);
  }
}

// ---------------- generic bf16-MFMA GEMM: C = epi(A[M,K] @ B + bias) ----------------
// 64x64 tile per block (better occupancy at these small M/N), BK=32, 4 waves (2x2 of 32x32).
// EPI: 0=none 1=silu 2=gelu(exact) 3=sigmoid(z)*other 4=z+other
#define LDP 40
template <int EPI, bool OUTF32>
__global__ __launch_bounds__(256) void gemm_bt(const U16* __restrict__ A,
                                               const U16* __restrict__ BT,
                                               const float* __restrict__ bias,
                                               const float* __restrict__ other,
                                               void* __restrict__ Cout,
                                               int M, int N, int K) {
  __shared__ __align__(16) U16 sA[64 * LDP];
  __shared__ __align__(16) U16 sB[64 * LDP];
  int tid = threadIdx.x;
  int lane = tid & 63, wave = tid >> 6;
  int m0 = blockIdx.y * 64, n0 = blockIdx.x * 64;
  int wm = (wave >> 1) * 32, wn = (wave & 1) * 32;
  int lm = lane & 15, lq = lane >> 4;
  int srow = tid >> 2;
  int scol = (tid & 3) * 8;
  f32x4_t acc[2][2] = {};
  for (int k0 = 0; k0 < K; k0 += 32) {
    __syncthreads();
    uint4 a0 = *(const uint4*)(A + (size_t)(m0 + srow) * K + k0 + scol);
    uint4 b0 = *(const uint4*)(BT + (size_t)(n0 + srow) * K + k0 + scol);
    *(uint4*)&sA[srow * LDP + scol] = a0;
    *(uint4*)&sB[srow * LDP + scol] = b0;
    __syncthreads();
    Frag af[2], bf[2];
#pragma unroll
    for (int mt = 0; mt < 2; ++mt)
      af[mt].u4 = *(const uint4*)&sA[(wm + mt * 16 + lm) * LDP + lq * 8];
#pragma unroll
    for (int nt = 0; nt < 2; ++nt)
      bf[nt].u4 = *(const uint4*)&sB[(wn + nt * 16 + lm) * LDP + lq * 8];
#pragma unroll
    for (int mt = 0; mt < 2; ++mt)
#pragma unroll
      for (int nt = 0; nt < 2; ++nt)
        acc[mt][nt] = __builtin_amdgcn_mfma_f32_16x16x32_bf16(af[mt].b8, bf[nt].b8,
                                                              acc[mt][nt], 0, 0, 0);
  }
#pragma unroll
  for (int nt = 0; nt < 2; ++nt) {
    int gc = n0 + wn + nt * 16 + lm;
    float bz = bias[gc];
#pragma unroll
    for (int mt = 0; mt < 2; ++mt) {
#pragma unroll
      for (int r = 0; r < 4; ++r) {
        int gr = m0 + wm + mt * 16 + lq * 4 + r;
        size_t idx = (size_t)gr * N + gc;
        float z = acc[mt][nt][r] + bz;
        float o;
        if (EPI == 0) o = z;
        else if (EPI == 1) o = z / (1.f + __expf(-z));
        else if (EPI == 2) o = 0.5f * z * (1.f + erff(z * 0.70710678118f));
        else if (EPI == 3) o = other[idx] / (1.f + __expf(-z));
        else o = z + other[idx];
        if (OUTF32) ((float*)Cout)[idx] = o;
        else ((U16*)Cout)[idx] = f2b(o);
      }
    }
  }
}

// ---------------- fused relative-bias MLP (transposed first layer; silu stays in-register) ---
// bias[b,h,i,j] = silu(dist[(b,i,j),:64] @ w1 + b1) @ w2 + b2
// First MFMA computes z^T (A=w1 permuted rows, B=dist rows) so the silu result lands
// directly in the A-fragment layout of the second MFMA: lane holds dist-row = lane&15,
// frag elem j=4*tt+r <-> hidden k-pos 8*lq+j. w1 rows staged permuted:
//   LDS row s (=tt*16+m) holds hidden h = pp*32 + 8*(m/4) + 4*tt + (m%4).
// 128 dist rows per block: each wave owns 2 groups of 16 rows.
__global__ __launch_bounds__(256) void rb_kernel(const float* __restrict__ dist,  // [262144,64]
                                                 const U16* __restrict__ w1T,     // [768,64] bf16
                                                 const float* __restrict__ b1,    // [768]
                                                 const U16* __restrict__ w2T,     // [16,768] bf16 padded
                                                 const float* __restrict__ b2,    // [12]
                                                 float* __restrict__ biasOut) {   // [4,12,256,256]
  int tid = threadIdx.x;
  int lane = tid & 63, wave = tid >> 6;
  int lm = lane & 15, lq = lane >> 4;
  int r0 = blockIdx.x * 128;
  __shared__ __align__(16) U16 sW1[32 * 72];   // stride 72: 2-way bank alias only
  __shared__ __align__(16) U16 sW2[16 * 40];
  __shared__ float sB1[32];
  // dist B-fragments: 2 row-groups x 2 k-chunks, loaded once (reused all 24 pp iters)
  Frag bd[2][2];
#pragma unroll
  for (int g = 0; g < 2; ++g) {
    const float* ap = dist + (size_t)(r0 + (wave * 2 + g) * 16 + lm) * 64 + lq * 8;
    float4 v0 = ((const float4*)ap)[0];
    float4 v1 = ((const float4*)ap)[1];
    float4 v2 = ((const float4*)(ap + 32))[0];
    float4 v3 = ((const float4*)(ap + 32))[1];
    bd[g][0].s[0] = f2b(v0.x); bd[g][0].s[1] = f2b(v0.y);
    bd[g][0].s[2] = f2b(v0.z); bd[g][0].s[3] = f2b(v0.w);
    bd[g][0].s[4] = f2b(v1.x); bd[g][0].s[5] = f2b(v1.y);
    bd[g][0].s[6] = f2b(v1.z); bd[g][0].s[7] = f2b(v1.w);
    bd[g][1].s[0] = f2b(v2.x); bd[g][1].s[1] = f2b(v2.y);
    bd[g][1].s[2] = f2b(v2.z); bd[g][1].s[3] = f2b(v2.w);
    bd[g][1].s[4] = f2b(v3.x); bd[g][1].s[5] = f2b(v3.y);
    bd[g][1].s[6] = f2b(v3.z); bd[g][1].s[7] = f2b(v3.w);
  }
  f32x4_t bacc[2] = {};
  for (int pp = 0; pp < 24; ++pp) {
    __syncthreads();
    {  // stage w1 (permuted rows), w2 (plain), b1 (plain)
      int s = tid >> 3, ch = tid & 7;
      int m = s & 15, tt = s >> 4;
      int hact = pp * 32 + ((m >> 2) << 3) + (tt << 2) + (m & 3);
      *(uint4*)&sW1[s * 72 + ch * 8] = *(const uint4*)&w1T[(size_t)hact * 64 + ch * 8];
      if (tid < 64) {
        int n = tid >> 2, c2 = tid & 3;
        *(uint4*)&sW2[n * 40 + c2 * 8] = *(const uint4*)&w2T[(size_t)n * 768 + pp * 32 + c2 * 8];
      } else if (tid < 96) {
        sB1[tid - 64] = b1[pp * 32 + tid - 64];
      }
    }
    __syncthreads();
    Frag af2[2];
#pragma unroll
    for (int tt = 0; tt < 2; ++tt) {
      Frag w0, w1f;
      w0.u4 = *(const uint4*)&sW1[(tt * 16 + lm) * 72 + lq * 8];
      w1f.u4 = *(const uint4*)&sW1[(tt * 16 + lm) * 72 + 32 + lq * 8];
      float4 bb = *(const float4*)&sB1[lq * 8 + tt * 4];
      const float* bbp = (const float*)&bb;
#pragma unroll
      for (int g = 0; g < 2; ++g) {
        f32x4_t z4 = {0.f, 0.f, 0.f, 0.f};
        z4 = __builtin_amdgcn_mfma_f32_16x16x32_bf16(w0.b8, bd[g][0].b8, z4, 0, 0, 0);
        z4 = __builtin_amdgcn_mfma_f32_16x16x32_bf16(w1f.b8, bd[g][1].b8, z4, 0, 0, 0);
#pragma unroll
        for (int r = 0; r < 4; ++r) {
          float z = z4[r] + bbp[r];
          af2[g].s[tt * 4 + r] = f2b(z / (1.f + __expf(-z)));
        }
      }
    }
    Frag wb;
    wb.u4 = *(const uint4*)&sW2[lm * 40 + lq * 8];
    bacc[0] = __builtin_amdgcn_mfma_f32_16x16x32_bf16(af2[0].b8, wb.b8, bacc[0], 0, 0, 0);
    bacc[1] = __builtin_amdgcn_mfma_f32_16x16x32_bf16(af2[1].b8, wb.b8, bacc[1], 0, 0, 0);
  }
  int h = lm;
  if (h < 12) {
    float hb = b2[h];
#pragma unroll
    for (int g = 0; g < 2; ++g) {
#pragma unroll
      for (int r = 0; r < 4; ++r) {
        int gr = r0 + (wave * 2 + g) * 16 + lq * 4 + r;  // flat (b,i,j)
        int b = gr >> 16, rem = gr & 65535, i = rem >> 8, j = rem & 255;
        biasOut[(((size_t)b * 12 + h) * 256 + i) * 256 + j] = bacc[g][r] + hb;
      }
    }
  }
}

// ---------------- attention: one block per (b,h,i) query row (fp32 throughout) ----------------
__global__ __launch_bounds__(256) void attn_kernel(const float* __restrict__ qkv,   // [1024,2304]
                                                   const float* __restrict__ biasB, // [4,12,256,256]
                                                   const int* __restrict__ mask,    // [4,256,256]
                                                   float* __restrict__ ctx) {       // [1024,768]
  int i = blockIdx.x, h = blockIdx.y, b = blockIdx.z;
  int tid = threadIdx.x;
  __shared__ float qs[64];
  __shared__ float red[256];
  __shared__ float p[256];
  __shared__ float csum[256];
  if (tid < 64) qs[tid] = qkv[((size_t)(b * 256 + i)) * 2304 + h * 64 + tid];
  __syncthreads();
  const float* kp = qkv + ((size_t)(b * 256 + tid)) * 2304 + 768 + h * 64;
  float acc = 0.f;
#pragma unroll
  for (int c = 0; c < 16; ++c) {
    float4 kv = ((const float4*)kp)[c];
    acc += qs[c * 4 + 0] * kv.x + qs[c * 4 + 1] * kv.y + qs[c * 4 + 2] * kv.z +
           qs[c * 4 + 3] * kv.w;
  }
  float logit = acc * 0.125f + biasB[(((size_t)b * 12 + h) * 256 + i) * 256 + tid];
  if (!mask[((size_t)b * 256 + i) * 256 + tid]) logit = -1e30f;
  red[tid] = logit;
  __syncthreads();
  for (int s = 128; s > 0; s >>= 1) {
    if (tid < s) red[tid] = fmaxf(red[tid], red[tid + s]);
    __syncthreads();
  }
  float mx = red[0];
  __syncthreads();
  float e = __expf(logit - mx);
  red[tid] = e;
  __syncthreads();
  for (int s = 128; s > 0; s >>= 1) {
    if (tid < s) red[tid] += red[tid + s];
    __syncthreads();
  }
  float inv = 1.f / red[0];
  p[tid] = e * inv;
  __syncthreads();
  int d = tid & 63, chunk = tid >> 6;
  const float* vp = qkv + ((size_t)(b * 256 + chunk * 64)) * 2304 + 1536 + h * 64 + d;
  float ca = 0.f;
#pragma unroll 8
  for (int jj = 0; jj < 64; ++jj) ca += p[chunk * 64 + jj] * vp[(size_t)jj * 2304];
  csum[tid] = ca;
  __syncthreads();
  if (tid < 64) {
    float o = csum[tid] + csum[64 + tid] + csum[128 + tid] + csum[192 + tid];
    ctx[((size_t)(b * 256 + i)) * 768 + h * 64 + tid] = o;
  }
}

// ---------------- launcher ----------------
extern "C" void kernel_launch(void* const* d_in, const int* in_sizes, int n_in,
                              void* d_out, int out_size, void* d_ws, size_t ws_size,
                              hipStream_t stream) {
  const float* x       = (const float*)d_in[0];
  const float* dist    = (const float*)d_in[1];
  const int* mask      = (const int*)d_in[2];
  const float* qkv_w   = (const float*)d_in[3];
  const float* qkv_b   = (const float*)d_in[4];
  const float* out_w   = (const float*)d_in[5];
  const float* out_b   = (const float*)d_in[6];
  const float* rb_w1   = (const float*)d_in[7];
  const float* rb_b1   = (const float*)d_in[8];
  const float* rb_w2   = (const float*)d_in[9];
  const float* rb_b2   = (const float*)d_in[10];
  const float* gate_w1 = (const float*)d_in[11];
  const float* gate_b1 = (const float*)d_in[12];
  const float* gate_w2 = (const float*)d_in[13];
  const float* gate_b2 = (const float*)d_in[14];
  const float* ff_w1   = (const float*)d_in[15];
  const float* ff_b1   = (const float*)d_in[16];
  const float* ff_w2   = (const float*)d_in[17];
  const float* ff_b2   = (const float*)d_in[18];
  const float* ln1_g   = (const float*)d_in[19];
  const float* ln1_b   = (const float*)d_in[20];
  const float* ln2_g   = (const float*)d_in[21];
  const float* ln2_b   = (const float*)d_in[22];

  char* w = (char*)d_ws;
  auto alloc = [&](size_t bytes) {
    char* p = w;
    w += (bytes + 255) & ~(size_t)255;
    return p;
  };
  U16* xn      = (U16*)alloc(1024 * 768 * 2);
  float* qkvb  = (float*)alloc((size_t)1024 * 2304 * 4);
  U16* qkv_wT  = (U16*)alloc(2304 * 768 * 2);
  U16* out_wT  = (U16*)alloc(768 * 768 * 2);
  U16* g1wT    = (U16*)alloc(768 * 768 * 2);
  U16* g2wT    = (U16*)alloc(768 * 768 * 2);
  U16* ff1wT   = (U16*)alloc(1536 * 768 * 2);
  U16* ff2wT   = (U16*)alloc(768 * 1536 * 2);
  U16* rb1wT   = (U16*)alloc(768 * 64 * 2);
  U16* rb2wT   = (U16*)alloc(16 * 768 * 2);
  float* biasB = (float*)alloc((size_t)4 * 12 * 256 * 256 * 4);
  float* ctx   = (float*)alloc(1024 * 768 * 4);
  U16* g1      = (U16*)alloc(1024 * 768 * 2);
  U16* cg      = (U16*)alloc(1024 * 768 * 2);
  float* x2    = (float*)alloc(1024 * 768 * 4);
  U16* y       = (U16*)alloc(1024 * 768 * 2);
  U16* f1      = (U16*)alloc(1024 * 1536 * 2);
  (void)ws_size; (void)in_sizes; (void)n_in; (void)out_size;

  // weight transposes (fp32 -> bf16)
  transpose_f2b<<<dim3(2304 / 32, 768 / 32), 256, 0, stream>>>(qkv_w, qkv_wT, 768, 2304);
  transpose_f2b<<<dim3(768 / 32, 768 / 32), 256, 0, stream>>>(out_w, out_wT, 768, 768);
  transpose_f2b<<<dim3(768 / 32, 768 / 32), 256, 0, stream>>>(gate_w1, g1wT, 768, 768);
  transpose_f2b<<<dim3(768 / 32, 768 / 32), 256, 0, stream>>>(gate_w2, g2wT, 768, 768);
  transpose_f2b<<<dim3(1536 / 32, 768 / 32), 256, 0, stream>>>(ff_w1, ff1wT, 768, 1536);
  transpose_f2b<<<dim3(768 / 32, 1536 / 32), 256, 0, stream>>>(ff_w2, ff2wT, 1536, 768);
  transpose_f2b<<<dim3(768 / 32, 64 / 32), 256, 0, stream>>>(rb_w1, rb1wT, 64, 768);
  w2pad_kernel<<<48, 256, 0, stream>>>(rb_w2, rb2wT);

  // LN1 -> xn (bf16)
  ln_kernel<<<1024, 256, 0, stream>>>(x, ln1_g, ln1_b, xn);
  // qkv projection -> fp32
  gemm_bt<0, true><<<dim3(36, 16), 256, 0, stream>>>(xn, qkv_wT, qkv_b, nullptr, qkvb,
                                                     1024, 2304, 768);
  // relative bias MLP (fused)
  rb_kernel<<<2048, 256, 0, stream>>>(dist, rb1wT, rb_b1, rb2wT, rb_b2, biasB);
  // attention -> ctx fp32
  attn_kernel<<<dim3(256, 12, 4), 256, 0, stream>>>(qkvb, biasB, mask, ctx);
  // gate MLP
  gemm_bt<1, false><<<dim3(12, 16), 256, 0, stream>>>(xn, g1wT, gate_b1, nullptr, g1,
                                                      1024, 768, 768);
  gemm_bt<3, false><<<dim3(12, 16), 256, 0, stream>>>(g1, g2wT, gate_b2, ctx, cg,
                                                      1024, 768, 768);
  // out projection + residual -> x2 (fp32)
  gemm_bt<4, true><<<dim3(12, 16), 256, 0, stream>>>(cg, out_wT, out_b, x, x2,
                                                     1024, 768, 768);
  // LN2 -> y (bf16)
  ln_kernel<<<1024, 256, 0, stream>>>(x2, ln2_g, ln2_b, y);
  // FF
  gemm_bt<2, false><<<dim3(24, 16), 256, 0, stream>>>(y, ff1wT, ff_b1, nullptr, f1,
                                                      1024, 1536, 768);
  gemm_bt<4, true><<<dim3(12, 16), 256, 0, stream>>>(f1, ff2wT, ff_b2, x2, (float*)d_out,
                                                     1024, 768, 1536);
}

// Round 4
// 427.746 us; speedup vs baseline: 1.4361x; 1.1943x over previous
//
#include <hip/hip_runtime.h>
#include <cmath>

#define U16 unsigned short

typedef __bf16 bf16x8_t __attribute__((ext_vector_type(8)));
typedef float f32x4_t __attribute__((ext_vector_type(4)));

union Frag { uint4 u4; unsigned u[4]; bf16x8_t b8; U16 s[8]; };

__device__ __forceinline__ float b2f(U16 u) {
  union { unsigned int i; float f; } x; x.i = ((unsigned int)u) << 16; return x.f;
}
__device__ __forceinline__ U16 f2b(float f) {
  union { float f; unsigned int i; } x; x.f = f;
  unsigned int r = x.i + 0x7FFFu + ((x.i >> 16) & 1u);
  return (U16)(r >> 16);
}
// pack two fp32 -> bf16x2 (RNE), a = low half, b = high half
__device__ __forceinline__ unsigned pack2bf(float a, float b) {
  union { float f; unsigned u; } xa, xb; xa.f = a; xb.f = b;
  unsigned ra = xa.u + 0x7FFFu + ((xa.u >> 16) & 1u);
  unsigned rb = xb.u + 0x7FFFu + ((xb.u >> 16) & 1u);
  return (ra >> 16) | (rb & 0xFFFF0000u);
}
__device__ __forceinline__ float fast_silu(float z) {
  return z * __builtin_amdgcn_rcpf(1.f + __expf(-z));
}

// ---------------- weight transpose + fp32->bf16: in[R,C] fp32 -> out[C,R] bf16 ----------------
__global__ __launch_bounds__(256) void transpose_f2b(const float* __restrict__ in,
                                                     U16* __restrict__ out, int R, int C) {
  __shared__ float tile[32][33];
  int c0 = blockIdx.x * 32, r0 = blockIdx.y * 32;
  int tx = threadIdx.x & 31, ty = threadIdx.x >> 5;
#pragma unroll
  for (int yy = 0; yy < 4; ++yy)
    tile[ty + yy * 8][tx] = in[(size_t)(r0 + ty + yy * 8) * C + c0 + tx];
  __syncthreads();
#pragma unroll
  for (int yy = 0; yy < 4; ++yy)
    out[(size_t)(c0 + ty + yy * 8) * R + r0 + tx] = f2b(tile[tx][ty + yy * 8]);
}

// rb_w2 fp32 [768,12] -> chunked bf16 layout w2L[pp][lane][8]:
//   w2L[((pp*64+lane)*8)+j] = w2[(pp*32+(lane>>4)*8+j)*12 + (lane&15)]  (0 if row>=12)
__global__ __launch_bounds__(256) void w2chunk_kernel(const float* __restrict__ w2,
                                                      U16* __restrict__ w2L) {
  int idx = blockIdx.x * 256 + threadIdx.x;
  if (idx < 24 * 64 * 8) {
    int j = idx & 7, lane = (idx >> 3) & 63, pp = idx >> 9;
    int row = lane & 15, col = pp * 32 + ((lane >> 4) << 3) + j;
    w2L[idx] = (row < 12) ? f2b(w2[col * 12 + row]) : (U16)0;
  }
}

// ---------------- layernorm over D=768 (fp32 in, bf16 out), one block per row ----------------
__global__ __launch_bounds__(256) void ln_kernel(const float* __restrict__ X,
                                                 const float* __restrict__ gam,
                                                 const float* __restrict__ bet,
                                                 U16* __restrict__ Y) {
  int row = blockIdx.x, tid = threadIdx.x;
  __shared__ float r1[256], r2[256];
  float v[3];
#pragma unroll
  for (int j = 0; j < 3; ++j) v[j] = X[(size_t)row * 768 + tid + j * 256];
  r1[tid] = v[0] + v[1] + v[2];
  r2[tid] = v[0] * v[0] + v[1] * v[1] + v[2] * v[2];
  __syncthreads();
  for (int s = 128; s > 0; s >>= 1) {
    if (tid < s) { r1[tid] += r1[tid + s]; r2[tid] += r2[tid + s]; }
    __syncthreads();
  }
  float mean = r1[0] * (1.f / 768.f);
  float var = r2[0] * (1.f / 768.f) - mean * mean;
  float rstd = rsqrtf(var + 1e-5f);
#pragma unroll
  for (int j = 0; j < 3; ++j) {
    int c = tid + j * 256;
    Y[(size_t)row * 768 + c] = f2b((v[j] - mean) * rstd * gam[c] + bet[c]);
  }
}

// ---------------- generic bf16-MFMA GEMM: C = epi(A[M,K] @ B + bias) ----------------
// 64x64 tile per block, BK=32, 4 waves (2x2 of 32x32).
// EPI: 0=none 1=silu 2=gelu(exact) 3=sigmoid(z)*other 4=z+other
#define LDP 40
template <int EPI, bool OUTF32>
__global__ __launch_bounds__(256) void gemm_bt(const U16* __restrict__ A,
                                               const U16* __restrict__ BT,
                                               const float* __restrict__ bias,
                                               const float* __restrict__ other,
                                               void* __restrict__ Cout,
                                               int M, int N, int K) {
  __shared__ __align__(16) U16 sA[64 * LDP];
  __shared__ __align__(16) U16 sB[64 * LDP];
  int tid = threadIdx.x;
  int lane = tid & 63, wave = tid >> 6;
  int m0 = blockIdx.y * 64, n0 = blockIdx.x * 64;
  int wm = (wave >> 1) * 32, wn = (wave & 1) * 32;
  int lm = lane & 15, lq = lane >> 4;
  int srow = tid >> 2;
  int scol = (tid & 3) * 8;
  f32x4_t acc[2][2] = {};
  for (int k0 = 0; k0 < K; k0 += 32) {
    __syncthreads();
    uint4 a0 = *(const uint4*)(A + (size_t)(m0 + srow) * K + k0 + scol);
    uint4 b0 = *(const uint4*)(BT + (size_t)(n0 + srow) * K + k0 + scol);
    *(uint4*)&sA[srow * LDP + scol] = a0;
    *(uint4*)&sB[srow * LDP + scol] = b0;
    __syncthreads();
    Frag af[2], bf[2];
#pragma unroll
    for (int mt = 0; mt < 2; ++mt)
      af[mt].u4 = *(const uint4*)&sA[(wm + mt * 16 + lm) * LDP + lq * 8];
#pragma unroll
    for (int nt = 0; nt < 2; ++nt)
      bf[nt].u4 = *(const uint4*)&sB[(wn + nt * 16 + lm) * LDP + lq * 8];
#pragma unroll
    for (int mt = 0; mt < 2; ++mt)
#pragma unroll
      for (int nt = 0; nt < 2; ++nt)
        acc[mt][nt] = __builtin_amdgcn_mfma_f32_16x16x32_bf16(af[mt].b8, bf[nt].b8,
                                                              acc[mt][nt], 0, 0, 0);
  }
#pragma unroll
  for (int nt = 0; nt < 2; ++nt) {
    int gc = n0 + wn + nt * 16 + lm;
    float bz = bias[gc];
#pragma unroll
    for (int mt = 0; mt < 2; ++mt) {
#pragma unroll
      for (int r = 0; r < 4; ++r) {
        int gr = m0 + wm + mt * 16 + lq * 4 + r;
        size_t idx = (size_t)gr * N + gc;
        float z = acc[mt][nt][r] + bz;
        float o;
        if (EPI == 0) o = z;
        else if (EPI == 1) o = fast_silu(z);
        else if (EPI == 2) o = 0.5f * z * (1.f + erff(z * 0.70710678118f));
        else if (EPI == 3) o = other[idx] * __builtin_amdgcn_rcpf(1.f + __expf(-z));
        else o = z + other[idx];
        if (OUTF32) ((float*)Cout)[idx] = o;
        else ((U16*)Cout)[idx] = f2b(o);
      }
    }
  }
}

// ---------------- fused relative-bias MLP v3: no LDS, no barriers ----------------
// bias[b,h,i,j] = silu(dist[(b,i,j),:64] @ w1 + b1) @ w2 + b2
// First MFMA computes z^T (A=w1 rows in permuted order, B=dist rows) so silu output
// lands directly in the A-frag layout of the second MFMA. Weight fragments are loaded
// straight from global (L1-resident: w1 96KB, w2L 24KB, shared by all blocks).
// Verified permutation (R3): A-tile row m of tt holds hidden h=pp*32+8*(m>>2)+4*tt+(m&3);
// D row m=lq*4+r -> h=pp*32+8*lq+4*tt+r, matching A-frag k-pos lq*8+(tt*4+r) of layer 2.
__global__ __launch_bounds__(256) void rb_kernel(const float* __restrict__ dist,  // [262144,64]
                                                 const U16* __restrict__ w1T,     // [768,64] bf16
                                                 const float* __restrict__ b1,    // [768]
                                                 const U16* __restrict__ w2L,     // [24*64*8] bf16
                                                 const float* __restrict__ b2,    // [12]
                                                 float* __restrict__ biasOut) {   // [4,12,256,256]
  int tid = threadIdx.x;
  int lane = tid & 63, wave = tid >> 6;
  int lm = lane & 15, lq = lane >> 4;
  int r0 = blockIdx.x * 128;
  // dist B-fragments: 2 row-groups x 2 k-chunks, loaded once (reused all 24 pp iters)
  Frag bd[2][2];
#pragma unroll
  for (int g = 0; g < 2; ++g) {
    const float* ap = dist + (size_t)(r0 + (wave * 2 + g) * 16 + lm) * 64 + lq * 8;
    float4 v0 = ((const float4*)ap)[0];
    float4 v1 = ((const float4*)ap)[1];
    float4 v2 = ((const float4*)(ap + 32))[0];
    float4 v3 = ((const float4*)(ap + 32))[1];
    bd[g][0].u[0] = pack2bf(v0.x, v0.y); bd[g][0].u[1] = pack2bf(v0.z, v0.w);
    bd[g][0].u[2] = pack2bf(v1.x, v1.y); bd[g][0].u[3] = pack2bf(v1.z, v1.w);
    bd[g][1].u[0] = pack2bf(v2.x, v2.y); bd[g][1].u[1] = pack2bf(v2.z, v2.w);
    bd[g][1].u[2] = pack2bf(v3.x, v3.y); bd[g][1].u[3] = pack2bf(v3.z, v3.w);
  }
  // per-lane weight pointers (advance per pp)
  const U16* w1p0 = w1T + (size_t)(((lm >> 2) << 3) + (lm & 3)) * 64 + lq * 8;      // tt=0
  const U16* w1p1 = w1p0 + 4 * 64;                                                  // tt=1
  const U16* w2p = w2L + lane * 8;
  const float* b1p = b1 + lq * 8;
  f32x4_t bacc[2] = {{0.f, 0.f, 0.f, 0.f}, {0.f, 0.f, 0.f, 0.f}};
  for (int pp = 0; pp < 24; ++pp) {
    Frag w00, w01, w10, w11, wb;
    w00.u4 = *(const uint4*)w1p0;
    w01.u4 = *(const uint4*)(w1p0 + 32);
    w10.u4 = *(const uint4*)w1p1;
    w11.u4 = *(const uint4*)(w1p1 + 32);
    wb.u4 = *(const uint4*)w2p;
    float4 bb0 = *(const float4*)b1p;
    float4 bb1 = *(const float4*)(b1p + 4);
    Frag af2[2];
#pragma unroll
    for (int g = 0; g < 2; ++g) {
      f32x4_t z0 = {0.f, 0.f, 0.f, 0.f}, z1 = {0.f, 0.f, 0.f, 0.f};
      z0 = __builtin_amdgcn_mfma_f32_16x16x32_bf16(w00.b8, bd[g][0].b8, z0, 0, 0, 0);
      z0 = __builtin_amdgcn_mfma_f32_16x16x32_bf16(w01.b8, bd[g][1].b8, z0, 0, 0, 0);
      z1 = __builtin_amdgcn_mfma_f32_16x16x32_bf16(w10.b8, bd[g][0].b8, z1, 0, 0, 0);
      z1 = __builtin_amdgcn_mfma_f32_16x16x32_bf16(w11.b8, bd[g][1].b8, z1, 0, 0, 0);
      float s0 = fast_silu(z0[0] + bb0.x), s1 = fast_silu(z0[1] + bb0.y);
      float s2 = fast_silu(z0[2] + bb0.z), s3 = fast_silu(z0[3] + bb0.w);
      float t0 = fast_silu(z1[0] + bb1.x), t1 = fast_silu(z1[1] + bb1.y);
      float t2 = fast_silu(z1[2] + bb1.z), t3 = fast_silu(z1[3] + bb1.w);
      af2[g].u[0] = pack2bf(s0, s1); af2[g].u[1] = pack2bf(s2, s3);
      af2[g].u[2] = pack2bf(t0, t1); af2[g].u[3] = pack2bf(t2, t3);
    }
    bacc[0] = __builtin_amdgcn_mfma_f32_16x16x32_bf16(af2[0].b8, wb.b8, bacc[0], 0, 0, 0);
    bacc[1] = __builtin_amdgcn_mfma_f32_16x16x32_bf16(af2[1].b8, wb.b8, bacc[1], 0, 0, 0);
    w1p0 += 32 * 64; w1p1 += 32 * 64; w2p += 64 * 8; b1p += 32;
  }
  int h = lm;
  if (h < 12) {
    float hb = b2[h];
#pragma unroll
    for (int g = 0; g < 2; ++g) {
#pragma unroll
      for (int r = 0; r < 4; ++r) {
        int gr = r0 + (wave * 2 + g) * 16 + lq * 4 + r;  // flat (b,i,j)
        int b = gr >> 16, rem = gr & 65535, i = rem >> 8, j = rem & 255;
        biasOut[(((size_t)b * 12 + h) * 256 + i) * 256 + j] = bacc[g][r] + hb;
      }
    }
  }
}

// ---------------- attention v2: wave handles 4 query rows; shfl softmax ----------------
// grid (16, 48): blockIdx.x = 16-query chunk, blockIdx.y = b*12+h. 4 waves/block.
__global__ __launch_bounds__(256) void attn_kernel(const float* __restrict__ qkv,   // [1024,2304]
                                                   const float* __restrict__ biasB, // [4,12,256,256]
                                                   const int* __restrict__ mask,    // [4,256,256]
                                                   float* __restrict__ ctx) {       // [1024,768]
  int tid = threadIdx.x, lane = tid & 63, w = tid >> 6;
  int bh = blockIdx.y, b = bh / 12, h = bh % 12;
  int i0 = blockIdx.x * 16;
  __shared__ float sQ[16][68];
  __shared__ float sP[4][4][256];
  {
    int r = tid >> 4, c = (tid & 15) * 4;
    *(float4*)&sQ[r][c] = *(const float4*)&qkv[((size_t)(b * 256 + i0 + r)) * 2304 + h * 64 + c];
  }
  __syncthreads();
  int iw = i0 + w * 4;
  float lacc[4][4] = {};  // [qi][jc]
  const float* kbase = qkv + (size_t)b * 256 * 2304 + 768 + h * 64 + (size_t)lane * 2304;
#pragma unroll 4
  for (int dc = 0; dc < 16; ++dc) {
    float4 k0 = *(const float4*)(kbase + (size_t)0 * 64 * 2304 + dc * 4);
    float4 k1 = *(const float4*)(kbase + (size_t)1 * 64 * 2304 + dc * 4);
    float4 k2 = *(const float4*)(kbase + (size_t)2 * 64 * 2304 + dc * 4);
    float4 k3 = *(const float4*)(kbase + (size_t)3 * 64 * 2304 + dc * 4);
#pragma unroll
    for (int qi = 0; qi < 4; ++qi) {
      float4 q4 = *(const float4*)&sQ[w * 4 + qi][dc * 4];
      lacc[qi][0] += q4.x * k0.x + q4.y * k0.y + q4.z * k0.z + q4.w * k0.w;
      lacc[qi][1] += q4.x * k1.x + q4.y * k1.y + q4.z * k1.z + q4.w * k1.w;
      lacc[qi][2] += q4.x * k2.x + q4.y * k2.y + q4.z * k2.z + q4.w * k2.w;
      lacc[qi][3] += q4.x * k3.x + q4.y * k3.y + q4.z * k3.z + q4.w * k3.w;
    }
  }
#pragma unroll
  for (int qi = 0; qi < 4; ++qi) {
    int gi = iw + qi;
    const float* brow = biasB + (((size_t)b * 12 + h) * 256 + gi) * 256;
    const int* mrow = mask + ((size_t)b * 256 + gi) * 256;
    float lg[4];
#pragma unroll
    for (int jc = 0; jc < 4; ++jc) {
      float lv = lacc[qi][jc] * 0.125f + brow[jc * 64 + lane];
      lg[jc] = mrow[jc * 64 + lane] ? lv : -1e30f;
    }
    float mx = fmaxf(fmaxf(lg[0], lg[1]), fmaxf(lg[2], lg[3]));
#pragma unroll
    for (int m = 32; m > 0; m >>= 1) mx = fmaxf(mx, __shfl_xor(mx, m));
    float e[4], sum = 0.f;
#pragma unroll
    for (int jc = 0; jc < 4; ++jc) { e[jc] = __expf(lg[jc] - mx); sum += e[jc]; }
#pragma unroll
    for (int m = 32; m > 0; m >>= 1) sum += __shfl_xor(sum, m);
    float inv = __builtin_amdgcn_rcpf(sum);
#pragma unroll
    for (int jc = 0; jc < 4; ++jc) sP[w][qi][jc * 64 + lane] = e[jc] * inv;
  }
  __syncthreads();
  float ca[4] = {0.f, 0.f, 0.f, 0.f};
  const float* vcol = qkv + (size_t)b * 256 * 2304 + 1536 + h * 64 + lane;
#pragma unroll 2
  for (int j4 = 0; j4 < 256; j4 += 4) {
    float4 p0 = *(const float4*)&sP[w][0][j4];
    float4 p1 = *(const float4*)&sP[w][1][j4];
    float4 p2 = *(const float4*)&sP[w][2][j4];
    float4 p3 = *(const float4*)&sP[w][3][j4];
    const float* pp0 = (const float*)&p0;
    const float* pp1 = (const float*)&p1;
    const float* pp2 = (const float*)&p2;
    const float* pp3 = (const float*)&p3;
#pragma unroll
    for (int jj = 0; jj < 4; ++jj) {
      float v = vcol[(size_t)(j4 + jj) * 2304];
      ca[0] += pp0[jj] * v;
      ca[1] += pp1[jj] * v;
      ca[2] += pp2[jj] * v;
      ca[3] += pp3[jj] * v;
    }
  }
#pragma unroll
  for (int qi = 0; qi < 4; ++qi)
    ctx[((size_t)(b * 256 + iw + qi)) * 768 + h * 64 + lane] = ca[qi];
}

// ---------------- launcher ----------------
extern "C" void kernel_launch(void* const* d_in, const int* in_sizes, int n_in,
                              void* d_out, int out_size, void* d_ws, size_t ws_size,
                              hipStream_t stream) {
  const float* x       = (const float*)d_in[0];
  const float* dist    = (const float*)d_in[1];
  const int* mask      = (const int*)d_in[2];
  const float* qkv_w   = (const float*)d_in[3];
  const float* qkv_b   = (const float*)d_in[4];
  const float* out_w   = (const float*)d_in[5];
  const float* out_b   = (const float*)d_in[6];
  const float* rb_w1   = (const float*)d_in[7];
  const float* rb_b1   = (const float*)d_in[8];
  const float* rb_w2   = (const float*)d_in[9];
  const float* rb_b2   = (const float*)d_in[10];
  const float* gate_w1 = (const float*)d_in[11];
  const float* gate_b1 = (const float*)d_in[12];
  const float* gate_w2 = (const float*)d_in[13];
  const float* gate_b2 = (const float*)d_in[14];
  const float* ff_w1   = (const float*)d_in[15];
  const float* ff_b1   = (const float*)d_in[16];
  const float* ff_w2   = (const float*)d_in[17];
  const float* ff_b2   = (const float*)d_in[18];
  const float* ln1_g   = (const float*)d_in[19];
  const float* ln1_b   = (const float*)d_in[20];
  const float* ln2_g   = (const float*)d_in[21];
  const float* ln2_b   = (const float*)d_in[22];

  char* w = (char*)d_ws;
  auto alloc = [&](size_t bytes) {
    char* p = w;
    w += (bytes + 255) & ~(size_t)255;
    return p;
  };
  U16* xn      = (U16*)alloc(1024 * 768 * 2);
  float* qkvb  = (float*)alloc((size_t)1024 * 2304 * 4);
  U16* qkv_wT  = (U16*)alloc(2304 * 768 * 2);
  U16* out_wT  = (U16*)alloc(768 * 768 * 2);
  U16* g1wT    = (U16*)alloc(768 * 768 * 2);
  U16* g2wT    = (U16*)alloc(768 * 768 * 2);
  U16* ff1wT   = (U16*)alloc(1536 * 768 * 2);
  U16* ff2wT   = (U16*)alloc(768 * 1536 * 2);
  U16* rb1wT   = (U16*)alloc(768 * 64 * 2);
  U16* rb2wL   = (U16*)alloc(24 * 64 * 8 * 2);
  float* biasB = (float*)alloc((size_t)4 * 12 * 256 * 256 * 4);
  float* ctx   = (float*)alloc(1024 * 768 * 4);
  U16* g1      = (U16*)alloc(1024 * 768 * 2);
  U16* cg      = (U16*)alloc(1024 * 768 * 2);
  float* x2    = (float*)alloc(1024 * 768 * 4);
  U16* y       = (U16*)alloc(1024 * 768 * 2);
  U16* f1      = (U16*)alloc(1024 * 1536 * 2);
  (void)ws_size; (void)in_sizes; (void)n_in; (void)out_size;

  // weight prep (fp32 -> bf16)
  transpose_f2b<<<dim3(2304 / 32, 768 / 32), 256, 0, stream>>>(qkv_w, qkv_wT, 768, 2304);
  transpose_f2b<<<dim3(768 / 32, 768 / 32), 256, 0, stream>>>(out_w, out_wT, 768, 768);
  transpose_f2b<<<dim3(768 / 32, 768 / 32), 256, 0, stream>>>(gate_w1, g1wT, 768, 768);
  transpose_f2b<<<dim3(768 / 32, 768 / 32), 256, 0, stream>>>(gate_w2, g2wT, 768, 768);
  transpose_f2b<<<dim3(1536 / 32, 768 / 32), 256, 0, stream>>>(ff_w1, ff1wT, 768, 1536);
  transpose_f2b<<<dim3(768 / 32, 1536 / 32), 256, 0, stream>>>(ff_w2, ff2wT, 1536, 768);
  transpose_f2b<<<dim3(768 / 32, 64 / 32), 256, 0, stream>>>(rb_w1, rb1wT, 64, 768);
  w2chunk_kernel<<<48, 256, 0, stream>>>(rb_w2, rb2wL);

  // LN1 -> xn (bf16)
  ln_kernel<<<1024, 256, 0, stream>>>(x, ln1_g, ln1_b, xn);
  // qkv projection -> fp32
  gemm_bt<0, true><<<dim3(36, 16), 256, 0, stream>>>(xn, qkv_wT, qkv_b, nullptr, qkvb,
                                                     1024, 2304, 768);
  // relative bias MLP (fused, no-barrier)
  rb_kernel<<<2048, 256, 0, stream>>>(dist, rb1wT, rb_b1, rb2wL, rb_b2, biasB);
  // attention -> ctx fp32
  attn_kernel<<<dim3(16, 48), 256, 0, stream>>>(qkvb, biasB, mask, ctx);
  // gate MLP
  gemm_bt<1, false><<<dim3(12, 16), 256, 0, stream>>>(xn, g1wT, gate_b1, nullptr, g1,
                                                      1024, 768, 768);
  gemm_bt<3, false><<<dim3(12, 16), 256, 0, stream>>>(g1, g2wT, gate_b2, ctx, cg,
                                                      1024, 768, 768);
  // out projection + residual -> x2 (fp32)
  gemm_bt<4, true><<<dim3(12, 16), 256, 0, stream>>>(cg, out_wT, out_b, x, x2,
                                                     1024, 768, 768);
  // LN2 -> y (bf16)
  ln_kernel<<<1024, 256, 0, stream>>>(x2, ln2_g, ln2_b, y);
  // FF
  gemm_bt<2, false><<<dim3(24, 16), 256, 0, stream>>>(y, ff1wT, ff_b1, nullptr, f1,
                                                      1024, 1536, 768);
  gemm_bt<4, true><<<dim3(12, 16), 256, 0, stream>>>(f1, ff2wT, ff_b2, x2, (float*)d_out,
                                                     1024, 768, 1536);
}

// Round 5
// 369.596 us; speedup vs baseline: 1.6621x; 1.1573x over previous
//
#include <hip/hip_runtime.h>
#include <cmath>

#define U16 unsigned short

typedef __bf16 bf16x8_t __attribute__((ext_vector_type(8)));
typedef float f32x4_t __attribute__((ext_vector_type(4)));

union Frag { uint4 u4; unsigned u[4]; bf16x8_t b8; U16 s[8]; };

__device__ __forceinline__ float b2f(U16 u) {
  union { unsigned int i; float f; } x; x.i = ((unsigned int)u) << 16; return x.f;
}
__device__ __forceinline__ U16 f2b(float f) {
  union { float f; unsigned int i; } x; x.f = f;
  unsigned int r = x.i + 0x7FFFu + ((x.i >> 16) & 1u);
  return (U16)(r >> 16);
}
// pack two fp32 -> bf16x2, round-half-up (0.5 ULP; deviates from RNE only on exact ties)
// 3 VALU ops: 2 adds + 1 v_perm  (vs 11 for full RNE pair)
__device__ __forceinline__ unsigned pack2bf_fast(float a, float b) {
  union { float f; unsigned u; } xa, xb; xa.f = a; xb.f = b;
  return __builtin_amdgcn_perm(xb.u + 0x8000u, xa.u + 0x8000u, 0x07060302);
}
__device__ __forceinline__ float fast_silu(float z) {
  return z * __builtin_amdgcn_rcpf(1.f + __expf(-z));
}

// ---------------- merged weight-prep kernel ----------------
// blocks [0,5808): 32x32 transpose tiles fp32->bf16 for 7 weights
// blocks [5808,5856): rb_w2 chunking
__global__ __launch_bounds__(256) void prep_kernel(
    const float* __restrict__ qkv_w, const float* __restrict__ out_w,
    const float* __restrict__ g1w, const float* __restrict__ g2w,
    const float* __restrict__ ff1w, const float* __restrict__ ff2w,
    const float* __restrict__ rb1w, const float* __restrict__ rb2w,
    U16* __restrict__ qkv_wT, U16* __restrict__ out_wT, U16* __restrict__ g1wT,
    U16* __restrict__ g2wT, U16* __restrict__ ff1wT, U16* __restrict__ ff2wT,
    U16* __restrict__ rb1wT, U16* __restrict__ rb2wL) {
  int bid = blockIdx.x;
  if (bid >= 5808) {  // rb_w2 [768,12] -> w2L[pp][lane][8]
    int idx = (bid - 5808) * 256 + threadIdx.x;
    int j = idx & 7, lane = (idx >> 3) & 63, pp = idx >> 9;
    int row = lane & 15, col = pp * 32 + ((lane >> 4) << 3) + j;
    rb2wL[idx] = (row < 12) ? f2b(rb2w[col * 12 + row]) : (U16)0;
    return;
  }
  const float* in; U16* out; int R, C, base;
  if (bid < 1728)      { in = qkv_w; out = qkv_wT; R = 768;  C = 2304; base = 0; }
  else if (bid < 2304) { in = out_w; out = out_wT; R = 768;  C = 768;  base = 1728; }
  else if (bid < 2880) { in = g1w;   out = g1wT;   R = 768;  C = 768;  base = 2304; }
  else if (bid < 3456) { in = g2w;   out = g2wT;   R = 768;  C = 768;  base = 2880; }
  else if (bid < 4608) { in = ff1w;  out = ff1wT;  R = 768;  C = 1536; base = 3456; }
  else if (bid < 5760) { in = ff2w;  out = ff2wT;  R = 1536; C = 768;  base = 4608; }
  else                 { in = rb1w;  out = rb1wT;  R = 64;   C = 768;  base = 5760; }
  int bx = bid - base, tilesx = C / 32;
  int c0 = (bx % tilesx) * 32, r0 = (bx / tilesx) * 32;
  __shared__ float tile[32][33];
  int tx = threadIdx.x & 31, ty = threadIdx.x >> 5;
#pragma unroll
  for (int yy = 0; yy < 4; ++yy)
    tile[ty + yy * 8][tx] = in[(size_t)(r0 + ty + yy * 8) * C + c0 + tx];
  __syncthreads();
#pragma unroll
  for (int yy = 0; yy < 4; ++yy)
    out[(size_t)(c0 + ty + yy * 8) * R + r0 + tx] = f2b(tile[tx][ty + yy * 8]);
}

// ---------------- layernorm over D=768 (fp32 in, bf16 out), one block per row ----------------
__global__ __launch_bounds__(256) void ln_kernel(const float* __restrict__ X,
                                                 const float* __restrict__ gam,
                                                 const float* __restrict__ bet,
                                                 U16* __restrict__ Y) {
  int row = blockIdx.x, tid = threadIdx.x;
  __shared__ float r1[256], r2[256];
  float v[3];
#pragma unroll
  for (int j = 0; j < 3; ++j) v[j] = X[(size_t)row * 768 + tid + j * 256];
  r1[tid] = v[0] + v[1] + v[2];
  r2[tid] = v[0] * v[0] + v[1] * v[1] + v[2] * v[2];
  __syncthreads();
  for (int s = 128; s > 0; s >>= 1) {
    if (tid < s) { r1[tid] += r1[tid + s]; r2[tid] += r2[tid + s]; }
    __syncthreads();
  }
  float mean = r1[0] * (1.f / 768.f);
  float var = r2[0] * (1.f / 768.f) - mean * mean;
  float rstd = rsqrtf(var + 1e-5f);
#pragma unroll
  for (int j = 0; j < 3; ++j) {
    int c = tid + j * 256;
    Y[(size_t)row * 768 + c] = f2b((v[j] - mean) * rstd * gam[c] + bet[c]);
  }
}

// ---------------- generic bf16-MFMA GEMM: C = epi(A[M,K] @ B + bias) ----------------
// 64x64 tile per block, BK=32, 4 waves (2x2 of 32x32).
// EPI: 0=none 1=silu 2=gelu(exact) 3=sigmoid(z)*other 4=z+other
#define LDP 40
template <int EPI, bool OUTF32>
__global__ __launch_bounds__(256) void gemm_bt(const U16* __restrict__ A,
                                               const U16* __restrict__ BT,
                                               const float* __restrict__ bias,
                                               const float* __restrict__ other,
                                               void* __restrict__ Cout,
                                               int M, int N, int K) {
  __shared__ __align__(16) U16 sA[64 * LDP];
  __shared__ __align__(16) U16 sB[64 * LDP];
  int tid = threadIdx.x;
  int lane = tid & 63, wave = tid >> 6;
  int m0 = blockIdx.y * 64, n0 = blockIdx.x * 64;
  int wm = (wave >> 1) * 32, wn = (wave & 1) * 32;
  int lm = lane & 15, lq = lane >> 4;
  int srow = tid >> 2;
  int scol = (tid & 3) * 8;
  f32x4_t acc[2][2] = {};
  for (int k0 = 0; k0 < K; k0 += 32) {
    __syncthreads();
    uint4 a0 = *(const uint4*)(A + (size_t)(m0 + srow) * K + k0 + scol);
    uint4 b0 = *(const uint4*)(BT + (size_t)(n0 + srow) * K + k0 + scol);
    *(uint4*)&sA[srow * LDP + scol] = a0;
    *(uint4*)&sB[srow * LDP + scol] = b0;
    __syncthreads();
    Frag af[2], bf[2];
#pragma unroll
    for (int mt = 0; mt < 2; ++mt)
      af[mt].u4 = *(const uint4*)&sA[(wm + mt * 16 + lm) * LDP + lq * 8];
#pragma unroll
    for (int nt = 0; nt < 2; ++nt)
      bf[nt].u4 = *(const uint4*)&sB[(wn + nt * 16 + lm) * LDP + lq * 8];
#pragma unroll
    for (int mt = 0; mt < 2; ++mt)
#pragma unroll
      for (int nt = 0; nt < 2; ++nt)
        acc[mt][nt] = __builtin_amdgcn_mfma_f32_16x16x32_bf16(af[mt].b8, bf[nt].b8,
                                                              acc[mt][nt], 0, 0, 0);
  }
#pragma unroll
  for (int nt = 0; nt < 2; ++nt) {
    int gc = n0 + wn + nt * 16 + lm;
    float bz = bias[gc];
#pragma unroll
    for (int mt = 0; mt < 2; ++mt) {
#pragma unroll
      for (int r = 0; r < 4; ++r) {
        int gr = m0 + wm + mt * 16 + lq * 4 + r;
        size_t idx = (size_t)gr * N + gc;
        float z = acc[mt][nt][r] + bz;
        float o;
        if (EPI == 0) o = z;
        else if (EPI == 1) o = fast_silu(z);
        else if (EPI == 2) o = 0.5f * z * (1.f + erff(z * 0.70710678118f));
        else if (EPI == 3) o = other[idx] * __builtin_amdgcn_rcpf(1.f + __expf(-z));
        else o = z + other[idx];
        if (OUTF32) ((float*)Cout)[idx] = o;
        else ((U16*)Cout)[idx] = f2b(o);
      }
    }
  }
}

// ---------------- fused relative-bias MLP v4 ----------------
// bias[b,h,i,j] = silu(dist[(b,i,j),:64] @ w1 + b1) @ w2 + b2
// Transposed layer-1 (A=w1 permuted rows, B=dist) so silu lands in layer-2 A-frag layout
// (mapping verified R3/R4). v4: 256 rows/block (4 groups/wave) halves redundant weight
// loads per silu; 3-op bf16 pack; 4 independent accumulator chains.
__global__ __launch_bounds__(256) void rb_kernel(const float* __restrict__ dist,  // [262144,64]
                                                 const U16* __restrict__ w1T,     // [768,64] bf16
                                                 const float* __restrict__ b1,    // [768]
                                                 const U16* __restrict__ w2L,     // [24*64*8] bf16
                                                 const float* __restrict__ b2,    // [12]
                                                 float* __restrict__ biasOut) {   // [4,12,256,256]
  int tid = threadIdx.x;
  int lane = tid & 63, wave = tid >> 6;
  int lm = lane & 15, lq = lane >> 4;
  int r0 = blockIdx.x * 256;
  // dist B-fragments: 4 row-groups x 2 k-chunks, loaded once (reused all 24 pp iters)
  Frag bd[4][2];
#pragma unroll
  for (int g = 0; g < 4; ++g) {
    const float* ap = dist + (size_t)(r0 + (wave * 4 + g) * 16 + lm) * 64 + lq * 8;
    float4 v0 = ((const float4*)ap)[0];
    float4 v1 = ((const float4*)ap)[1];
    float4 v2 = ((const float4*)(ap + 32))[0];
    float4 v3 = ((const float4*)(ap + 32))[1];
    bd[g][0].u[0] = pack2bf_fast(v0.x, v0.y); bd[g][0].u[1] = pack2bf_fast(v0.z, v0.w);
    bd[g][0].u[2] = pack2bf_fast(v1.x, v1.y); bd[g][0].u[3] = pack2bf_fast(v1.z, v1.w);
    bd[g][1].u[0] = pack2bf_fast(v2.x, v2.y); bd[g][1].u[1] = pack2bf_fast(v2.z, v2.w);
    bd[g][1].u[2] = pack2bf_fast(v3.x, v3.y); bd[g][1].u[3] = pack2bf_fast(v3.z, v3.w);
  }
  // per-lane weight pointers (advance per pp)
  const U16* w1p0 = w1T + (size_t)(((lm >> 2) << 3) + (lm & 3)) * 64 + lq * 8;  // tt=0
  const U16* w1p1 = w1p0 + 4 * 64;                                              // tt=1
  const U16* w2p = w2L + lane * 8;
  const float* b1p = b1 + lq * 8;
  f32x4_t bacc[4] = {};
  for (int pp = 0; pp < 24; ++pp) {
    Frag w00, w01, w10, w11, wb;
    w00.u4 = *(const uint4*)w1p0;
    w01.u4 = *(const uint4*)(w1p0 + 32);
    w10.u4 = *(const uint4*)w1p1;
    w11.u4 = *(const uint4*)(w1p1 + 32);
    wb.u4 = *(const uint4*)w2p;
    float4 bb0 = *(const float4*)b1p;
    float4 bb1 = *(const float4*)(b1p + 4);
#pragma unroll
    for (int g = 0; g < 4; ++g) {
      f32x4_t z0 = {0.f, 0.f, 0.f, 0.f}, z1 = {0.f, 0.f, 0.f, 0.f};
      z0 = __builtin_amdgcn_mfma_f32_16x16x32_bf16(w00.b8, bd[g][0].b8, z0, 0, 0, 0);
      z0 = __builtin_amdgcn_mfma_f32_16x16x32_bf16(w01.b8, bd[g][1].b8, z0, 0, 0, 0);
      z1 = __builtin_amdgcn_mfma_f32_16x16x32_bf16(w10.b8, bd[g][0].b8, z1, 0, 0, 0);
      z1 = __builtin_amdgcn_mfma_f32_16x16x32_bf16(w11.b8, bd[g][1].b8, z1, 0, 0, 0);
      float s0 = fast_silu(z0[0] + bb0.x), s1 = fast_silu(z0[1] + bb0.y);
      float s2 = fast_silu(z0[2] + bb0.z), s3 = fast_silu(z0[3] + bb0.w);
      float t0 = fast_silu(z1[0] + bb1.x), t1 = fast_silu(z1[1] + bb1.y);
      float t2 = fast_silu(z1[2] + bb1.z), t3 = fast_silu(z1[3] + bb1.w);
      Frag af2;
      af2.u[0] = pack2bf_fast(s0, s1); af2.u[1] = pack2bf_fast(s2, s3);
      af2.u[2] = pack2bf_fast(t0, t1); af2.u[3] = pack2bf_fast(t2, t3);
      bacc[g] = __builtin_amdgcn_mfma_f32_16x16x32_bf16(af2.b8, wb.b8, bacc[g], 0, 0, 0);
    }
    w1p0 += 32 * 64; w1p1 += 32 * 64; w2p += 64 * 8; b1p += 32;
  }
  int h = lm;
  if (h < 12) {
    float hb = b2[h];
#pragma unroll
    for (int g = 0; g < 4; ++g) {
#pragma unroll
      for (int r = 0; r < 4; ++r) {
        int gr = r0 + (wave * 4 + g) * 16 + lq * 4 + r;  // flat (b,i,j)
        int b = gr >> 16, rem = gr & 65535, i = rem >> 8, j = rem & 255;
        biasOut[(((size_t)b * 12 + h) * 256 + i) * 256 + j] = bacc[g][r] + hb;
      }
    }
  }
}

// ---------------- attention v2: wave handles 4 query rows; shfl softmax ----------------
// grid (16, 48): blockIdx.x = 16-query chunk, blockIdx.y = b*12+h. 4 waves/block.
__global__ __launch_bounds__(256) void attn_kernel(const float* __restrict__ qkv,   // [1024,2304]
                                                   const float* __restrict__ biasB, // [4,12,256,256]
                                                   const int* __restrict__ mask,    // [4,256,256]
                                                   float* __restrict__ ctx) {       // [1024,768]
  int tid = threadIdx.x, lane = tid & 63, w = tid >> 6;
  int bh = blockIdx.y, b = bh / 12, h = bh % 12;
  int i0 = blockIdx.x * 16;
  __shared__ float sQ[16][68];
  __shared__ float sP[4][4][256];
  {
    int r = tid >> 4, c = (tid & 15) * 4;
    *(float4*)&sQ[r][c] = *(const float4*)&qkv[((size_t)(b * 256 + i0 + r)) * 2304 + h * 64 + c];
  }
  __syncthreads();
  int iw = i0 + w * 4;
  float lacc[4][4] = {};  // [qi][jc]
  const float* kbase = qkv + (size_t)b * 256 * 2304 + 768 + h * 64 + (size_t)lane * 2304;
#pragma unroll 4
  for (int dc = 0; dc < 16; ++dc) {
    float4 k0 = *(const float4*)(kbase + (size_t)0 * 64 * 2304 + dc * 4);
    float4 k1 = *(const float4*)(kbase + (size_t)1 * 64 * 2304 + dc * 4);
    float4 k2 = *(const float4*)(kbase + (size_t)2 * 64 * 2304 + dc * 4);
    float4 k3 = *(const float4*)(kbase + (size_t)3 * 64 * 2304 + dc * 4);
#pragma unroll
    for (int qi = 0; qi < 4; ++qi) {
      float4 q4 = *(const float4*)&sQ[w * 4 + qi][dc * 4];
      lacc[qi][0] += q4.x * k0.x + q4.y * k0.y + q4.z * k0.z + q4.w * k0.w;
      lacc[qi][1] += q4.x * k1.x + q4.y * k1.y + q4.z * k1.z + q4.w * k1.w;
      lacc[qi][2] += q4.x * k2.x + q4.y * k2.y + q4.z * k2.z + q4.w * k2.w;
      lacc[qi][3] += q4.x * k3.x + q4.y * k3.y + q4.z * k3.z + q4.w * k3.w;
    }
  }
#pragma unroll
  for (int qi = 0; qi < 4; ++qi) {
    int gi = iw + qi;
    const float* brow = biasB + (((size_t)b * 12 + h) * 256 + gi) * 256;
    const int* mrow = mask + ((size_t)b * 256 + gi) * 256;
    float lg[4];
#pragma unroll
    for (int jc = 0; jc < 4; ++jc) {
      float lv = lacc[qi][jc] * 0.125f + brow[jc * 64 + lane];
      lg[jc] = mrow[jc * 64 + lane] ? lv : -1e30f;
    }
    float mx = fmaxf(fmaxf(lg[0], lg[1]), fmaxf(lg[2], lg[3]));
#pragma unroll
    for (int m = 32; m > 0; m >>= 1) mx = fmaxf(mx, __shfl_xor(mx, m));
    float e[4], sum = 0.f;
#pragma unroll
    for (int jc = 0; jc < 4; ++jc) { e[jc] = __expf(lg[jc] - mx); sum += e[jc]; }
#pragma unroll
    for (int m = 32; m > 0; m >>= 1) sum += __shfl_xor(sum, m);
    float inv = __builtin_amdgcn_rcpf(sum);
#pragma unroll
    for (int jc = 0; jc < 4; ++jc) sP[w][qi][jc * 64 + lane] = e[jc] * inv;
  }
  __syncthreads();
  float ca[4] = {0.f, 0.f, 0.f, 0.f};
  const float* vcol = qkv + (size_t)b * 256 * 2304 + 1536 + h * 64 + lane;
#pragma unroll 2
  for (int j4 = 0; j4 < 256; j4 += 4) {
    float4 p0 = *(const float4*)&sP[w][0][j4];
    float4 p1 = *(const float4*)&sP[w][1][j4];
    float4 p2 = *(const float4*)&sP[w][2][j4];
    float4 p3 = *(const float4*)&sP[w][3][j4];
    const float* pp0 = (const float*)&p0;
    const float* pp1 = (const float*)&p1;
    const float* pp2 = (const float*)&p2;
    const float* pp3 = (const float*)&p3;
#pragma unroll
    for (int jj = 0; jj < 4; ++jj) {
      float v = vcol[(size_t)(j4 + jj) * 2304];
      ca[0] += pp0[jj] * v;
      ca[1] += pp1[jj] * v;
      ca[2] += pp2[jj] * v;
      ca[3] += pp3[jj] * v;
    }
  }
#pragma unroll
  for (int qi = 0; qi < 4; ++qi)
    ctx[((size_t)(b * 256 + iw + qi)) * 768 + h * 64 + lane] = ca[qi];
}

// ---------------- launcher ----------------
extern "C" void kernel_launch(void* const* d_in, const int* in_sizes, int n_in,
                              void* d_out, int out_size, void* d_ws, size_t ws_size,
                              hipStream_t stream) {
  const float* x       = (const float*)d_in[0];
  const float* dist    = (const float*)d_in[1];
  const int* mask      = (const int*)d_in[2];
  const float* qkv_w   = (const float*)d_in[3];
  const float* qkv_b   = (const float*)d_in[4];
  const float* out_w   = (const float*)d_in[5];
  const float* out_b   = (const float*)d_in[6];
  const float* rb_w1   = (const float*)d_in[7];
  const float* rb_b1   = (const float*)d_in[8];
  const float* rb_w2   = (const float*)d_in[9];
  const float* rb_b2   = (const float*)d_in[10];
  const float* gate_w1 = (const float*)d_in[11];
  const float* gate_b1 = (const float*)d_in[12];
  const float* gate_w2 = (const float*)d_in[13];
  const float* gate_b2 = (const float*)d_in[14];
  const float* ff_w1   = (const float*)d_in[15];
  const float* ff_b1   = (const float*)d_in[16];
  const float* ff_w2   = (const float*)d_in[17];
  const float* ff_b2   = (const float*)d_in[18];
  const float* ln1_g   = (const float*)d_in[19];
  const float* ln1_b   = (const float*)d_in[20];
  const float* ln2_g   = (const float*)d_in[21];
  const float* ln2_b   = (const float*)d_in[22];

  char* w = (char*)d_ws;
  auto alloc = [&](size_t bytes) {
    char* p = w;
    w += (bytes + 255) & ~(size_t)255;
    return p;
  };
  U16* xn      = (U16*)alloc(1024 * 768 * 2);
  float* qkvb  = (float*)alloc((size_t)1024 * 2304 * 4);
  U16* qkv_wT  = (U16*)alloc(2304 * 768 * 2);
  U16* out_wT  = (U16*)alloc(768 * 768 * 2);
  U16* g1wT    = (U16*)alloc(768 * 768 * 2);
  U16* g2wT    = (U16*)alloc(768 * 768 * 2);
  U16* ff1wT   = (U16*)alloc(1536 * 768 * 2);
  U16* ff2wT   = (U16*)alloc(768 * 1536 * 2);
  U16* rb1wT   = (U16*)alloc(768 * 64 * 2);
  U16* rb2wL   = (U16*)alloc(24 * 64 * 8 * 2);
  float* biasB = (float*)alloc((size_t)4 * 12 * 256 * 256 * 4);
  float* ctx   = (float*)alloc(1024 * 768 * 4);
  U16* g1      = (U16*)alloc(1024 * 768 * 2);
  U16* cg      = (U16*)alloc(1024 * 768 * 2);
  float* x2    = (float*)alloc(1024 * 768 * 4);
  U16* y       = (U16*)alloc(1024 * 768 * 2);
  U16* f1      = (U16*)alloc(1024 * 1536 * 2);
  (void)ws_size; (void)in_sizes; (void)n_in; (void)out_size;

  // all weight prep in one launch
  prep_kernel<<<5856, 256, 0, stream>>>(qkv_w, out_w, gate_w1, gate_w2, ff_w1, ff_w2,
                                        rb_w1, rb_w2, qkv_wT, out_wT, g1wT, g2wT,
                                        ff1wT, ff2wT, rb1wT, rb2wL);

  // LN1 -> xn (bf16)
  ln_kernel<<<1024, 256, 0, stream>>>(x, ln1_g, ln1_b, xn);
  // qkv projection -> fp32
  gemm_bt<0, true><<<dim3(36, 16), 256, 0, stream>>>(xn, qkv_wT, qkv_b, nullptr, qkvb,
                                                     1024, 2304, 768);
  // relative bias MLP (fused, no-barrier)
  rb_kernel<<<1024, 256, 0, stream>>>(dist, rb1wT, rb_b1, rb2wL, rb_b2, biasB);
  // attention -> ctx fp32
  attn_kernel<<<dim3(16, 48), 256, 0, stream>>>(qkvb, biasB, mask, ctx);
  // gate MLP
  gemm_bt<1, false><<<dim3(12, 16), 256, 0, stream>>>(xn, g1wT, gate_b1, nullptr, g1,
                                                      1024, 768, 768);
  gemm_bt<3, false><<<dim3(12, 16), 256, 0, stream>>>(g1, g2wT, gate_b2, ctx, cg,
                                                      1024, 768, 768);
  // out projection + residual -> x2 (fp32)
  gemm_bt<4, true><<<dim3(12, 16), 256, 0, stream>>>(cg, out_wT, out_b, x, x2,
                                                     1024, 768, 768);
  // LN2 -> y (bf16)
  ln_kernel<<<1024, 256, 0, stream>>>(x2, ln2_g, ln2_b, y);
  // FF
  gemm_bt<2, false><<<dim3(24, 16), 256, 0, stream>>>(y, ff1wT, ff_b1, nullptr, f1,
                                                      1024, 1536, 768);
  gemm_bt<4, true><<<dim3(12, 16), 256, 0, stream>>>(f1, ff2wT, ff_b2, x2, (float*)d_out,
                                                     1024, 768, 1536);
}

// Round 6
// 353.759 us; speedup vs baseline: 1.7365x; 1.0448x over previous
//
#include <hip/hip_runtime.h>
#include <hip/hip_bf16.h>
#include <cmath>

#define U16 unsigned short

typedef __bf16 bf16x8_t __attribute__((ext_vector_type(8)));
typedef float f32x4_t __attribute__((ext_vector_type(4)));

union Frag { uint4 u4; unsigned u[4]; bf16x8_t b8; U16 s[8]; };

__device__ __forceinline__ float b2f(U16 u) {
  union { unsigned int i; float f; } x; x.i = ((unsigned int)u) << 16; return x.f;
}
__device__ __forceinline__ U16 f2b(float f) {
  union { float f; unsigned int i; } x; x.f = f;
  unsigned int r = x.i + 0x7FFFu + ((x.i >> 16) & 1u);
  return (U16)(r >> 16);
}
// pack two fp32 -> bf16x2 via v_cvt_pk_bf16_f32 (single instruction on gfx950, RNE)
__device__ __forceinline__ unsigned cvt_pk_bf16(float a, float b) {
  union { __hip_bfloat162 h2; unsigned u; } x;
  x.h2 = __float22bfloat162_rn(make_float2(a, b));
  return x.u;  // a = low half, b = high half
}
// pack two fp32 -> bf16x2, round-half-up (3 VALU ops) — used on one-time paths
__device__ __forceinline__ unsigned pack2bf_fast(float a, float b) {
  union { float f; unsigned u; } xa, xb; xa.f = a; xb.f = b;
  return __builtin_amdgcn_perm(xb.u + 0x8000u, xa.u + 0x8000u, 0x07060302);
}
__device__ __forceinline__ float fast_silu(float z) {
  return z * __builtin_amdgcn_rcpf(1.f + __expf(-z));
}

// ---------------- merged weight-prep kernel ----------------
// blocks [0,5808): 32x32 transpose tiles fp32->bf16 for 7 weights
// blocks [5808,5856): rb_w2 chunking
__global__ __launch_bounds__(256) void prep_kernel(
    const float* __restrict__ qkv_w, const float* __restrict__ out_w,
    const float* __restrict__ g1w, const float* __restrict__ g2w,
    const float* __restrict__ ff1w, const float* __restrict__ ff2w,
    const float* __restrict__ rb1w, const float* __restrict__ rb2w,
    U16* __restrict__ qkv_wT, U16* __restrict__ out_wT, U16* __restrict__ g1wT,
    U16* __restrict__ g2wT, U16* __restrict__ ff1wT, U16* __restrict__ ff2wT,
    U16* __restrict__ rb1wT, U16* __restrict__ rb2wL) {
  int bid = blockIdx.x;
  if (bid >= 5808) {  // rb_w2 [768,12] -> w2L[pp][lane][8]
    int idx = (bid - 5808) * 256 + threadIdx.x;
    int j = idx & 7, lane = (idx >> 3) & 63, pp = idx >> 9;
    int row = lane & 15, col = pp * 32 + ((lane >> 4) << 3) + j;
    rb2wL[idx] = (row < 12) ? f2b(rb2w[col * 12 + row]) : (U16)0;
    return;
  }
  const float* in; U16* out; int R, C, base;
  if (bid < 1728)      { in = qkv_w; out = qkv_wT; R = 768;  C = 2304; base = 0; }
  else if (bid < 2304) { in = out_w; out = out_wT; R = 768;  C = 768;  base = 1728; }
  else if (bid < 2880) { in = g1w;   out = g1wT;   R = 768;  C = 768;  base = 2304; }
  else if (bid < 3456) { in = g2w;   out = g2wT;   R = 768;  C = 768;  base = 2880; }
  else if (bid < 4608) { in = ff1w;  out = ff1wT;  R = 768;  C = 1536; base = 3456; }
  else if (bid < 5760) { in = ff2w;  out = ff2wT;  R = 1536; C = 768;  base = 4608; }
  else                 { in = rb1w;  out = rb1wT;  R = 64;   C = 768;  base = 5760; }
  int bx = bid - base, tilesx = C / 32;
  int c0 = (bx % tilesx) * 32, r0 = (bx / tilesx) * 32;
  __shared__ float tile[32][33];
  int tx = threadIdx.x & 31, ty = threadIdx.x >> 5;
#pragma unroll
  for (int yy = 0; yy < 4; ++yy)
    tile[ty + yy * 8][tx] = in[(size_t)(r0 + ty + yy * 8) * C + c0 + tx];
  __syncthreads();
#pragma unroll
  for (int yy = 0; yy < 4; ++yy)
    out[(size_t)(c0 + ty + yy * 8) * R + r0 + tx] = f2b(tile[tx][ty + yy * 8]);
}

// ---------------- K transpose: qkvb K-part -> kT[b,h,d,n] fp32 ----------------
__global__ __launch_bounds__(256) void kt_kernel(const float* __restrict__ qkvb,
                                                 float* __restrict__ kT) {
  int bid = blockIdx.x;
  int bh = bid >> 4, tile = bid & 15;
  int b = bh / 12, h = bh % 12;
  int n0 = (tile & 7) * 32, d0 = (tile >> 3) * 32;
  __shared__ float t[32][33];
  int tx = threadIdx.x & 31, ty = threadIdx.x >> 5;
#pragma unroll
  for (int yy = 0; yy < 4; ++yy)
    t[ty + yy * 8][tx] =
        qkvb[(size_t)(b * 256 + n0 + ty + yy * 8) * 2304 + 768 + h * 64 + d0 + tx];
  __syncthreads();
#pragma unroll
  for (int yy = 0; yy < 4; ++yy)
    kT[(size_t)bh * 16384 + (size_t)(d0 + ty + yy * 8) * 256 + n0 + tx] = t[tx][ty + yy * 8];
}

// ---------------- layernorm over D=768 (fp32 in, bf16 out), one block per row ----------------
__global__ __launch_bounds__(256) void ln_kernel(const float* __restrict__ X,
                                                 const float* __restrict__ gam,
                                                 const float* __restrict__ bet,
                                                 U16* __restrict__ Y) {
  int row = blockIdx.x, tid = threadIdx.x;
  __shared__ float r1[256], r2[256];
  float v[3];
#pragma unroll
  for (int j = 0; j < 3; ++j) v[j] = X[(size_t)row * 768 + tid + j * 256];
  r1[tid] = v[0] + v[1] + v[2];
  r2[tid] = v[0] * v[0] + v[1] * v[1] + v[2] * v[2];
  __syncthreads();
  for (int s = 128; s > 0; s >>= 1) {
    if (tid < s) { r1[tid] += r1[tid + s]; r2[tid] += r2[tid + s]; }
    __syncthreads();
  }
  float mean = r1[0] * (1.f / 768.f);
  float var = r2[0] * (1.f / 768.f) - mean * mean;
  float rstd = rsqrtf(var + 1e-5f);
#pragma unroll
  for (int j = 0; j < 3; ++j) {
    int c = tid + j * 256;
    Y[(size_t)row * 768 + c] = f2b((v[j] - mean) * rstd * gam[c] + bet[c]);
  }
}

// ---------------- generic bf16-MFMA GEMM: C = epi(A[M,K] @ B + bias) ----------------
// 64x64 tile per block, BK=32, 4 waves (2x2 of 32x32).
// EPI: 0=none 1=silu 2=gelu(exact) 3=sigmoid(z)*other 4=z+other
#define LDP 40
template <int EPI, bool OUTF32>
__global__ __launch_bounds__(256) void gemm_bt(const U16* __restrict__ A,
                                               const U16* __restrict__ BT,
                                               const float* __restrict__ bias,
                                               const float* __restrict__ other,
                                               void* __restrict__ Cout,
                                               int M, int N, int K) {
  __shared__ __align__(16) U16 sA[64 * LDP];
  __shared__ __align__(16) U16 sB[64 * LDP];
  int tid = threadIdx.x;
  int lane = tid & 63, wave = tid >> 6;
  int m0 = blockIdx.y * 64, n0 = blockIdx.x * 64;
  int wm = (wave >> 1) * 32, wn = (wave & 1) * 32;
  int lm = lane & 15, lq = lane >> 4;
  int srow = tid >> 2;
  int scol = (tid & 3) * 8;
  f32x4_t acc[2][2] = {};
  for (int k0 = 0; k0 < K; k0 += 32) {
    __syncthreads();
    uint4 a0 = *(const uint4*)(A + (size_t)(m0 + srow) * K + k0 + scol);
    uint4 b0 = *(const uint4*)(BT + (size_t)(n0 + srow) * K + k0 + scol);
    *(uint4*)&sA[srow * LDP + scol] = a0;
    *(uint4*)&sB[srow * LDP + scol] = b0;
    __syncthreads();
    Frag af[2], bf[2];
#pragma unroll
    for (int mt = 0; mt < 2; ++mt)
      af[mt].u4 = *(const uint4*)&sA[(wm + mt * 16 + lm) * LDP + lq * 8];
#pragma unroll
    for (int nt = 0; nt < 2; ++nt)
      bf[nt].u4 = *(const uint4*)&sB[(wn + nt * 16 + lm) * LDP + lq * 8];
#pragma unroll
    for (int mt = 0; mt < 2; ++mt)
#pragma unroll
      for (int nt = 0; nt < 2; ++nt)
        acc[mt][nt] = __builtin_amdgcn_mfma_f32_16x16x32_bf16(af[mt].b8, bf[nt].b8,
                                                              acc[mt][nt], 0, 0, 0);
  }
#pragma unroll
  for (int nt = 0; nt < 2; ++nt) {
    int gc = n0 + wn + nt * 16 + lm;
    float bz = bias[gc];
#pragma unroll
    for (int mt = 0; mt < 2; ++mt) {
#pragma unroll
      for (int r = 0; r < 4; ++r) {
        int gr = m0 + wm + mt * 16 + lq * 4 + r;
        size_t idx = (size_t)gr * N + gc;
        float z = acc[mt][nt][r] + bz;
        float o;
        if (EPI == 0) o = z;
        else if (EPI == 1) o = fast_silu(z);
        else if (EPI == 2) o = 0.5f * z * (1.f + erff(z * 0.70710678118f));
        else if (EPI == 3) o = other[idx] * __builtin_amdgcn_rcpf(1.f + __expf(-z));
        else o = z + other[idx];
        if (OUTF32) ((float*)Cout)[idx] = o;
        else ((U16*)Cout)[idx] = f2b(o);
      }
    }
  }
}

// ---------------- fused relative-bias MLP v5 ----------------
// bias[b,h,i,j] = silu(dist[(b,i,j),:64] @ w1 + b1) @ w2 + b2
// Transposed layer-1 (A=w1 permuted rows, B=dist) so silu lands in layer-2 A-frag layout
// (mapping verified R3-R5). v5: b1 folded into layer-1 MFMA C-init, b2 folded into
// layer-2 accumulator init, single-instruction v_cvt_pk_bf16_f32 packs.
__global__ __launch_bounds__(256) void rb_kernel(const float* __restrict__ dist,  // [262144,64]
                                                 const U16* __restrict__ w1T,     // [768,64] bf16
                                                 const float* __restrict__ b1,    // [768]
                                                 const U16* __restrict__ w2L,     // [24*64*8] bf16
                                                 const float* __restrict__ b2,    // [12]
                                                 float* __restrict__ biasOut) {   // [4,12,256,256]
  int tid = threadIdx.x;
  int lane = tid & 63, wave = tid >> 6;
  int lm = lane & 15, lq = lane >> 4;
  int r0 = blockIdx.x * 256;
  float hb = (lm < 12) ? b2[lm] : 0.f;
  // dist B-fragments: 4 row-groups x 2 k-chunks, loaded once (reused all 24 pp iters)
  Frag bd[4][2];
#pragma unroll
  for (int g = 0; g < 4; ++g) {
    const float* ap = dist + (size_t)(r0 + (wave * 4 + g) * 16 + lm) * 64 + lq * 8;
    float4 v0 = ((const float4*)ap)[0];
    float4 v1 = ((const float4*)ap)[1];
    float4 v2 = ((const float4*)(ap + 32))[0];
    float4 v3 = ((const float4*)(ap + 32))[1];
    bd[g][0].u[0] = cvt_pk_bf16(v0.x, v0.y); bd[g][0].u[1] = cvt_pk_bf16(v0.z, v0.w);
    bd[g][0].u[2] = cvt_pk_bf16(v1.x, v1.y); bd[g][0].u[3] = cvt_pk_bf16(v1.z, v1.w);
    bd[g][1].u[0] = cvt_pk_bf16(v2.x, v2.y); bd[g][1].u[1] = cvt_pk_bf16(v2.z, v2.w);
    bd[g][1].u[2] = cvt_pk_bf16(v3.x, v3.y); bd[g][1].u[3] = cvt_pk_bf16(v3.z, v3.w);
  }
  // per-lane weight pointers (advance per pp)
  const U16* w1p0 = w1T + (size_t)(((lm >> 2) << 3) + (lm & 3)) * 64 + lq * 8;  // tt=0
  const U16* w1p1 = w1p0 + 4 * 64;                                              // tt=1
  const U16* w2p = w2L + lane * 8;
  const float* b1p = b1 + lq * 8;
  f32x4_t bacc[4] = {{hb, hb, hb, hb}, {hb, hb, hb, hb}, {hb, hb, hb, hb}, {hb, hb, hb, hb}};
  for (int pp = 0; pp < 24; ++pp) {
    Frag w00, w01, w10, w11, wb;
    w00.u4 = *(const uint4*)w1p0;
    w01.u4 = *(const uint4*)(w1p0 + 32);
    w10.u4 = *(const uint4*)w1p1;
    w11.u4 = *(const uint4*)(w1p1 + 32);
    wb.u4 = *(const uint4*)w2p;
    float4 bb0 = *(const float4*)b1p;
    float4 bb1 = *(const float4*)(b1p + 4);
    f32x4_t cz0 = {bb0.x, bb0.y, bb0.z, bb0.w};
    f32x4_t cz1 = {bb1.x, bb1.y, bb1.z, bb1.w};
#pragma unroll
    for (int g = 0; g < 4; ++g) {
      f32x4_t z0 = cz0, z1 = cz1;  // bias pre-loaded as MFMA C operand
      z0 = __builtin_amdgcn_mfma_f32_16x16x32_bf16(w00.b8, bd[g][0].b8, z0, 0, 0, 0);
      z0 = __builtin_amdgcn_mfma_f32_16x16x32_bf16(w01.b8, bd[g][1].b8, z0, 0, 0, 0);
      z1 = __builtin_amdgcn_mfma_f32_16x16x32_bf16(w10.b8, bd[g][0].b8, z1, 0, 0, 0);
      z1 = __builtin_amdgcn_mfma_f32_16x16x32_bf16(w11.b8, bd[g][1].b8, z1, 0, 0, 0);
      float s0 = fast_silu(z0[0]), s1 = fast_silu(z0[1]);
      float s2 = fast_silu(z0[2]), s3 = fast_silu(z0[3]);
      float t0 = fast_silu(z1[0]), t1 = fast_silu(z1[1]);
      float t2 = fast_silu(z1[2]), t3 = fast_silu(z1[3]);
      Frag af2;
      af2.u[0] = cvt_pk_bf16(s0, s1); af2.u[1] = cvt_pk_bf16(s2, s3);
      af2.u[2] = cvt_pk_bf16(t0, t1); af2.u[3] = cvt_pk_bf16(t2, t3);
      bacc[g] = __builtin_amdgcn_mfma_f32_16x16x32_bf16(af2.b8, wb.b8, bacc[g], 0, 0, 0);
    }
    w1p0 += 32 * 64; w1p1 += 32 * 64; w2p += 64 * 8; b1p += 32;
  }
  if (lm < 12) {
#pragma unroll
    for (int g = 0; g < 4; ++g) {
#pragma unroll
      for (int r = 0; r < 4; ++r) {
        int gr = r0 + (wave * 4 + g) * 16 + lq * 4 + r;  // flat (b,i,j)
        int b = gr >> 16, rem = gr & 65535, i = rem >> 8, j = rem & 255;
        biasOut[(((size_t)b * 12 + lm) * 256 + i) * 256 + j] = bacc[g][r];
      }
    }
  }
}

// ---------------- attention v3: coalesced K via kT; barrier-free ----------------
// grid (16, 48): blockIdx.x = 16-query chunk, blockIdx.y = b*12+h. 4 waves/block.
// sQ rows / sP strips are wave-private (loaded and read by the same wave) -> no barriers.
__global__ __launch_bounds__(256) void attn_kernel(const float* __restrict__ qkv,   // [1024,2304]
                                                   const float* __restrict__ kT,    // [48,64,256]
                                                   const float* __restrict__ biasB, // [4,12,256,256]
                                                   const int* __restrict__ mask,    // [4,256,256]
                                                   float* __restrict__ ctx) {       // [1024,768]
  int tid = threadIdx.x, lane = tid & 63, w = tid >> 6;
  int bh = blockIdx.y, b = bh / 12, h = bh % 12;
  int i0 = blockIdx.x * 16;
  __shared__ float sQ[16][66];
  __shared__ float sP[4][4][256];
  {
    int r = tid >> 4, c = (tid & 15) * 4;
    *(float4*)&sQ[r][c] =
        *(const float4*)&qkv[((size_t)(b * 256 + i0 + r)) * 2304 + h * 64 + c];
  }
  int iw = i0 + w * 4;
  float lacc[4][4] = {};  // [qi][jc]
  const float* kp = kT + (size_t)bh * 16384 + lane;
#pragma unroll 4
  for (int d = 0; d < 64; d += 2) {
    float k00 = kp[d * 256], k01 = kp[d * 256 + 64];
    float k02 = kp[d * 256 + 128], k03 = kp[d * 256 + 192];
    float k10 = kp[d * 256 + 256], k11 = kp[d * 256 + 320];
    float k12 = kp[d * 256 + 384], k13 = kp[d * 256 + 448];
#pragma unroll
    for (int qi = 0; qi < 4; ++qi) {
      float2 q2 = *(const float2*)&sQ[w * 4 + qi][d];
      lacc[qi][0] += q2.x * k00 + q2.y * k10;
      lacc[qi][1] += q2.x * k01 + q2.y * k11;
      lacc[qi][2] += q2.x * k02 + q2.y * k12;
      lacc[qi][3] += q2.x * k03 + q2.y * k13;
    }
  }
#pragma unroll
  for (int qi = 0; qi < 4; ++qi) {
    int gi = iw + qi;
    const float* brow = biasB + (((size_t)b * 12 + h) * 256 + gi) * 256;
    const int* mrow = mask + ((size_t)b * 256 + gi) * 256;
    float lg[4];
#pragma unroll
    for (int jc = 0; jc < 4; ++jc) {
      float lv = lacc[qi][jc] * 0.125f + brow[jc * 64 + lane];
      lg[jc] = mrow[jc * 64 + lane] ? lv : -1e30f;
    }
    float mx = fmaxf(fmaxf(lg[0], lg[1]), fmaxf(lg[2], lg[3]));
#pragma unroll
    for (int m = 32; m > 0; m >>= 1) mx = fmaxf(mx, __shfl_xor(mx, m));
    float e[4], sum = 0.f;
#pragma unroll
    for (int jc = 0; jc < 4; ++jc) { e[jc] = __expf(lg[jc] - mx); sum += e[jc]; }
#pragma unroll
    for (int m = 32; m > 0; m >>= 1) sum += __shfl_xor(sum, m);
    float inv = __builtin_amdgcn_rcpf(sum);
#pragma unroll
    for (int jc = 0; jc < 4; ++jc) sP[w][qi][jc * 64 + lane] = e[jc] * inv;
  }
  float ca[4] = {0.f, 0.f, 0.f, 0.f};
  const float* vcol = qkv + (size_t)b * 256 * 2304 + 1536 + h * 64 + lane;
#pragma unroll 2
  for (int j4 = 0; j4 < 256; j4 += 4) {
    float4 p0 = *(const float4*)&sP[w][0][j4];
    float4 p1 = *(const float4*)&sP[w][1][j4];
    float4 p2 = *(const float4*)&sP[w][2][j4];
    float4 p3 = *(const float4*)&sP[w][3][j4];
    const float* pp0 = (const float*)&p0;
    const float* pp1 = (const float*)&p1;
    const float* pp2 = (const float*)&p2;
    const float* pp3 = (const float*)&p3;
#pragma unroll
    for (int jj = 0; jj < 4; ++jj) {
      float v = vcol[(size_t)(j4 + jj) * 2304];
      ca[0] += pp0[jj] * v;
      ca[1] += pp1[jj] * v;
      ca[2] += pp2[jj] * v;
      ca[3] += pp3[jj] * v;
    }
  }
#pragma unroll
  for (int qi = 0; qi < 4; ++qi)
    ctx[((size_t)(b * 256 + iw + qi)) * 768 + h * 64 + lane] = ca[qi];
}

// ---------------- launcher ----------------
extern "C" void kernel_launch(void* const* d_in, const int* in_sizes, int n_in,
                              void* d_out, int out_size, void* d_ws, size_t ws_size,
                              hipStream_t stream) {
  const float* x       = (const float*)d_in[0];
  const float* dist    = (const float*)d_in[1];
  const int* mask      = (const int*)d_in[2];
  const float* qkv_w   = (const float*)d_in[3];
  const float* qkv_b   = (const float*)d_in[4];
  const float* out_w   = (const float*)d_in[5];
  const float* out_b   = (const float*)d_in[6];
  const float* rb_w1   = (const float*)d_in[7];
  const float* rb_b1   = (const float*)d_in[8];
  const float* rb_w2   = (const float*)d_in[9];
  const float* rb_b2   = (const float*)d_in[10];
  const float* gate_w1 = (const float*)d_in[11];
  const float* gate_b1 = (const float*)d_in[12];
  const float* gate_w2 = (const float*)d_in[13];
  const float* gate_b2 = (const float*)d_in[14];
  const float* ff_w1   = (const float*)d_in[15];
  const float* ff_b1   = (const float*)d_in[16];
  const float* ff_w2   = (const float*)d_in[17];
  const float* ff_b2   = (const float*)d_in[18];
  const float* ln1_g   = (const float*)d_in[19];
  const float* ln1_b   = (const float*)d_in[20];
  const float* ln2_g   = (const float*)d_in[21];
  const float* ln2_b   = (const float*)d_in[22];

  char* w = (char*)d_ws;
  auto alloc = [&](size_t bytes) {
    char* p = w;
    w += (bytes + 255) & ~(size_t)255;
    return p;
  };
  U16* xn      = (U16*)alloc(1024 * 768 * 2);
  float* qkvb  = (float*)alloc((size_t)1024 * 2304 * 4);
  float* kT    = (float*)alloc((size_t)48 * 64 * 256 * 4);
  U16* qkv_wT  = (U16*)alloc(2304 * 768 * 2);
  U16* out_wT  = (U16*)alloc(768 * 768 * 2);
  U16* g1wT    = (U16*)alloc(768 * 768 * 2);
  U16* g2wT    = (U16*)alloc(768 * 768 * 2);
  U16* ff1wT   = (U16*)alloc(1536 * 768 * 2);
  U16* ff2wT   = (U16*)alloc(768 * 1536 * 2);
  U16* rb1wT   = (U16*)alloc(768 * 64 * 2);
  U16* rb2wL   = (U16*)alloc(24 * 64 * 8 * 2);
  float* biasB = (float*)alloc((size_t)4 * 12 * 256 * 256 * 4);
  float* ctx   = (float*)alloc(1024 * 768 * 4);
  U16* g1      = (U16*)alloc(1024 * 768 * 2);
  U16* cg      = (U16*)alloc(1024 * 768 * 2);
  float* x2    = (float*)alloc(1024 * 768 * 4);
  U16* y       = (U16*)alloc(1024 * 768 * 2);
  U16* f1      = (U16*)alloc(1024 * 1536 * 2);
  (void)ws_size; (void)in_sizes; (void)n_in; (void)out_size;

  // all weight prep in one launch
  prep_kernel<<<5856, 256, 0, stream>>>(qkv_w, out_w, gate_w1, gate_w2, ff_w1, ff_w2,
                                        rb_w1, rb_w2, qkv_wT, out_wT, g1wT, g2wT,
                                        ff1wT, ff2wT, rb1wT, rb2wL);

  // LN1 -> xn (bf16)
  ln_kernel<<<1024, 256, 0, stream>>>(x, ln1_g, ln1_b, xn);
  // qkv projection -> fp32
  gemm_bt<0, true><<<dim3(36, 16), 256, 0, stream>>>(xn, qkv_wT, qkv_b, nullptr, qkvb,
                                                     1024, 2304, 768);
  // K transpose for coalesced attention reads
  kt_kernel<<<768, 256, 0, stream>>>(qkvb, kT);
  // relative bias MLP (fused, no-barrier)
  rb_kernel<<<1024, 256, 0, stream>>>(dist, rb1wT, rb_b1, rb2wL, rb_b2, biasB);
  // attention -> ctx fp32
  attn_kernel<<<dim3(16, 48), 256, 0, stream>>>(qkvb, kT, biasB, mask, ctx);
  // gate MLP
  gemm_bt<1, false><<<dim3(12, 16), 256, 0, stream>>>(xn, g1wT, gate_b1, nullptr, g1,
                                                      1024, 768, 768);
  gemm_bt<3, false><<<dim3(12, 16), 256, 0, stream>>>(g1, g2wT, gate_b2, ctx, cg,
                                                      1024, 768, 768);
  // out projection + residual -> x2 (fp32)
  gemm_bt<4, true><<<dim3(12, 16), 256, 0, stream>>>(cg, out_wT, out_b, x, x2,
                                                     1024, 768, 768);
  // LN2 -> y (bf16)
  ln_kernel<<<1024, 256, 0, stream>>>(x2, ln2_g, ln2_b, y);
  // FF
  gemm_bt<2, false><<<dim3(24, 16), 256, 0, stream>>>(y, ff1wT, ff_b1, nullptr, f1,
                                                      1024, 1536, 768);
  gemm_bt<4, true><<<dim3(12, 16), 256, 0, stream>>>(f1, ff2wT, ff_b2, x2, (float*)d_out,
                                                     1024, 768, 1536);
}

// Round 7
// 327.576 us; speedup vs baseline: 1.8753x; 1.0799x over previous
//
#include <hip/hip_runtime.h>
#include <hip/hip_bf16.h>
#include <cmath>

#define U16 unsigned short

typedef __bf16 bf16x8_t __attribute__((ext_vector_type(8)));
typedef float f32x4_t __attribute__((ext_vector_type(4)));

union Frag { uint4 u4; unsigned u[4]; bf16x8_t b8; U16 s[8]; };

__device__ __forceinline__ float b2f(U16 u) {
  union { unsigned int i; float f; } x; x.i = ((unsigned int)u) << 16; return x.f;
}
__device__ __forceinline__ U16 f2b(float f) {
  union { float f; unsigned int i; } x; x.f = f;
  unsigned int r = x.i + 0x7FFFu + ((x.i >> 16) & 1u);
  return (U16)(r >> 16);
}
// pack two fp32 -> bf16x2 via v_cvt_pk_bf16_f32 (single instruction on gfx950, RNE)
__device__ __forceinline__ unsigned cvt_pk_bf16(float a, float b) {
  union { __hip_bfloat162 h2; unsigned u; } x;
  x.h2 = __float22bfloat162_rn(make_float2(a, b));
  return x.u;  // a = low half, b = high half
}
__device__ __forceinline__ float fast_silu(float z) {
  return z * __builtin_amdgcn_rcpf(1.f + __expf(-z));
}
// async global->LDS, 16B per lane (HW: wave-uniform base + lane*16; lane order must
// match the lds pointer's lane component — verified pattern from learn_hip m97)
__device__ __forceinline__ void load_lds16(const U16* g, U16* l) {
  __builtin_amdgcn_global_load_lds((const __attribute__((address_space(1))) void*)g,
                                   (__attribute__((address_space(3))) void*)l, 16, 0, 0);
}

// ---------------- merged weight-prep kernel ----------------
// [0,5808): 32x32 transpose tiles fp32->bf16; [5808,5856): rb_w2 chunk; [5856,5868): bias concat
__global__ __launch_bounds__(256) void prep_kernel(
    const float* __restrict__ qkv_w, const float* __restrict__ out_w,
    const float* __restrict__ g1w, const float* __restrict__ g2w,
    const float* __restrict__ ff1w, const float* __restrict__ ff2w,
    const float* __restrict__ rb1w, const float* __restrict__ rb2w,
    const float* __restrict__ qkv_b, const float* __restrict__ gate_b1,
    U16* __restrict__ qkv_wT, U16* __restrict__ out_wT, U16* __restrict__ g1wT,
    U16* __restrict__ g2wT, U16* __restrict__ ff1wT, U16* __restrict__ ff2wT,
    U16* __restrict__ rb1wT, U16* __restrict__ rb2wL, float* __restrict__ qg_bias) {
  int bid = blockIdx.x;
  if (bid >= 5856) {  // qkv_b ++ gate_b1 -> qg_bias[3072]
    int idx = (bid - 5856) * 256 + threadIdx.x;
    qg_bias[idx] = (idx < 2304) ? qkv_b[idx] : gate_b1[idx - 2304];
    return;
  }
  if (bid >= 5808) {  // rb_w2 [768,12] -> w2L[pp][lane][8]
    int idx = (bid - 5808) * 256 + threadIdx.x;
    int j = idx & 7, lane = (idx >> 3) & 63, pp = idx >> 9;
    int row = lane & 15, col = pp * 32 + ((lane >> 4) << 3) + j;
    rb2wL[idx] = (row < 12) ? f2b(rb2w[col * 12 + row]) : (U16)0;
    return;
  }
  const float* in; U16* out; int R, C, base;
  if (bid < 1728)      { in = qkv_w; out = qkv_wT; R = 768;  C = 2304; base = 0; }
  else if (bid < 2304) { in = out_w; out = out_wT; R = 768;  C = 768;  base = 1728; }
  else if (bid < 2880) { in = g1w;   out = g1wT;   R = 768;  C = 768;  base = 2304; }
  else if (bid < 3456) { in = g2w;   out = g2wT;   R = 768;  C = 768;  base = 2880; }
  else if (bid < 4608) { in = ff1w;  out = ff1wT;  R = 768;  C = 1536; base = 3456; }
  else if (bid < 5760) { in = ff2w;  out = ff2wT;  R = 1536; C = 768;  base = 4608; }
  else                 { in = rb1w;  out = rb1wT;  R = 64;   C = 768;  base = 5760; }
  int bx = bid - base, tilesx = C / 32;
  int c0 = (bx % tilesx) * 32, r0 = (bx / tilesx) * 32;
  __shared__ float tile[32][33];
  int tx = threadIdx.x & 31, ty = threadIdx.x >> 5;
#pragma unroll
  for (int yy = 0; yy < 4; ++yy)
    tile[ty + yy * 8][tx] = in[(size_t)(r0 + ty + yy * 8) * C + c0 + tx];
  __syncthreads();
#pragma unroll
  for (int yy = 0; yy < 4; ++yy)
    out[(size_t)(c0 + ty + yy * 8) * R + r0 + tx] = f2b(tile[tx][ty + yy * 8]);
}

// ---------------- K transpose: qkvb K-part -> kT[b,h,d,n] fp32 ----------------
__global__ __launch_bounds__(256) void kt_kernel(const float* __restrict__ qkvb,
                                                 float* __restrict__ kT) {
  int bid = blockIdx.x;
  int bh = bid >> 4, tile = bid & 15;
  int b = bh / 12, h = bh % 12;
  int n0 = (tile & 7) * 32, d0 = (tile >> 3) * 32;
  __shared__ float t[32][33];
  int tx = threadIdx.x & 31, ty = threadIdx.x >> 5;
#pragma unroll
  for (int yy = 0; yy < 4; ++yy)
    t[ty + yy * 8][tx] =
        qkvb[(size_t)(b * 256 + n0 + ty + yy * 8) * 2304 + 768 + h * 64 + d0 + tx];
  __syncthreads();
#pragma unroll
  for (int yy = 0; yy < 4; ++yy)
    kT[(size_t)bh * 16384 + (size_t)(d0 + ty + yy * 8) * 256 + n0 + tx] = t[tx][ty + yy * 8];
}

// ---------------- layernorm over D=768: shfl-reduce, single barrier ----------------
__global__ __launch_bounds__(256) void ln_kernel(const float* __restrict__ X,
                                                 const float* __restrict__ gam,
                                                 const float* __restrict__ bet,
                                                 U16* __restrict__ Y) {
  int row = blockIdx.x, tid = threadIdx.x, lane = tid & 63, wave = tid >> 6;
  __shared__ float p1[4], p2[4];
  float v[3];
#pragma unroll
  for (int j = 0; j < 3; ++j) v[j] = X[(size_t)row * 768 + tid + j * 256];
  float s1 = v[0] + v[1] + v[2];
  float s2 = v[0] * v[0] + v[1] * v[1] + v[2] * v[2];
#pragma unroll
  for (int m = 32; m > 0; m >>= 1) {
    s1 += __shfl_xor(s1, m);
    s2 += __shfl_xor(s2, m);
  }
  if (lane == 0) { p1[wave] = s1; p2[wave] = s2; }
  __syncthreads();
  float t1 = p1[0] + p1[1] + p1[2] + p1[3];
  float t2 = p2[0] + p2[1] + p2[2] + p2[3];
  float mean = t1 * (1.f / 768.f);
  float var = t2 * (1.f / 768.f) - mean * mean;
  float rstd = rsqrtf(var + 1e-5f);
#pragma unroll
  for (int j = 0; j < 3; ++j) {
    int c = tid + j * 256;
    Y[(size_t)row * 768 + c] = f2b((v[j] - mean) * rstd * gam[c] + bet[c]);
  }
}

// ---------------- generic bf16-MFMA GEMM v2: async LDS staging ----------------
// 64x64 tile, BK=32, 4 waves (2x2 of 32x32). Unpadded LDS (stage order == lane order,
// required by global_load_lds wave-uniform+lane*16 semantics; <=2-way conflicts, free).
// EPI: 0=none 1=silu 2=gelu(exact) 3=sigmoid(z)*other 4=z+other 5=fused qkv/gate1
template <int EPI, bool OUTF32>
__global__ __launch_bounds__(256) void gemm_bt(const U16* __restrict__ A,
                                               const U16* __restrict__ BT,
                                               const float* __restrict__ bias,
                                               const float* __restrict__ other,
                                               void* __restrict__ Cout,
                                               float* __restrict__ Cout2,
                                               int M, int N, int K) {
  __shared__ __align__(16) U16 sA[64 * 32];
  __shared__ __align__(16) U16 sB[64 * 32];
  int tid = threadIdx.x;
  int lane = tid & 63, wave = tid >> 6;
  int m0 = blockIdx.y * 64, n0 = blockIdx.x * 64;
  int wm = (wave >> 1) * 32, wn = (wave & 1) * 32;
  int lm = lane & 15, lq = lane >> 4;
  int srow = tid >> 2, scol = (tid & 3) * 8;
  const U16* ag = A + (size_t)(m0 + srow) * K + scol;
  const U16* bg = BT + (size_t)(n0 + srow) * K + scol;
  U16* lA = &sA[tid * 8];
  U16* lB = &sB[tid * 8];
  f32x4_t acc[2][2] = {};
  for (int k0 = 0; k0 < K; k0 += 32) {
    __syncthreads();
    load_lds16(ag + k0, lA);
    load_lds16(bg + k0, lB);
    __syncthreads();  // barrier drains vmcnt -> LDS contents visible
    Frag af[2], bf[2];
#pragma unroll
    for (int mt = 0; mt < 2; ++mt)
      af[mt].u4 = *(const uint4*)&sA[(wm + mt * 16 + lm) * 32 + lq * 8];
#pragma unroll
    for (int nt = 0; nt < 2; ++nt)
      bf[nt].u4 = *(const uint4*)&sB[(wn + nt * 16 + lm) * 32 + lq * 8];
#pragma unroll
    for (int mt = 0; mt < 2; ++mt)
#pragma unroll
      for (int nt = 0; nt < 2; ++nt)
        acc[mt][nt] = __builtin_amdgcn_mfma_f32_16x16x32_bf16(af[mt].b8, bf[nt].b8,
                                                              acc[mt][nt], 0, 0, 0);
  }
#pragma unroll
  for (int nt = 0; nt < 2; ++nt) {
    int gc = n0 + wn + nt * 16 + lm;
    float bz = bias[gc];
#pragma unroll
    for (int mt = 0; mt < 2; ++mt) {
#pragma unroll
      for (int r = 0; r < 4; ++r) {
        int gr = m0 + wm + mt * 16 + lq * 4 + r;
        float z = acc[mt][nt][r] + bz;
        if (EPI == 5) {
          // fused qkv (fp32, cols<2304) + gate1 silu (bf16, cols>=2304)
          if (gc < 2304) Cout2[(size_t)gr * 2304 + gc] = z;
          else ((U16*)Cout)[(size_t)gr * 768 + gc - 2304] = f2b(fast_silu(z));
          continue;
        }
        size_t idx = (size_t)gr * N + gc;
        float o;
        if (EPI == 0) o = z;
        else if (EPI == 1) o = fast_silu(z);
        else if (EPI == 2) o = 0.5f * z * (1.f + erff(z * 0.70710678118f));
        else if (EPI == 3) o = other[idx] * __builtin_amdgcn_rcpf(1.f + __expf(-z));
        else o = z + other[idx];
        if (OUTF32) ((float*)Cout)[idx] = o;
        else ((U16*)Cout)[idx] = f2b(o);
      }
    }
  }
}

// ---------------- fused relative-bias MLP v6: weight software-prefetch ----------------
// bias[b,h,i,j] = silu(dist[(b,i,j),:64] @ w1 + b1) @ w2 + b2
// Transposed layer-1 (A=w1 permuted rows, B=dist); silu lands in layer-2 A-frag layout
// (mapping verified R3-R6). v6: next pp's weights loaded before current pp's compute
// so the ~200cyc L2 hits overlap the silu chain.
__global__ __launch_bounds__(256) void rb_kernel(const float* __restrict__ dist,  // [262144,64]
                                                 const U16* __restrict__ w1T,     // [768,64] bf16
                                                 const float* __restrict__ b1,    // [768]
                                                 const U16* __restrict__ w2L,     // [24*64*8] bf16
                                                 const float* __restrict__ b2,    // [12]
                                                 float* __restrict__ biasOut) {   // [4,12,256,256]
  int tid = threadIdx.x;
  int lane = tid & 63, wave = tid >> 6;
  int lm = lane & 15, lq = lane >> 4;
  int r0 = blockIdx.x * 256;
  float hb = (lm < 12) ? b2[lm] : 0.f;
  Frag bd[4][2];
#pragma unroll
  for (int g = 0; g < 4; ++g) {
    const float* ap = dist + (size_t)(r0 + (wave * 4 + g) * 16 + lm) * 64 + lq * 8;
    float4 v0 = ((const float4*)ap)[0];
    float4 v1 = ((const float4*)ap)[1];
    float4 v2 = ((const float4*)(ap + 32))[0];
    float4 v3 = ((const float4*)(ap + 32))[1];
    bd[g][0].u[0] = cvt_pk_bf16(v0.x, v0.y); bd[g][0].u[1] = cvt_pk_bf16(v0.z, v0.w);
    bd[g][0].u[2] = cvt_pk_bf16(v1.x, v1.y); bd[g][0].u[3] = cvt_pk_bf16(v1.z, v1.w);
    bd[g][1].u[0] = cvt_pk_bf16(v2.x, v2.y); bd[g][1].u[1] = cvt_pk_bf16(v2.z, v2.w);
    bd[g][1].u[2] = cvt_pk_bf16(v3.x, v3.y); bd[g][1].u[3] = cvt_pk_bf16(v3.z, v3.w);
  }
  const U16* w1p0 = w1T + (size_t)(((lm >> 2) << 3) + (lm & 3)) * 64 + lq * 8;  // tt=0
  const U16* w1p1 = w1p0 + 4 * 64;                                              // tt=1
  const U16* w2p = w2L + lane * 8;
  const float* b1p = b1 + lq * 8;
  // current weights (pp=0)
  Frag cw00, cw01, cw10, cw11, cwb;
  cw00.u4 = *(const uint4*)w1p0;
  cw01.u4 = *(const uint4*)(w1p0 + 32);
  cw10.u4 = *(const uint4*)w1p1;
  cw11.u4 = *(const uint4*)(w1p1 + 32);
  cwb.u4 = *(const uint4*)w2p;
  float4 cb0 = *(const float4*)b1p;
  float4 cb1 = *(const float4*)(b1p + 4);
  f32x4_t bacc[4] = {{hb, hb, hb, hb}, {hb, hb, hb, hb}, {hb, hb, hb, hb}, {hb, hb, hb, hb}};
  for (int pp = 0; pp < 24; ++pp) {
    Frag nw00 = cw00, nw01 = cw01, nw10 = cw10, nw11 = cw11, nwb = cwb;
    float4 nb0 = cb0, nb1 = cb1;
    if (pp < 23) {  // prefetch next slice before consuming current
      w1p0 += 32 * 64; w1p1 += 32 * 64; w2p += 64 * 8; b1p += 32;
      nw00.u4 = *(const uint4*)w1p0;
      nw01.u4 = *(const uint4*)(w1p0 + 32);
      nw10.u4 = *(const uint4*)w1p1;
      nw11.u4 = *(const uint4*)(w1p1 + 32);
      nwb.u4 = *(const uint4*)w2p;
      nb0 = *(const float4*)b1p;
      nb1 = *(const float4*)(b1p + 4);
    }
    f32x4_t cz0 = {cb0.x, cb0.y, cb0.z, cb0.w};
    f32x4_t cz1 = {cb1.x, cb1.y, cb1.z, cb1.w};
#pragma unroll
    for (int g = 0; g < 4; ++g) {
      f32x4_t z0 = cz0, z1 = cz1;  // bias pre-loaded as MFMA C operand
      z0 = __builtin_amdgcn_mfma_f32_16x16x32_bf16(cw00.b8, bd[g][0].b8, z0, 0, 0, 0);
      z0 = __builtin_amdgcn_mfma_f32_16x16x32_bf16(cw01.b8, bd[g][1].b8, z0, 0, 0, 0);
      z1 = __builtin_amdgcn_mfma_f32_16x16x32_bf16(cw10.b8, bd[g][0].b8, z1, 0, 0, 0);
      z1 = __builtin_amdgcn_mfma_f32_16x16x32_bf16(cw11.b8, bd[g][1].b8, z1, 0, 0, 0);
      float s0 = fast_silu(z0[0]), s1 = fast_silu(z0[1]);
      float s2 = fast_silu(z0[2]), s3 = fast_silu(z0[3]);
      float t0 = fast_silu(z1[0]), t1 = fast_silu(z1[1]);
      float t2 = fast_silu(z1[2]), t3 = fast_silu(z1[3]);
      Frag af2;
      af2.u[0] = cvt_pk_bf16(s0, s1); af2.u[1] = cvt_pk_bf16(s2, s3);
      af2.u[2] = cvt_pk_bf16(t0, t1); af2.u[3] = cvt_pk_bf16(t2, t3);
      bacc[g] = __builtin_amdgcn_mfma_f32_16x16x32_bf16(af2.b8, cwb.b8, bacc[g], 0, 0, 0);
    }
    cw00 = nw00; cw01 = nw01; cw10 = nw10; cw11 = nw11; cwb = nwb;
    cb0 = nb0; cb1 = nb1;
  }
  if (lm < 12) {
#pragma unroll
    for (int g = 0; g < 4; ++g) {
#pragma unroll
      for (int r = 0; r < 4; ++r) {
        int gr = r0 + (wave * 4 + g) * 16 + lq * 4 + r;  // flat (b,i,j)
        int b = gr >> 16, rem = gr & 65535, i = rem >> 8, j = rem & 255;
        biasOut[(((size_t)b * 12 + lm) * 256 + i) * 256 + j] = bacc[g][r];
      }
    }
  }
}

// ---------------- attention v3: coalesced K via kT; barrier-free ----------------
__global__ __launch_bounds__(256) void attn_kernel(const float* __restrict__ qkv,   // [1024,2304]
                                                   const float* __restrict__ kT,    // [48,64,256]
                                                   const float* __restrict__ biasB, // [4,12,256,256]
                                                   const int* __restrict__ mask,    // [4,256,256]
                                                   float* __restrict__ ctx) {       // [1024,768]
  int tid = threadIdx.x, lane = tid & 63, w = tid >> 6;
  int bh = blockIdx.y, b = bh / 12, h = bh % 12;
  int i0 = blockIdx.x * 16;
  __shared__ float sQ[16][66];
  __shared__ float sP[4][4][256];
  {
    int r = tid >> 4, c = (tid & 15) * 4;
    *(float4*)&sQ[r][c] =
        *(const float4*)&qkv[((size_t)(b * 256 + i0 + r)) * 2304 + h * 64 + c];
  }
  int iw = i0 + w * 4;
  float lacc[4][4] = {};
  const float* kp = kT + (size_t)bh * 16384 + lane;
#pragma unroll 4
  for (int d = 0; d < 64; d += 2) {
    float k00 = kp[d * 256], k01 = kp[d * 256 + 64];
    float k02 = kp[d * 256 + 128], k03 = kp[d * 256 + 192];
    float k10 = kp[d * 256 + 256], k11 = kp[d * 256 + 320];
    float k12 = kp[d * 256 + 384], k13 = kp[d * 256 + 448];
#pragma unroll
    for (int qi = 0; qi < 4; ++qi) {
      float2 q2 = *(const float2*)&sQ[w * 4 + qi][d];
      lacc[qi][0] += q2.x * k00 + q2.y * k10;
      lacc[qi][1] += q2.x * k01 + q2.y * k11;
      lacc[qi][2] += q2.x * k02 + q2.y * k12;
      lacc[qi][3] += q2.x * k03 + q2.y * k13;
    }
  }
#pragma unroll
  for (int qi = 0; qi < 4; ++qi) {
    int gi = iw + qi;
    const float* brow = biasB + (((size_t)b * 12 + h) * 256 + gi) * 256;
    const int* mrow = mask + ((size_t)b * 256 + gi) * 256;
    float lg[4];
#pragma unroll
    for (int jc = 0; jc < 4; ++jc) {
      float lv = lacc[qi][jc] * 0.125f + brow[jc * 64 + lane];
      lg[jc] = mrow[jc * 64 + lane] ? lv : -1e30f;
    }
    float mx = fmaxf(fmaxf(lg[0], lg[1]), fmaxf(lg[2], lg[3]));
#pragma unroll
    for (int m = 32; m > 0; m >>= 1) mx = fmaxf(mx, __shfl_xor(mx, m));
    float e[4], sum = 0.f;
#pragma unroll
    for (int jc = 0; jc < 4; ++jc) { e[jc] = __expf(lg[jc] - mx); sum += e[jc]; }
#pragma unroll
    for (int m = 32; m > 0; m >>= 1) sum += __shfl_xor(sum, m);
    float inv = __builtin_amdgcn_rcpf(sum);
#pragma unroll
    for (int jc = 0; jc < 4; ++jc) sP[w][qi][jc * 64 + lane] = e[jc] * inv;
  }
  float ca[4] = {0.f, 0.f, 0.f, 0.f};
  const float* vcol = qkv + (size_t)b * 256 * 2304 + 1536 + h * 64 + lane;
#pragma unroll 2
  for (int j4 = 0; j4 < 256; j4 += 4) {
    float4 p0 = *(const float4*)&sP[w][0][j4];
    float4 p1 = *(const float4*)&sP[w][1][j4];
    float4 p2 = *(const float4*)&sP[w][2][j4];
    float4 p3 = *(const float4*)&sP[w][3][j4];
    const float* pp0 = (const float*)&p0;
    const float* pp1 = (const float*)&p1;
    const float* pp2 = (const float*)&p2;
    const float* pp3 = (const float*)&p3;
#pragma unroll
    for (int jj = 0; jj < 4; ++jj) {
      float v = vcol[(size_t)(j4 + jj) * 2304];
      ca[0] += pp0[jj] * v;
      ca[1] += pp1[jj] * v;
      ca[2] += pp2[jj] * v;
      ca[3] += pp3[jj] * v;
    }
  }
#pragma unroll
  for (int qi = 0; qi < 4; ++qi)
    ctx[((size_t)(b * 256 + iw + qi)) * 768 + h * 64 + lane] = ca[qi];
}

// ---------------- launcher ----------------
extern "C" void kernel_launch(void* const* d_in, const int* in_sizes, int n_in,
                              void* d_out, int out_size, void* d_ws, size_t ws_size,
                              hipStream_t stream) {
  const float* x       = (const float*)d_in[0];
  const float* dist    = (const float*)d_in[1];
  const int* mask      = (const int*)d_in[2];
  const float* qkv_w   = (const float*)d_in[3];
  const float* qkv_b   = (const float*)d_in[4];
  const float* out_w   = (const float*)d_in[5];
  const float* out_b   = (const float*)d_in[6];
  const float* rb_w1   = (const float*)d_in[7];
  const float* rb_b1   = (const float*)d_in[8];
  const float* rb_w2   = (const float*)d_in[9];
  const float* rb_b2   = (const float*)d_in[10];
  const float* gate_w1 = (const float*)d_in[11];
  const float* gate_b1 = (const float*)d_in[12];
  const float* gate_w2 = (const float*)d_in[13];
  const float* gate_b2 = (const float*)d_in[14];
  const float* ff_w1   = (const float*)d_in[15];
  const float* ff_b1   = (const float*)d_in[16];
  const float* ff_w2   = (const float*)d_in[17];
  const float* ff_b2   = (const float*)d_in[18];
  const float* ln1_g   = (const float*)d_in[19];
  const float* ln1_b   = (const float*)d_in[20];
  const float* ln2_g   = (const float*)d_in[21];
  const float* ln2_b   = (const float*)d_in[22];

  char* w = (char*)d_ws;
  auto alloc = [&](size_t bytes) {
    char* p = w;
    w += (bytes + 255) & ~(size_t)255;
    return p;
  };
  U16* xn      = (U16*)alloc(1024 * 768 * 2);
  float* qkvb  = (float*)alloc((size_t)1024 * 2304 * 4);
  float* kT    = (float*)alloc((size_t)48 * 64 * 256 * 4);
  // qkv_wT ++ g1wT contiguous => one fused B^T [3072,768]
  U16* qg_wT   = (U16*)alloc((size_t)3072 * 768 * 2);
  U16* qkv_wT  = qg_wT;
  U16* g1wT    = qg_wT + (size_t)2304 * 768;
  float* qg_b  = (float*)alloc(3072 * 4);
  U16* out_wT  = (U16*)alloc(768 * 768 * 2);
  U16* g2wT    = (U16*)alloc(768 * 768 * 2);
  U16* ff1wT   = (U16*)alloc(1536 * 768 * 2);
  U16* ff2wT   = (U16*)alloc(768 * 1536 * 2);
  U16* rb1wT   = (U16*)alloc(768 * 64 * 2);
  U16* rb2wL   = (U16*)alloc(24 * 64 * 8 * 2);
  float* biasB = (float*)alloc((size_t)4 * 12 * 256 * 256 * 4);
  float* ctx   = (float*)alloc(1024 * 768 * 4);
  U16* g1      = (U16*)alloc(1024 * 768 * 2);
  U16* cg      = (U16*)alloc(1024 * 768 * 2);
  float* x2    = (float*)alloc(1024 * 768 * 4);
  U16* y       = (U16*)alloc(1024 * 768 * 2);
  U16* f1      = (U16*)alloc(1024 * 1536 * 2);
  (void)ws_size; (void)in_sizes; (void)n_in; (void)out_size;

  prep_kernel<<<5868, 256, 0, stream>>>(qkv_w, out_w, gate_w1, gate_w2, ff_w1, ff_w2,
                                        rb_w1, rb_w2, qkv_b, gate_b1,
                                        qkv_wT, out_wT, g1wT, g2wT, ff1wT, ff2wT,
                                        rb1wT, rb2wL, qg_b);

  // LN1 -> xn (bf16)
  ln_kernel<<<1024, 256, 0, stream>>>(x, ln1_g, ln1_b, xn);
  // fused qkv (fp32) + gate1 silu (bf16)
  gemm_bt<5, false><<<dim3(48, 16), 256, 0, stream>>>(xn, qg_wT, qg_b, nullptr, g1,
                                                      qkvb, 1024, 3072, 768);
  // K transpose for coalesced attention reads
  kt_kernel<<<768, 256, 0, stream>>>(qkvb, kT);
  // relative bias MLP
  rb_kernel<<<1024, 256, 0, stream>>>(dist, rb1wT, rb_b1, rb2wL, rb_b2, biasB);
  // attention -> ctx fp32
  attn_kernel<<<dim3(16, 48), 256, 0, stream>>>(qkvb, kT, biasB, mask, ctx);
  // gate2: sigmoid(z) * ctx
  gemm_bt<3, false><<<dim3(12, 16), 256, 0, stream>>>(g1, g2wT, gate_b2, ctx, cg,
                                                      nullptr, 1024, 768, 768);
  // out projection + residual -> x2 (fp32)
  gemm_bt<4, true><<<dim3(12, 16), 256, 0, stream>>>(cg, out_wT, out_b, x, x2,
                                                     nullptr, 1024, 768, 768);
  // LN2 -> y (bf16)
  ln_kernel<<<1024, 256, 0, stream>>>(x2, ln2_g, ln2_b, y);
  // FF
  gemm_bt<2, false><<<dim3(24, 16), 256, 0, stream>>>(y, ff1wT, ff_b1, nullptr, f1,
                                                      nullptr, 1024, 1536, 768);
  gemm_bt<4, true><<<dim3(12, 16), 256, 0, stream>>>(f1, ff2wT, ff_b2, x2, (float*)d_out,
                                                     nullptr, 1024, 768, 1536);
}

// Round 8
// 327.161 us; speedup vs baseline: 1.8777x; 1.0013x over previous
//
#include <hip/hip_runtime.h>
#include <hip/hip_bf16.h>
#include <cmath>

#define U16 unsigned short

typedef __bf16 bf16x8_t __attribute__((ext_vector_type(8)));
typedef float f32x4_t __attribute__((ext_vector_type(4)));

union Frag { uint4 u4; unsigned u[4]; bf16x8_t b8; U16 s[8]; };

__device__ __forceinline__ float b2f(U16 u) {
  union { unsigned int i; float f; } x; x.i = ((unsigned int)u) << 16; return x.f;
}
__device__ __forceinline__ U16 f2b(float f) {
  union { float f; unsigned int i; } x; x.f = f;
  unsigned int r = x.i + 0x7FFFu + ((x.i >> 16) & 1u);
  return (U16)(r >> 16);
}
// pack two fp32 -> bf16x2 via v_cvt_pk_bf16_f32 (single instruction on gfx950, RNE)
__device__ __forceinline__ unsigned cvt_pk_bf16(float a, float b) {
  union { __hip_bfloat162 h2; unsigned u; } x;
  x.h2 = __float22bfloat162_rn(make_float2(a, b));
  return x.u;  // a = low half, b = high half
}
__device__ __forceinline__ float fast_silu(float z) {
  return z * __builtin_amdgcn_rcpf(1.f + __expf(-z));
}
// async global->LDS, 16B per lane (wave-uniform base + lane*16; stage order == lane order)
__device__ __forceinline__ void load_lds16(const U16* g, U16* l) {
  __builtin_amdgcn_global_load_lds((const __attribute__((address_space(1))) void*)g,
                                   (__attribute__((address_space(3))) void*)l, 16, 0, 0);
}

// ---------------- layernorm row (shfl reduce, one barrier) ----------------
__device__ __forceinline__ void ln_row(int row, const float* __restrict__ X,
                                       const float* __restrict__ gam,
                                       const float* __restrict__ bet,
                                       U16* __restrict__ Y) {
  int tid = threadIdx.x, lane = tid & 63, wave = tid >> 6;
  __shared__ float p1[4], p2[4];
  float v[3];
#pragma unroll
  for (int j = 0; j < 3; ++j) v[j] = X[(size_t)row * 768 + tid + j * 256];
  float s1 = v[0] + v[1] + v[2];
  float s2 = v[0] * v[0] + v[1] * v[1] + v[2] * v[2];
#pragma unroll
  for (int m = 32; m > 0; m >>= 1) {
    s1 += __shfl_xor(s1, m);
    s2 += __shfl_xor(s2, m);
  }
  if (lane == 0) { p1[wave] = s1; p2[wave] = s2; }
  __syncthreads();
  float t1 = p1[0] + p1[1] + p1[2] + p1[3];
  float t2 = p2[0] + p2[1] + p2[2] + p2[3];
  float mean = t1 * (1.f / 768.f);
  float var = t2 * (1.f / 768.f) - mean * mean;
  float rstd = rsqrtf(var + 1e-5f);
#pragma unroll
  for (int j = 0; j < 3; ++j) {
    int c = tid + j * 256;
    Y[(size_t)row * 768 + c] = f2b((v[j] - mean) * rstd * gam[c] + bet[c]);
  }
}

// ---------------- merged weight-prep + LN1 kernel ----------------
// [0,5808): 32x32 transpose tiles; [5808,5856): rb_w2 chunk; [5856,5868): bias concat;
// [5868,6892): LN1 rows.
__global__ __launch_bounds__(256) void prep_kernel(
    const float* __restrict__ qkv_w, const float* __restrict__ out_w,
    const float* __restrict__ g1w, const float* __restrict__ g2w,
    const float* __restrict__ ff1w, const float* __restrict__ ff2w,
    const float* __restrict__ rb1w, const float* __restrict__ rb2w,
    const float* __restrict__ qkv_b, const float* __restrict__ gate_b1,
    U16* __restrict__ qkv_wT, U16* __restrict__ out_wT, U16* __restrict__ g1wT,
    U16* __restrict__ g2wT, U16* __restrict__ ff1wT, U16* __restrict__ ff2wT,
    U16* __restrict__ rb1wT, U16* __restrict__ rb2wL, float* __restrict__ qg_bias,
    const float* __restrict__ x, const float* __restrict__ ln1_g,
    const float* __restrict__ ln1_b, U16* __restrict__ xn) {
  int bid = blockIdx.x;
  if (bid >= 5868) {  // LN1
    ln_row(bid - 5868, x, ln1_g, ln1_b, xn);
    return;
  }
  if (bid >= 5856) {  // qkv_b ++ gate_b1 -> qg_bias[3072]
    int idx = (bid - 5856) * 256 + threadIdx.x;
    qg_bias[idx] = (idx < 2304) ? qkv_b[idx] : gate_b1[idx - 2304];
    return;
  }
  if (bid >= 5808) {  // rb_w2 [768,12] -> w2L[pp][lane][8]
    int idx = (bid - 5808) * 256 + threadIdx.x;
    int j = idx & 7, lane = (idx >> 3) & 63, pp = idx >> 9;
    int row = lane & 15, col = pp * 32 + ((lane >> 4) << 3) + j;
    rb2wL[idx] = (row < 12) ? f2b(rb2w[col * 12 + row]) : (U16)0;
    return;
  }
  const float* in; U16* out; int R, C, base;
  if (bid < 1728)      { in = qkv_w; out = qkv_wT; R = 768;  C = 2304; base = 0; }
  else if (bid < 2304) { in = out_w; out = out_wT; R = 768;  C = 768;  base = 1728; }
  else if (bid < 2880) { in = g1w;   out = g1wT;   R = 768;  C = 768;  base = 2304; }
  else if (bid < 3456) { in = g2w;   out = g2wT;   R = 768;  C = 768;  base = 2880; }
  else if (bid < 4608) { in = ff1w;  out = ff1wT;  R = 768;  C = 1536; base = 3456; }
  else if (bid < 5760) { in = ff2w;  out = ff2wT;  R = 1536; C = 768;  base = 4608; }
  else                 { in = rb1w;  out = rb1wT;  R = 64;   C = 768;  base = 5760; }
  int bx = bid - base, tilesx = C / 32;
  int c0 = (bx % tilesx) * 32, r0 = (bx / tilesx) * 32;
  __shared__ float tile[32][33];
  int tx = threadIdx.x & 31, ty = threadIdx.x >> 5;
#pragma unroll
  for (int yy = 0; yy < 4; ++yy)
    tile[ty + yy * 8][tx] = in[(size_t)(r0 + ty + yy * 8) * C + c0 + tx];
  __syncthreads();
#pragma unroll
  for (int yy = 0; yy < 4; ++yy)
    out[(size_t)(c0 + ty + yy * 8) * R + r0 + tx] = f2b(tile[tx][ty + yy * 8]);
}

// ---------------- double-buffered bf16-MFMA GEMM core ----------------
// 64x64 tile, BK=32, 4 waves (2x2 of 32x32). One barrier per k-iter; next tile's
// global_load_lds issued right after the barrier (flies across current tile's compute).
// EPI: 0=none 1=silu 2=gelu(exact) 3=sigmoid(z)*other 4=z+other 5=fused qkv/gate1
template <int EPI, bool OUTF32>
__device__ __forceinline__ void gemm_core(U16* sA, U16* sB,  // each [2*2048]
                                          const U16* __restrict__ A,
                                          const U16* __restrict__ BT,
                                          const float* __restrict__ bias,
                                          const float* __restrict__ other,
                                          void* __restrict__ Cout,
                                          float* __restrict__ Cout2,
                                          int N, int K, int bx, int by) {
  int tid = threadIdx.x;
  int lane = tid & 63, wave = tid >> 6;
  int m0 = by * 64, n0 = bx * 64;
  int wm = (wave >> 1) * 32, wn = (wave & 1) * 32;
  int lm = lane & 15, lq = lane >> 4;
  int srow = tid >> 2, scol = (tid & 3) * 8;
  const U16* ag = A + (size_t)(m0 + srow) * K + scol;
  const U16* bg = BT + (size_t)(n0 + srow) * K + scol;
  int nit = K >> 5;
  load_lds16(ag, sA + tid * 8);
  load_lds16(bg, sB + tid * 8);
  f32x4_t acc[2][2] = {};
  for (int i = 0; i < nit; ++i) {
    __syncthreads();  // drains vmcnt: buffer i&1 ready; all waves done reading (i+1)&1
    int cb = (i & 1) * 2048, nb = ((i + 1) & 1) * 2048;
    if (i + 1 < nit) {
      load_lds16(ag + (i + 1) * 32, sA + nb + tid * 8);
      load_lds16(bg + (i + 1) * 32, sB + nb + tid * 8);
    }
    Frag af[2], bf[2];
#pragma unroll
    for (int mt = 0; mt < 2; ++mt)
      af[mt].u4 = *(const uint4*)&sA[cb + (wm + mt * 16 + lm) * 32 + lq * 8];
#pragma unroll
    for (int nt = 0; nt < 2; ++nt)
      bf[nt].u4 = *(const uint4*)&sB[cb + (wn + nt * 16 + lm) * 32 + lq * 8];
#pragma unroll
    for (int mt = 0; mt < 2; ++mt)
#pragma unroll
      for (int nt = 0; nt < 2; ++nt)
        acc[mt][nt] = __builtin_amdgcn_mfma_f32_16x16x32_bf16(af[mt].b8, bf[nt].b8,
                                                              acc[mt][nt], 0, 0, 0);
  }
#pragma unroll
  for (int nt = 0; nt < 2; ++nt) {
    int gc = n0 + wn + nt * 16 + lm;
    float bz = bias[gc];
#pragma unroll
    for (int mt = 0; mt < 2; ++mt) {
#pragma unroll
      for (int r = 0; r < 4; ++r) {
        int gr = m0 + wm + mt * 16 + lq * 4 + r;
        float z = acc[mt][nt][r] + bz;
        if (EPI == 5) {
          if (gc < 2304) Cout2[(size_t)gr * 2304 + gc] = z;
          else ((U16*)Cout)[(size_t)gr * 768 + gc - 2304] = f2b(fast_silu(z));
          continue;
        }
        size_t idx = (size_t)gr * N + gc;
        float o;
        if (EPI == 0) o = z;
        else if (EPI == 1) o = fast_silu(z);
        else if (EPI == 2) o = 0.5f * z * (1.f + erff(z * 0.70710678118f));
        else if (EPI == 3) o = other[idx] * __builtin_amdgcn_rcpf(1.f + __expf(-z));
        else o = z + other[idx];
        if (OUTF32) ((float*)Cout)[idx] = o;
        else ((U16*)Cout)[idx] = f2b(o);
      }
    }
  }
}

template <int EPI, bool OUTF32>
__global__ __launch_bounds__(256) void gemm_bt(const U16* __restrict__ A,
                                               const U16* __restrict__ BT,
                                               const float* __restrict__ bias,
                                               const float* __restrict__ other,
                                               void* __restrict__ Cout,
                                               int N, int K) {
  __shared__ __align__(16) U16 sA[2 * 2048];
  __shared__ __align__(16) U16 sB[2 * 2048];
  gemm_core<EPI, OUTF32>(sA, sB, A, BT, bias, other, Cout, nullptr, N, K,
                         blockIdx.x, blockIdx.y);
}

// ---------------- relative-bias MLP body v7: even/odd register-set prefetch ----------------
// bias[b,h,i,j] = silu(dist[(b,i,j),:64] @ w1 + b1) @ w2 + b2 (mapping verified R3-R7)
__device__ void rb_body(int bid, const float* __restrict__ dist,
                        const U16* __restrict__ w1T, const float* __restrict__ b1,
                        const U16* __restrict__ w2L, const float* __restrict__ b2,
                        float* __restrict__ biasOut) {
  int tid = threadIdx.x;
  int lane = tid & 63, wave = tid >> 6;
  int lm = lane & 15, lq = lane >> 4;
  int r0 = bid * 256;
  float hb = (lm < 12) ? b2[lm] : 0.f;
  Frag bd[4][2];
#pragma unroll
  for (int g = 0; g < 4; ++g) {
    const float* ap = dist + (size_t)(r0 + (wave * 4 + g) * 16 + lm) * 64 + lq * 8;
    float4 v0 = ((const float4*)ap)[0];
    float4 v1 = ((const float4*)ap)[1];
    float4 v2 = ((const float4*)(ap + 32))[0];
    float4 v3 = ((const float4*)(ap + 32))[1];
    bd[g][0].u[0] = cvt_pk_bf16(v0.x, v0.y); bd[g][0].u[1] = cvt_pk_bf16(v0.z, v0.w);
    bd[g][0].u[2] = cvt_pk_bf16(v1.x, v1.y); bd[g][0].u[3] = cvt_pk_bf16(v1.z, v1.w);
    bd[g][1].u[0] = cvt_pk_bf16(v2.x, v2.y); bd[g][1].u[1] = cvt_pk_bf16(v2.z, v2.w);
    bd[g][1].u[2] = cvt_pk_bf16(v3.x, v3.y); bd[g][1].u[3] = cvt_pk_bf16(v3.z, v3.w);
  }
  const U16* w1p0 = w1T + (size_t)(((lm >> 2) << 3) + (lm & 3)) * 64 + lq * 8;  // tt=0
  const U16* w1p1 = w1p0 + 256;                                                 // tt=1
  const U16* w2p = w2L + lane * 8;
  const float* b1p = b1 + lq * 8;
  f32x4_t bacc[4] = {{hb, hb, hb, hb}, {hb, hb, hb, hb}, {hb, hb, hb, hb}, {hb, hb, hb, hb}};

  auto loadw = [&](int j, Frag& f00, Frag& f01, Frag& f10, Frag& f11, Frag& fwb,
                   float4& fb0, float4& fb1) {
    const U16* p0 = w1p0 + (size_t)j * 2048;
    const U16* p1 = w1p1 + (size_t)j * 2048;
    f00.u4 = *(const uint4*)p0;
    f01.u4 = *(const uint4*)(p0 + 32);
    f10.u4 = *(const uint4*)p1;
    f11.u4 = *(const uint4*)(p1 + 32);
    fwb.u4 = *(const uint4*)(w2p + (size_t)j * 512);
    fb0 = *(const float4*)(b1p + j * 32);
    fb1 = *(const float4*)(b1p + j * 32 + 4);
  };
  auto comp = [&](Frag& f00, Frag& f01, Frag& f10, Frag& f11, Frag& fwb,
                  float4 fb0, float4 fb1) {
    f32x4_t cz0 = {fb0.x, fb0.y, fb0.z, fb0.w};
    f32x4_t cz1 = {fb1.x, fb1.y, fb1.z, fb1.w};
#pragma unroll
    for (int g = 0; g < 4; ++g) {
      f32x4_t z0 = cz0, z1 = cz1;  // bias as MFMA C operand
      z0 = __builtin_amdgcn_mfma_f32_16x16x32_bf16(f00.b8, bd[g][0].b8, z0, 0, 0, 0);
      z0 = __builtin_amdgcn_mfma_f32_16x16x32_bf16(f01.b8, bd[g][1].b8, z0, 0, 0, 0);
      z1 = __builtin_amdgcn_mfma_f32_16x16x32_bf16(f10.b8, bd[g][0].b8, z1, 0, 0, 0);
      z1 = __builtin_amdgcn_mfma_f32_16x16x32_bf16(f11.b8, bd[g][1].b8, z1, 0, 0, 0);
      float s0 = fast_silu(z0[0]), s1 = fast_silu(z0[1]);
      float s2 = fast_silu(z0[2]), s3 = fast_silu(z0[3]);
      float t0 = fast_silu(z1[0]), t1 = fast_silu(z1[1]);
      float t2 = fast_silu(z1[2]), t3 = fast_silu(z1[3]);
      Frag af2;
      af2.u[0] = cvt_pk_bf16(s0, s1); af2.u[1] = cvt_pk_bf16(s2, s3);
      af2.u[2] = cvt_pk_bf16(t0, t1); af2.u[3] = cvt_pk_bf16(t2, t3);
      bacc[g] = __builtin_amdgcn_mfma_f32_16x16x32_bf16(af2.b8, fwb.b8, bacc[g], 0, 0, 0);
    }
  };

  Frag e00, e01, e10, e11, ewb, o00, o01, o10, o11, owb;
  float4 eb0, eb1, ob0, ob1;
  loadw(0, e00, e01, e10, e11, ewb, eb0, eb1);
  for (int pp = 0; pp < 24; pp += 2) {
    loadw(pp + 1, o00, o01, o10, o11, owb, ob0, ob1);
    comp(e00, e01, e10, e11, ewb, eb0, eb1);
    if (pp + 2 < 24) loadw(pp + 2, e00, e01, e10, e11, ewb, eb0, eb1);
    comp(o00, o01, o10, o11, owb, ob0, ob1);
  }
  if (lm < 12) {
#pragma unroll
    for (int g = 0; g < 4; ++g) {
#pragma unroll
      for (int r = 0; r < 4; ++r) {
        int gr = r0 + (wave * 4 + g) * 16 + lq * 4 + r;  // flat (b,i,j)
        int b = gr >> 16, rem = gr & 65535, i = rem >> 8, j = rem & 255;
        biasOut[(((size_t)b * 12 + lm) * 256 + i) * 256 + j] = bacc[g][r];
      }
    }
  }
}

// ---------------- merged launch: fused qkv/gate1 GEMM (blocks 0..767) + rb (768..1791) ----
__global__ __launch_bounds__(256) void qkvrb_kernel(
    const U16* __restrict__ xn, const U16* __restrict__ qg_wT,
    const float* __restrict__ qg_b, float* __restrict__ qkvb, U16* __restrict__ g1,
    const float* __restrict__ dist, const U16* __restrict__ rb1wT,
    const float* __restrict__ rb_b1, const U16* __restrict__ rb2wL,
    const float* __restrict__ rb_b2, float* __restrict__ biasB) {
  __shared__ __align__(16) U16 sA[2 * 2048];
  __shared__ __align__(16) U16 sB[2 * 2048];
  int bid = blockIdx.x;
  if (bid < 768) {
    gemm_core<5, false>(sA, sB, xn, qg_wT, qg_b, nullptr, g1, qkvb, 3072, 768,
                        bid % 48, bid / 48);
  } else {
    rb_body(bid - 768, dist, rb1wT, rb_b1, rb2wL, rb_b2, biasB);
  }
}

// ---------------- attention v4: in-LDS K transpose (bf16); no kt kernel ----------------
// grid (16, 48). Per block: stage K[256,64] -> sK[d][n] bf16 (coalesced reads, 2-way
// conflict writes = free), one barrier, then QK/softmax/PV as before.
__global__ __launch_bounds__(256) void attn_kernel(const float* __restrict__ qkv,   // [1024,2304]
                                                   const float* __restrict__ biasB, // [4,12,256,256]
                                                   const int* __restrict__ mask,    // [4,256,256]
                                                   float* __restrict__ ctx) {       // [1024,768]
  int tid = threadIdx.x, lane = tid & 63, w = tid >> 6;
  int bh = blockIdx.y, b = bh / 12, h = bh % 12;
  int i0 = blockIdx.x * 16;
  __shared__ U16 sK[64 * 258];
  __shared__ float sQ[16][66];
  __shared__ float sP[4][4][256];
  {
    int r = tid >> 4, c = (tid & 15) * 4;
    *(float4*)&sQ[r][c] =
        *(const float4*)&qkv[((size_t)(b * 256 + i0 + r)) * 2304 + h * 64 + c];
  }
  {  // wave w stages K rows [w*64, w*64+64): lane = d (coalesced 256B loads)
    const float* kr = qkv + ((size_t)(b * 256 + w * 64)) * 2304 + 768 + h * 64 + lane;
#pragma unroll 8
    for (int rr = 0; rr < 64; ++rr) {
      float kv = kr[(size_t)rr * 2304];
      sK[lane * 258 + w * 64 + rr] = (U16)cvt_pk_bf16(kv, kv);
    }
  }
  __syncthreads();
  int iw = i0 + w * 4;
  float lacc[4][4] = {};
#pragma unroll 4
  for (int d = 0; d < 64; ++d) {
    float k0 = b2f(sK[d * 258 + lane]);
    float k1 = b2f(sK[d * 258 + 64 + lane]);
    float k2 = b2f(sK[d * 258 + 128 + lane]);
    float k3 = b2f(sK[d * 258 + 192 + lane]);
#pragma unroll
    for (int qi = 0; qi < 4; ++qi) {
      float qv = sQ[w * 4 + qi][d];
      lacc[qi][0] += qv * k0;
      lacc[qi][1] += qv * k1;
      lacc[qi][2] += qv * k2;
      lacc[qi][3] += qv * k3;
    }
  }
#pragma unroll
  for (int qi = 0; qi < 4; ++qi) {
    int gi = iw + qi;
    const float* brow = biasB + (((size_t)b * 12 + h) * 256 + gi) * 256;
    const int* mrow = mask + ((size_t)b * 256 + gi) * 256;
    float lg[4];
#pragma unroll
    for (int jc = 0; jc < 4; ++jc) {
      float lv = lacc[qi][jc] * 0.125f + brow[jc * 64 + lane];
      lg[jc] = mrow[jc * 64 + lane] ? lv : -1e30f;
    }
    float mx = fmaxf(fmaxf(lg[0], lg[1]), fmaxf(lg[2], lg[3]));
#pragma unroll
    for (int m = 32; m > 0; m >>= 1) mx = fmaxf(mx, __shfl_xor(mx, m));
    float e[4], sum = 0.f;
#pragma unroll
    for (int jc = 0; jc < 4; ++jc) { e[jc] = __expf(lg[jc] - mx); sum += e[jc]; }
#pragma unroll
    for (int m = 32; m > 0; m >>= 1) sum += __shfl_xor(sum, m);
    float inv = __builtin_amdgcn_rcpf(sum);
#pragma unroll
    for (int jc = 0; jc < 4; ++jc) sP[w][qi][jc * 64 + lane] = e[jc] * inv;
  }
  float ca[4] = {0.f, 0.f, 0.f, 0.f};
  const float* vcol = qkv + (size_t)b * 256 * 2304 + 1536 + h * 64 + lane;
#pragma unroll 2
  for (int j4 = 0; j4 < 256; j4 += 4) {
    float4 p0 = *(const float4*)&sP[w][0][j4];
    float4 p1 = *(const float4*)&sP[w][1][j4];
    float4 p2 = *(const float4*)&sP[w][2][j4];
    float4 p3 = *(const float4*)&sP[w][3][j4];
    const float* pp0 = (const float*)&p0;
    const float* pp1 = (const float*)&p1;
    const float* pp2 = (const float*)&p2;
    const float* pp3 = (const float*)&p3;
#pragma unroll
    for (int jj = 0; jj < 4; ++jj) {
      float v = vcol[(size_t)(j4 + jj) * 2304];
      ca[0] += pp0[jj] * v;
      ca[1] += pp1[jj] * v;
      ca[2] += pp2[jj] * v;
      ca[3] += pp3[jj] * v;
    }
  }
#pragma unroll
  for (int qi = 0; qi < 4; ++qi)
    ctx[((size_t)(b * 256 + iw + qi)) * 768 + h * 64 + lane] = ca[qi];
}

// ---------------- standalone LN (for LN2) ----------------
__global__ __launch_bounds__(256) void ln_kernel(const float* __restrict__ X,
                                                 const float* __restrict__ gam,
                                                 const float* __restrict__ bet,
                                                 U16* __restrict__ Y) {
  ln_row(blockIdx.x, X, gam, bet, Y);
}

// ---------------- launcher ----------------
extern "C" void kernel_launch(void* const* d_in, const int* in_sizes, int n_in,
                              void* d_out, int out_size, void* d_ws, size_t ws_size,
                              hipStream_t stream) {
  const float* x       = (const float*)d_in[0];
  const float* dist    = (const float*)d_in[1];
  const int* mask      = (const int*)d_in[2];
  const float* qkv_w   = (const float*)d_in[3];
  const float* qkv_b   = (const float*)d_in[4];
  const float* out_w   = (const float*)d_in[5];
  const float* out_b   = (const float*)d_in[6];
  const float* rb_w1   = (const float*)d_in[7];
  const float* rb_b1   = (const float*)d_in[8];
  const float* rb_w2   = (const float*)d_in[9];
  const float* rb_b2   = (const float*)d_in[10];
  const float* gate_w1 = (const float*)d_in[11];
  const float* gate_b1 = (const float*)d_in[12];
  const float* gate_w2 = (const float*)d_in[13];
  const float* gate_b2 = (const float*)d_in[14];
  const float* ff_w1   = (const float*)d_in[15];
  const float* ff_b1   = (const float*)d_in[16];
  const float* ff_w2   = (const float*)d_in[17];
  const float* ff_b2   = (const float*)d_in[18];
  const float* ln1_g   = (const float*)d_in[19];
  const float* ln1_b   = (const float*)d_in[20];
  const float* ln2_g   = (const float*)d_in[21];
  const float* ln2_b   = (const float*)d_in[22];

  char* w = (char*)d_ws;
  auto alloc = [&](size_t bytes) {
    char* p = w;
    w += (bytes + 255) & ~(size_t)255;
    return p;
  };
  U16* xn      = (U16*)alloc(1024 * 768 * 2);
  float* qkvb  = (float*)alloc((size_t)1024 * 2304 * 4);
  U16* qg_wT   = (U16*)alloc((size_t)3072 * 768 * 2);  // qkv_wT ++ g1wT contiguous
  U16* qkv_wT  = qg_wT;
  U16* g1wT    = qg_wT + (size_t)2304 * 768;
  float* qg_b  = (float*)alloc(3072 * 4);
  U16* out_wT  = (U16*)alloc(768 * 768 * 2);
  U16* g2wT    = (U16*)alloc(768 * 768 * 2);
  U16* ff1wT   = (U16*)alloc(1536 * 768 * 2);
  U16* ff2wT   = (U16*)alloc(768 * 1536 * 2);
  U16* rb1wT   = (U16*)alloc(768 * 64 * 2);
  U16* rb2wL   = (U16*)alloc(24 * 64 * 8 * 2);
  float* biasB = (float*)alloc((size_t)4 * 12 * 256 * 256 * 4);
  float* ctx   = (float*)alloc(1024 * 768 * 4);
  U16* g1      = (U16*)alloc(1024 * 768 * 2);
  U16* cg      = (U16*)alloc(1024 * 768 * 2);
  float* x2    = (float*)alloc(1024 * 768 * 4);
  U16* y       = (U16*)alloc(1024 * 768 * 2);
  U16* f1      = (U16*)alloc(1024 * 1536 * 2);
  (void)ws_size; (void)in_sizes; (void)n_in; (void)out_size;

  // 1: weight prep + LN1
  prep_kernel<<<6892, 256, 0, stream>>>(qkv_w, out_w, gate_w1, gate_w2, ff_w1, ff_w2,
                                        rb_w1, rb_w2, qkv_b, gate_b1,
                                        qkv_wT, out_wT, g1wT, g2wT, ff1wT, ff2wT,
                                        rb1wT, rb2wL, qg_b, x, ln1_g, ln1_b, xn);
  // 2: fused qkv+gate1 GEMM co-scheduled with rb bias MLP
  qkvrb_kernel<<<1792, 256, 0, stream>>>(xn, qg_wT, qg_b, qkvb, g1,
                                         dist, rb1wT, rb_b1, rb2wL, rb_b2, biasB);
  // 3: attention
  attn_kernel<<<dim3(16, 48), 256, 0, stream>>>(qkvb, biasB, mask, ctx);
  // 4: gate2 (sigmoid(z) * ctx)
  gemm_bt<3, false><<<dim3(12, 16), 256, 0, stream>>>(g1, g2wT, gate_b2, ctx, cg,
                                                      768, 768);
  // 5: out projection + residual -> x2 (fp32)
  gemm_bt<4, true><<<dim3(12, 16), 256, 0, stream>>>(cg, out_wT, out_b, x, x2,
                                                     768, 768);
  // 6: LN2
  ln_kernel<<<1024, 256, 0, stream>>>(x2, ln2_g, ln2_b, y);
  // 7: FF1 (gelu)
  gemm_bt<2, false><<<dim3(24, 16), 256, 0, stream>>>(y, ff1wT, ff_b1, nullptr, f1,
                                                      1536, 768);
  // 8: FF2 + residual -> out
  gemm_bt<4, true><<<dim3(12, 16), 256, 0, stream>>>(f1, ff2wT, ff_b2, x2, (float*)d_out,
                                                     768, 1536);
}

// Round 9
// 326.195 us; speedup vs baseline: 1.8832x; 1.0030x over previous
//
#include <hip/hip_runtime.h>
#include <hip/hip_bf16.h>
#include <cmath>

#define U16 unsigned short

typedef __bf16 bf16x8_t __attribute__((ext_vector_type(8)));
typedef float f32x4_t __attribute__((ext_vector_type(4)));

union Frag { uint4 u4; unsigned u[4]; bf16x8_t b8; U16 s[8]; };

__device__ __forceinline__ float b2f(U16 u) {
  union { unsigned int i; float f; } x; x.i = ((unsigned int)u) << 16; return x.f;
}
__device__ __forceinline__ U16 f2b(float f) {
  union { float f; unsigned int i; } x; x.f = f;
  unsigned int r = x.i + 0x7FFFu + ((x.i >> 16) & 1u);
  return (U16)(r >> 16);
}
__device__ __forceinline__ unsigned cvt_pk_bf16(float a, float b) {
  union { __hip_bfloat162 h2; unsigned u; } x;
  x.h2 = __float22bfloat162_rn(make_float2(a, b));
  return x.u;
}
__device__ __forceinline__ float fast_silu(float z) {
  return z * __builtin_amdgcn_rcpf(1.f + __expf(-z));
}
__device__ __forceinline__ void load_lds16(const U16* g, U16* l) {
  __builtin_amdgcn_global_load_lds((const __attribute__((address_space(1))) void*)g,
                                   (__attribute__((address_space(3))) void*)l, 16, 0, 0);
}

// ---------------- layernorm row (shfl reduce, one barrier) ----------------
__device__ __forceinline__ void ln_row(int row, const float* __restrict__ X,
                                       const float* __restrict__ gam,
                                       const float* __restrict__ bet,
                                       U16* __restrict__ Y) {
  int tid = threadIdx.x, lane = tid & 63, wave = tid >> 6;
  __shared__ float p1[4], p2[4];
  float v[3];
#pragma unroll
  for (int j = 0; j < 3; ++j) v[j] = X[(size_t)row * 768 + tid + j * 256];
  float s1 = v[0] + v[1] + v[2];
  float s2 = v[0] * v[0] + v[1] * v[1] + v[2] * v[2];
#pragma unroll
  for (int m = 32; m > 0; m >>= 1) {
    s1 += __shfl_xor(s1, m);
    s2 += __shfl_xor(s2, m);
  }
  if (lane == 0) { p1[wave] = s1; p2[wave] = s2; }
  __syncthreads();
  float t1 = p1[0] + p1[1] + p1[2] + p1[3];
  float t2 = p2[0] + p2[1] + p2[2] + p2[3];
  float mean = t1 * (1.f / 768.f);
  float var = t2 * (1.f / 768.f) - mean * mean;
  float rstd = rsqrtf(var + 1e-5f);
#pragma unroll
  for (int j = 0; j < 3; ++j) {
    int c = tid + j * 256;
    Y[(size_t)row * 768 + c] = f2b((v[j] - mean) * rstd * gam[c] + bet[c]);
  }
}

// ---------------- merged weight-prep + LN1 kernel ----------------
__global__ __launch_bounds__(256) void prep_kernel(
    const float* __restrict__ qkv_w, const float* __restrict__ out_w,
    const float* __restrict__ g1w, const float* __restrict__ g2w,
    const float* __restrict__ ff1w, const float* __restrict__ ff2w,
    const float* __restrict__ rb1w, const float* __restrict__ rb2w,
    const float* __restrict__ qkv_b, const float* __restrict__ gate_b1,
    U16* __restrict__ qkv_wT, U16* __restrict__ out_wT, U16* __restrict__ g1wT,
    U16* __restrict__ g2wT, U16* __restrict__ ff1wT, U16* __restrict__ ff2wT,
    U16* __restrict__ rb1wT, U16* __restrict__ rb2wL, float* __restrict__ qg_bias,
    const float* __restrict__ x, const float* __restrict__ ln1_g,
    const float* __restrict__ ln1_b, U16* __restrict__ xn) {
  int bid = blockIdx.x;
  if (bid >= 5868) {  // LN1
    ln_row(bid - 5868, x, ln1_g, ln1_b, xn);
    return;
  }
  if (bid >= 5856) {  // qkv_b ++ gate_b1
    int idx = (bid - 5856) * 256 + threadIdx.x;
    qg_bias[idx] = (idx < 2304) ? qkv_b[idx] : gate_b1[idx - 2304];
    return;
  }
  if (bid >= 5808) {  // rb_w2 chunk
    int idx = (bid - 5808) * 256 + threadIdx.x;
    int j = idx & 7, lane = (idx >> 3) & 63, pp = idx >> 9;
    int row = lane & 15, col = pp * 32 + ((lane >> 4) << 3) + j;
    rb2wL[idx] = (row < 12) ? f2b(rb2w[col * 12 + row]) : (U16)0;
    return;
  }
  const float* in; U16* out; int R, C, base;
  if (bid < 1728)      { in = qkv_w; out = qkv_wT; R = 768;  C = 2304; base = 0; }
  else if (bid < 2304) { in = out_w; out = out_wT; R = 768;  C = 768;  base = 1728; }
  else if (bid < 2880) { in = g1w;   out = g1wT;   R = 768;  C = 768;  base = 2304; }
  else if (bid < 3456) { in = g2w;   out = g2wT;   R = 768;  C = 768;  base = 2880; }
  else if (bid < 4608) { in = ff1w;  out = ff1wT;  R = 768;  C = 1536; base = 3456; }
  else if (bid < 5760) { in = ff2w;  out = ff2wT;  R = 1536; C = 768;  base = 4608; }
  else                 { in = rb1w;  out = rb1wT;  R = 64;   C = 768;  base = 5760; }
  int bx = bid - base, tilesx = C / 32;
  int c0 = (bx % tilesx) * 32, r0 = (bx / tilesx) * 32;
  __shared__ float tile[32][33];
  int tx = threadIdx.x & 31, ty = threadIdx.x >> 5;
#pragma unroll
  for (int yy = 0; yy < 4; ++yy)
    tile[ty + yy * 8][tx] = in[(size_t)(r0 + ty + yy * 8) * C + c0 + tx];
  __syncthreads();
#pragma unroll
  for (int yy = 0; yy < 4; ++yy)
    out[(size_t)(c0 + ty + yy * 8) * R + r0 + tx] = f2b(tile[tx][ty + yy * 8]);
}

// ---------------- double-buffered bf16-MFMA GEMM core ----------------
// EPI: 0=none 2=gelu 4=z+other(fp32 out) 5=fused qkv/gate1 6=sigmoid->bf16
template <int EPI, bool OUTF32>
__device__ __forceinline__ void gemm_core(U16* sA, U16* sB,  // each [2*2048]
                                          const U16* __restrict__ A,
                                          const U16* __restrict__ BT,
                                          const float* __restrict__ bias,
                                          const float* __restrict__ other,
                                          void* __restrict__ Cout,
                                          float* __restrict__ Cout2,
                                          int N, int K, int bx, int by) {
  int tid = threadIdx.x;
  int lane = tid & 63, wave = tid >> 6;
  int m0 = by * 64, n0 = bx * 64;
  int wm = (wave >> 1) * 32, wn = (wave & 1) * 32;
  int lm = lane & 15, lq = lane >> 4;
  int srow = tid >> 2, scol = (tid & 3) * 8;
  const U16* ag = A + (size_t)(m0 + srow) * K + scol;
  const U16* bg = BT + (size_t)(n0 + srow) * K + scol;
  int nit = K >> 5;
  load_lds16(ag, sA + tid * 8);
  load_lds16(bg, sB + tid * 8);
  f32x4_t acc[2][2] = {};
  for (int i = 0; i < nit; ++i) {
    __syncthreads();
    int cb = (i & 1) * 2048, nb = ((i + 1) & 1) * 2048;
    if (i + 1 < nit) {
      load_lds16(ag + (i + 1) * 32, sA + nb + tid * 8);
      load_lds16(bg + (i + 1) * 32, sB + nb + tid * 8);
    }
    Frag af[2], bf[2];
#pragma unroll
    for (int mt = 0; mt < 2; ++mt)
      af[mt].u4 = *(const uint4*)&sA[cb + (wm + mt * 16 + lm) * 32 + lq * 8];
#pragma unroll
    for (int nt = 0; nt < 2; ++nt)
      bf[nt].u4 = *(const uint4*)&sB[cb + (wn + nt * 16 + lm) * 32 + lq * 8];
#pragma unroll
    for (int mt = 0; mt < 2; ++mt)
#pragma unroll
      for (int nt = 0; nt < 2; ++nt)
        acc[mt][nt] = __builtin_amdgcn_mfma_f32_16x16x32_bf16(af[mt].b8, bf[nt].b8,
                                                              acc[mt][nt], 0, 0, 0);
  }
#pragma unroll
  for (int nt = 0; nt < 2; ++nt) {
    int gc = n0 + wn + nt * 16 + lm;
    float bz = bias[gc];
#pragma unroll
    for (int mt = 0; mt < 2; ++mt) {
#pragma unroll
      for (int r = 0; r < 4; ++r) {
        int gr = m0 + wm + mt * 16 + lq * 4 + r;
        float z = acc[mt][nt][r] + bz;
        if (EPI == 5) {
          if (gc < 2304) Cout2[(size_t)gr * 2304 + gc] = z;
          else ((U16*)Cout)[(size_t)gr * 768 + gc - 2304] = f2b(fast_silu(z));
          continue;
        }
        size_t idx = (size_t)gr * N + gc;
        float o;
        if (EPI == 0) o = z;
        else if (EPI == 2) o = 0.5f * z * (1.f + erff(z * 0.70710678118f));
        else if (EPI == 6) o = __builtin_amdgcn_rcpf(1.f + __expf(-z));
        else o = z + other[idx];
        if (OUTF32) ((float*)Cout)[idx] = o;
        else ((U16*)Cout)[idx] = f2b(o);
      }
    }
  }
}

template <int EPI, bool OUTF32>
__global__ __launch_bounds__(256) void gemm_bt(const U16* __restrict__ A,
                                               const U16* __restrict__ BT,
                                               const float* __restrict__ bias,
                                               const float* __restrict__ other,
                                               void* __restrict__ Cout,
                                               int N, int K) {
  __shared__ __align__(16) U16 sA[2 * 2048];
  __shared__ __align__(16) U16 sB[2 * 2048];
  gemm_core<EPI, OUTF32>(sA, sB, A, BT, bias, other, Cout, nullptr, N, K,
                         blockIdx.x, blockIdx.y);
}

// ---------------- relative-bias MLP body v7 (verified R3-R8) ----------------
__device__ void rb_body(int bid, const float* __restrict__ dist,
                        const U16* __restrict__ w1T, const float* __restrict__ b1,
                        const U16* __restrict__ w2L, const float* __restrict__ b2,
                        float* __restrict__ biasOut) {
  int tid = threadIdx.x;
  int lane = tid & 63, wave = tid >> 6;
  int lm = lane & 15, lq = lane >> 4;
  int r0 = bid * 256;
  float hb = (lm < 12) ? b2[lm] : 0.f;
  Frag bd[4][2];
#pragma unroll
  for (int g = 0; g < 4; ++g) {
    const float* ap = dist + (size_t)(r0 + (wave * 4 + g) * 16 + lm) * 64 + lq * 8;
    float4 v0 = ((const float4*)ap)[0];
    float4 v1 = ((const float4*)ap)[1];
    float4 v2 = ((const float4*)(ap + 32))[0];
    float4 v3 = ((const float4*)(ap + 32))[1];
    bd[g][0].u[0] = cvt_pk_bf16(v0.x, v0.y); bd[g][0].u[1] = cvt_pk_bf16(v0.z, v0.w);
    bd[g][0].u[2] = cvt_pk_bf16(v1.x, v1.y); bd[g][0].u[3] = cvt_pk_bf16(v1.z, v1.w);
    bd[g][1].u[0] = cvt_pk_bf16(v2.x, v2.y); bd[g][1].u[1] = cvt_pk_bf16(v2.z, v2.w);
    bd[g][1].u[2] = cvt_pk_bf16(v3.x, v3.y); bd[g][1].u[3] = cvt_pk_bf16(v3.z, v3.w);
  }
  const U16* w1p0 = w1T + (size_t)(((lm >> 2) << 3) + (lm & 3)) * 64 + lq * 8;
  const U16* w1p1 = w1p0 + 256;
  const U16* w2p = w2L + lane * 8;
  const float* b1p = b1 + lq * 8;
  f32x4_t bacc[4] = {{hb, hb, hb, hb}, {hb, hb, hb, hb}, {hb, hb, hb, hb}, {hb, hb, hb, hb}};

  auto loadw = [&](int j, Frag& f00, Frag& f01, Frag& f10, Frag& f11, Frag& fwb,
                   float4& fb0, float4& fb1) {
    const U16* p0 = w1p0 + (size_t)j * 2048;
    const U16* p1 = w1p1 + (size_t)j * 2048;
    f00.u4 = *(const uint4*)p0;
    f01.u4 = *(const uint4*)(p0 + 32);
    f10.u4 = *(const uint4*)p1;
    f11.u4 = *(const uint4*)(p1 + 32);
    fwb.u4 = *(const uint4*)(w2p + (size_t)j * 512);
    fb0 = *(const float4*)(b1p + j * 32);
    fb1 = *(const float4*)(b1p + j * 32 + 4);
  };
  auto comp = [&](Frag& f00, Frag& f01, Frag& f10, Frag& f11, Frag& fwb,
                  float4 fb0, float4 fb1) {
    f32x4_t cz0 = {fb0.x, fb0.y, fb0.z, fb0.w};
    f32x4_t cz1 = {fb1.x, fb1.y, fb1.z, fb1.w};
#pragma unroll
    for (int g = 0; g < 4; ++g) {
      f32x4_t z0 = cz0, z1 = cz1;
      z0 = __builtin_amdgcn_mfma_f32_16x16x32_bf16(f00.b8, bd[g][0].b8, z0, 0, 0, 0);
      z0 = __builtin_amdgcn_mfma_f32_16x16x32_bf16(f01.b8, bd[g][1].b8, z0, 0, 0, 0);
      z1 = __builtin_amdgcn_mfma_f32_16x16x32_bf16(f10.b8, bd[g][0].b8, z1, 0, 0, 0);
      z1 = __builtin_amdgcn_mfma_f32_16x16x32_bf16(f11.b8, bd[g][1].b8, z1, 0, 0, 0);
      float s0 = fast_silu(z0[0]), s1 = fast_silu(z0[1]);
      float s2 = fast_silu(z0[2]), s3 = fast_silu(z0[3]);
      float t0 = fast_silu(z1[0]), t1 = fast_silu(z1[1]);
      float t2 = fast_silu(z1[2]), t3 = fast_silu(z1[3]);
      Frag af2;
      af2.u[0] = cvt_pk_bf16(s0, s1); af2.u[1] = cvt_pk_bf16(s2, s3);
      af2.u[2] = cvt_pk_bf16(t0, t1); af2.u[3] = cvt_pk_bf16(t2, t3);
      bacc[g] = __builtin_amdgcn_mfma_f32_16x16x32_bf16(af2.b8, fwb.b8, bacc[g], 0, 0, 0);
    }
  };

  Frag e00, e01, e10, e11, ewb, o00, o01, o10, o11, owb;
  float4 eb0, eb1, ob0, ob1;
  loadw(0, e00, e01, e10, e11, ewb, eb0, eb1);
  for (int pp = 0; pp < 24; pp += 2) {
    loadw(pp + 1, o00, o01, o10, o11, owb, ob0, ob1);
    comp(e00, e01, e10, e11, ewb, eb0, eb1);
    if (pp + 2 < 24) loadw(pp + 2, e00, e01, e10, e11, ewb, eb0, eb1);
    comp(o00, o01, o10, o11, owb, ob0, ob1);
  }
  if (lm < 12) {
#pragma unroll
    for (int g = 0; g < 4; ++g) {
#pragma unroll
      for (int r = 0; r < 4; ++r) {
        int gr = r0 + (wave * 4 + g) * 16 + lq * 4 + r;
        int b = gr >> 16, rem = gr & 65535, i = rem >> 8, j = rem & 255;
        biasOut[(((size_t)b * 12 + lm) * 256 + i) * 256 + j] = bacc[g][r];
      }
    }
  }
}

// ---------------- merged launch: fused qkv/gate1 GEMM (0..767) + rb (768..1791) ----
__global__ __launch_bounds__(256) void qkvrb_kernel(
    const U16* __restrict__ xn, const U16* __restrict__ qg_wT,
    const float* __restrict__ qg_b, float* __restrict__ qkvb, U16* __restrict__ g1,
    const float* __restrict__ dist, const U16* __restrict__ rb1wT,
    const float* __restrict__ rb_b1, const U16* __restrict__ rb2wL,
    const float* __restrict__ rb_b2, float* __restrict__ biasB) {
  __shared__ __align__(16) U16 sA[2 * 2048];
  __shared__ __align__(16) U16 sB[2 * 2048];
  int bid = blockIdx.x;
  if (bid < 768) {
    gemm_core<5, false>(sA, sB, xn, qg_wT, qg_b, nullptr, g1, qkvb, 3072, 768,
                        bid % 48, bid / 48);
  } else {
    rb_body(bid - 768, dist, rb1wT, rb_b1, rb2wL, rb_b2, biasB);
  }
}

// ---------------- attention body (in-LDS K transpose; verified R8) ----------------
__device__ void attn_body(unsigned char* smem, int bid,
                          const float* __restrict__ qkv,
                          const float* __restrict__ biasB,
                          const int* __restrict__ mask,
                          float* __restrict__ ctx) {
  U16* sK = (U16*)smem;                          // 64*258*2 = 33024 B
  float(*sQ)[66] = (float(*)[66])(smem + 33024); // 16*66*4 = 4224 B
  float* sP = (float*)(smem + 33024 + 4224);     // 4*4*256*4 = 16384 B
  int tid = threadIdx.x, lane = tid & 63, w = tid >> 6;
  int bh = bid >> 4, b = bh / 12, h = bh % 12;
  int i0 = (bid & 15) * 16;
  {
    int r = tid >> 4, c = (tid & 15) * 4;
    *(float4*)&sQ[r][c] =
        *(const float4*)&qkv[((size_t)(b * 256 + i0 + r)) * 2304 + h * 64 + c];
  }
  {
    const float* kr = qkv + ((size_t)(b * 256 + w * 64)) * 2304 + 768 + h * 64 + lane;
#pragma unroll 8
    for (int rr = 0; rr < 64; ++rr) {
      float kv = kr[(size_t)rr * 2304];
      sK[lane * 258 + w * 64 + rr] = (U16)cvt_pk_bf16(kv, kv);
    }
  }
  __syncthreads();
  int iw = i0 + w * 4;
  float lacc[4][4] = {};
#pragma unroll 4
  for (int d = 0; d < 64; ++d) {
    float k0 = b2f(sK[d * 258 + lane]);
    float k1 = b2f(sK[d * 258 + 64 + lane]);
    float k2 = b2f(sK[d * 258 + 128 + lane]);
    float k3 = b2f(sK[d * 258 + 192 + lane]);
#pragma unroll
    for (int qi = 0; qi < 4; ++qi) {
      float qv = sQ[w * 4 + qi][d];
      lacc[qi][0] += qv * k0;
      lacc[qi][1] += qv * k1;
      lacc[qi][2] += qv * k2;
      lacc[qi][3] += qv * k3;
    }
  }
#pragma unroll
  for (int qi = 0; qi < 4; ++qi) {
    int gi = iw + qi;
    const float* brow = biasB + (((size_t)b * 12 + h) * 256 + gi) * 256;
    const int* mrow = mask + ((size_t)b * 256 + gi) * 256;
    float lg[4];
#pragma unroll
    for (int jc = 0; jc < 4; ++jc) {
      float lv = lacc[qi][jc] * 0.125f + brow[jc * 64 + lane];
      lg[jc] = mrow[jc * 64 + lane] ? lv : -1e30f;
    }
    float mx = fmaxf(fmaxf(lg[0], lg[1]), fmaxf(lg[2], lg[3]));
#pragma unroll
    for (int m = 32; m > 0; m >>= 1) mx = fmaxf(mx, __shfl_xor(mx, m));
    float e[4], sum = 0.f;
#pragma unroll
    for (int jc = 0; jc < 4; ++jc) { e[jc] = __expf(lg[jc] - mx); sum += e[jc]; }
#pragma unroll
    for (int m = 32; m > 0; m >>= 1) sum += __shfl_xor(sum, m);
    float inv = __builtin_amdgcn_rcpf(sum);
#pragma unroll
    for (int jc = 0; jc < 4; ++jc) sP[(w * 4 + qi) * 256 + jc * 64 + lane] = e[jc] * inv;
  }
  float ca[4] = {0.f, 0.f, 0.f, 0.f};
  const float* vcol = qkv + (size_t)b * 256 * 2304 + 1536 + h * 64 + lane;
#pragma unroll 2
  for (int j4 = 0; j4 < 256; j4 += 4) {
    float4 p0 = *(const float4*)&sP[(w * 4 + 0) * 256 + j4];
    float4 p1 = *(const float4*)&sP[(w * 4 + 1) * 256 + j4];
    float4 p2 = *(const float4*)&sP[(w * 4 + 2) * 256 + j4];
    float4 p3 = *(const float4*)&sP[(w * 4 + 3) * 256 + j4];
    const float* pp0 = (const float*)&p0;
    const float* pp1 = (const float*)&p1;
    const float* pp2 = (const float*)&p2;
    const float* pp3 = (const float*)&p3;
#pragma unroll
    for (int jj = 0; jj < 4; ++jj) {
      float v = vcol[(size_t)(j4 + jj) * 2304];
      ca[0] += pp0[jj] * v;
      ca[1] += pp1[jj] * v;
      ca[2] += pp2[jj] * v;
      ca[3] += pp3[jj] * v;
    }
  }
#pragma unroll
  for (int qi = 0; qi < 4; ++qi)
    ctx[((size_t)(b * 256 + iw + qi)) * 768 + h * 64 + lane] = ca[qi];
}

// ---------------- merged: attention (0..767) + gate2' sigmoid GEMM (768..959) ----------------
__global__ __launch_bounds__(256) void attn_gate_kernel(
    const float* __restrict__ qkv, const float* __restrict__ biasB,
    const int* __restrict__ mask, float* __restrict__ ctx,
    const U16* __restrict__ g1, const U16* __restrict__ g2wT,
    const float* __restrict__ gate_b2, U16* __restrict__ sg) {
  __shared__ __align__(16) unsigned char smem[53632];
  int bid = blockIdx.x;
  if (bid < 768) {
    attn_body(smem, bid, qkv, biasB, mask, ctx);
  } else {
    int g = bid - 768;
    gemm_core<6, false>((U16*)smem, (U16*)(smem + 8192), g1, g2wT, gate_b2, nullptr,
                        sg, nullptr, 768, 768, g % 12, g / 12);
  }
}

// ---------------- out-projection with on-the-fly A = ctx .* sg ----------------
// x2 = (ctx .* sg) @ out_w + out_b + x ; 64x64 tile, single-buffer 2-barrier.
__global__ __launch_bounds__(256) void outp_kernel(const float* __restrict__ ctx,
                                                   const U16* __restrict__ sg,
                                                   const U16* __restrict__ out_wT,
                                                   const float* __restrict__ out_b,
                                                   const float* __restrict__ x,
                                                   float* __restrict__ x2) {
  __shared__ __align__(16) U16 sA[64 * 32];
  __shared__ __align__(16) U16 sB[2 * 2048];
  int tid = threadIdx.x;
  int lane = tid & 63, wave = tid >> 6;
  int m0 = blockIdx.y * 64, n0 = blockIdx.x * 64;
  int wm = (wave >> 1) * 32, wn = (wave & 1) * 32;
  int lm = lane & 15, lq = lane >> 4;
  int srow = tid >> 2, scol = (tid & 3) * 8;
  const float* cg0 = ctx + (size_t)(m0 + srow) * 768 + scol;
  const U16* sg0 = sg + (size_t)(m0 + srow) * 768 + scol;
  const U16* bg = out_wT + (size_t)(n0 + srow) * 768 + scol;
  load_lds16(bg, sB + tid * 8);
  float4 ca0 = *(const float4*)cg0;
  float4 ca1 = *(const float4*)(cg0 + 4);
  Frag sa; sa.u4 = *(const uint4*)sg0;
  f32x4_t acc[2][2] = {};
  for (int i = 0; i < 24; ++i) {
    __syncthreads();  // prev LDS reads done
    int cb = (i & 1) * 2048, nb = ((i + 1) & 1) * 2048;
    if (i + 1 < 24) load_lds16(bg + (i + 1) * 32, sB + nb + tid * 8);
    Frag av;
    av.u[0] = cvt_pk_bf16(ca0.x * b2f(sa.s[0]), ca0.y * b2f(sa.s[1]));
    av.u[1] = cvt_pk_bf16(ca0.z * b2f(sa.s[2]), ca0.w * b2f(sa.s[3]));
    av.u[2] = cvt_pk_bf16(ca1.x * b2f(sa.s[4]), ca1.y * b2f(sa.s[5]));
    av.u[3] = cvt_pk_bf16(ca1.z * b2f(sa.s[6]), ca1.w * b2f(sa.s[7]));
    *(uint4*)&sA[tid * 8] = av.u4;
    if (i + 1 < 24) {  // prefetch next A inputs
      ca0 = *(const float4*)(cg0 + (i + 1) * 32);
      ca1 = *(const float4*)(cg0 + (i + 1) * 32 + 4);
      sa.u4 = *(const uint4*)(sg0 + (i + 1) * 32);
    }
    __syncthreads();  // drains vmcnt (B) + lgkm (A writes)
    Frag af[2], bf[2];
#pragma unroll
    for (int mt = 0; mt < 2; ++mt)
      af[mt].u4 = *(const uint4*)&sA[(wm + mt * 16 + lm) * 32 + lq * 8];
#pragma unroll
    for (int nt = 0; nt < 2; ++nt)
      bf[nt].u4 = *(const uint4*)&sB[cb + (wn + nt * 16 + lm) * 32 + lq * 8];
#pragma unroll
    for (int mt = 0; mt < 2; ++mt)
#pragma unroll
      for (int nt = 0; nt < 2; ++nt)
        acc[mt][nt] = __builtin_amdgcn_mfma_f32_16x16x32_bf16(af[mt].b8, bf[nt].b8,
                                                              acc[mt][nt], 0, 0, 0);
  }
#pragma unroll
  for (int nt = 0; nt < 2; ++nt) {
    int gc = n0 + wn + nt * 16 + lm;
    float bz = out_b[gc];
#pragma unroll
    for (int mt = 0; mt < 2; ++mt) {
#pragma unroll
      for (int r = 0; r < 4; ++r) {
        int gr = m0 + wm + mt * 16 + lq * 4 + r;
        size_t idx = (size_t)gr * 768 + gc;
        x2[idx] = acc[mt][nt][r] + bz + x[idx];
      }
    }
  }
}

// ---------------- standalone LN (LN2) ----------------
__global__ __launch_bounds__(256) void ln_kernel(const float* __restrict__ X,
                                                 const float* __restrict__ gam,
                                                 const float* __restrict__ bet,
                                                 U16* __restrict__ Y) {
  ln_row(blockIdx.x, X, gam, bet, Y);
}

// ---------------- launcher ----------------
extern "C" void kernel_launch(void* const* d_in, const int* in_sizes, int n_in,
                              void* d_out, int out_size, void* d_ws, size_t ws_size,
                              hipStream_t stream) {
  const float* x       = (const float*)d_in[0];
  const float* dist    = (const float*)d_in[1];
  const int* mask      = (const int*)d_in[2];
  const float* qkv_w   = (const float*)d_in[3];
  const float* qkv_b   = (const float*)d_in[4];
  const float* out_w   = (const float*)d_in[5];
  const float* out_b   = (const float*)d_in[6];
  const float* rb_w1   = (const float*)d_in[7];
  const float* rb_b1   = (const float*)d_in[8];
  const float* rb_w2   = (const float*)d_in[9];
  const float* rb_b2   = (const float*)d_in[10];
  const float* gate_w1 = (const float*)d_in[11];
  const float* gate_b1 = (const float*)d_in[12];
  const float* gate_w2 = (const float*)d_in[13];
  const float* gate_b2 = (const float*)d_in[14];
  const float* ff_w1   = (const float*)d_in[15];
  const float* ff_b1   = (const float*)d_in[16];
  const float* ff_w2   = (const float*)d_in[17];
  const float* ff_b2   = (const float*)d_in[18];
  const float* ln1_g   = (const float*)d_in[19];
  const float* ln1_b   = (const float*)d_in[20];
  const float* ln2_g   = (const float*)d_in[21];
  const float* ln2_b   = (const float*)d_in[22];

  char* w = (char*)d_ws;
  auto alloc = [&](size_t bytes) {
    char* p = w;
    w += (bytes + 255) & ~(size_t)255;
    return p;
  };
  U16* xn      = (U16*)alloc(1024 * 768 * 2);
  float* qkvb  = (float*)alloc((size_t)1024 * 2304 * 4);
  U16* qg_wT   = (U16*)alloc((size_t)3072 * 768 * 2);
  U16* qkv_wT  = qg_wT;
  U16* g1wT    = qg_wT + (size_t)2304 * 768;
  float* qg_b  = (float*)alloc(3072 * 4);
  U16* out_wT  = (U16*)alloc(768 * 768 * 2);
  U16* g2wT    = (U16*)alloc(768 * 768 * 2);
  U16* ff1wT   = (U16*)alloc(1536 * 768 * 2);
  U16* ff2wT   = (U16*)alloc(768 * 1536 * 2);
  U16* rb1wT   = (U16*)alloc(768 * 64 * 2);
  U16* rb2wL   = (U16*)alloc(24 * 64 * 8 * 2);
  float* biasB = (float*)alloc((size_t)4 * 12 * 256 * 256 * 4);
  float* ctx   = (float*)alloc(1024 * 768 * 4);
  U16* g1      = (U16*)alloc(1024 * 768 * 2);
  U16* sg      = (U16*)alloc(1024 * 768 * 2);
  float* x2    = (float*)alloc(1024 * 768 * 4);
  U16* y       = (U16*)alloc(1024 * 768 * 2);
  U16* f1      = (U16*)alloc(1024 * 1536 * 2);
  (void)ws_size; (void)in_sizes; (void)n_in; (void)out_size;

  // 1: weight prep + LN1
  prep_kernel<<<6892, 256, 0, stream>>>(qkv_w, out_w, gate_w1, gate_w2, ff_w1, ff_w2,
                                        rb_w1, rb_w2, qkv_b, gate_b1,
                                        qkv_wT, out_wT, g1wT, g2wT, ff1wT, ff2wT,
                                        rb1wT, rb2wL, qg_b, x, ln1_g, ln1_b, xn);
  // 2: fused qkv+gate1 GEMM co-scheduled with rb bias MLP
  qkvrb_kernel<<<1792, 256, 0, stream>>>(xn, qg_wT, qg_b, qkvb, g1,
                                         dist, rb1wT, rb_b1, rb2wL, rb_b2, biasB);
  // 3: attention co-scheduled with gate2' (sg = sigmoid(g1@g2w+b))
  attn_gate_kernel<<<960, 256, 0, stream>>>(qkvb, biasB, mask, ctx,
                                            g1, g2wT, gate_b2, sg);
  // 4: out projection with on-the-fly gating + residual
  outp_kernel<<<dim3(12, 16), 256, 0, stream>>>(ctx, sg, out_wT, out_b, x, x2);
  // 5: LN2
  ln_kernel<<<1024, 256, 0, stream>>>(x2, ln2_g, ln2_b, y);
  // 6: FF1 (gelu)
  gemm_bt<2, false><<<dim3(24, 16), 256, 0, stream>>>(y, ff1wT, ff_b1, nullptr, f1,
                                                      1536, 768);
  // 7: FF2 + residual -> out
  gemm_bt<4, true><<<dim3(12, 16), 256, 0, stream>>>(f1, ff2wT, ff_b2, x2, (float*)d_out,
                                                     768, 1536);
}

// Round 10
// 318.205 us; speedup vs baseline: 1.9305x; 1.0251x over previous
//
#include <hip/hip_runtime.h>
#include <hip/hip_bf16.h>
#include <cmath>

#define U16 unsigned short

typedef __bf16 bf16x8_t __attribute__((ext_vector_type(8)));
typedef float f32x4_t __attribute__((ext_vector_type(4)));

union Frag { uint4 u4; unsigned u[4]; bf16x8_t b8; U16 s[8]; };

__device__ __forceinline__ float b2f(U16 u) {
  union { unsigned int i; float f; } x; x.i = ((unsigned int)u) << 16; return x.f;
}
__device__ __forceinline__ U16 f2b(float f) {
  union { float f; unsigned int i; } x; x.f = f;
  unsigned int r = x.i + 0x7FFFu + ((x.i >> 16) & 1u);
  return (U16)(r >> 16);
}
__device__ __forceinline__ unsigned cvt_pk_bf16(float a, float b) {
  union { __hip_bfloat162 h2; unsigned u; } x;
  x.h2 = __float22bfloat162_rn(make_float2(a, b));
  return x.u;
}
__device__ __forceinline__ float fast_silu(float z) {
  return z * __builtin_amdgcn_rcpf(1.f + __expf(-z));
}
__device__ __forceinline__ void load_lds16(const U16* g, U16* l) {
  __builtin_amdgcn_global_load_lds((const __attribute__((address_space(1))) void*)g,
                                   (__attribute__((address_space(3))) void*)l, 16, 0, 0);
}

// ---------------- layernorm row (shfl reduce, one barrier) ----------------
__device__ __forceinline__ void ln_row(int row, const float* __restrict__ X,
                                       const float* __restrict__ gam,
                                       const float* __restrict__ bet,
                                       U16* __restrict__ Y) {
  int tid = threadIdx.x, lane = tid & 63, wave = tid >> 6;
  __shared__ float p1[4], p2[4];
  float v[3];
#pragma unroll
  for (int j = 0; j < 3; ++j) v[j] = X[(size_t)row * 768 + tid + j * 256];
  float s1 = v[0] + v[1] + v[2];
  float s2 = v[0] * v[0] + v[1] * v[1] + v[2] * v[2];
#pragma unroll
  for (int m = 32; m > 0; m >>= 1) {
    s1 += __shfl_xor(s1, m);
    s2 += __shfl_xor(s2, m);
  }
  if (lane == 0) { p1[wave] = s1; p2[wave] = s2; }
  __syncthreads();
  float t1 = p1[0] + p1[1] + p1[2] + p1[3];
  float t2 = p2[0] + p2[1] + p2[2] + p2[3];
  float mean = t1 * (1.f / 768.f);
  float var = t2 * (1.f / 768.f) - mean * mean;
  float rstd = rsqrtf(var + 1e-5f);
#pragma unroll
  for (int j = 0; j < 3; ++j) {
    int c = tid + j * 256;
    Y[(size_t)row * 768 + c] = f2b((v[j] - mean) * rstd * gam[c] + bet[c]);
  }
}

// ---------------- merged weight-prep + LN1 kernel ----------------
__global__ __launch_bounds__(256) void prep_kernel(
    const float* __restrict__ qkv_w, const float* __restrict__ out_w,
    const float* __restrict__ g1w, const float* __restrict__ g2w,
    const float* __restrict__ ff1w, const float* __restrict__ ff2w,
    const float* __restrict__ rb1w, const float* __restrict__ rb2w,
    const float* __restrict__ qkv_b, const float* __restrict__ gate_b1,
    U16* __restrict__ qkv_wT, U16* __restrict__ out_wT, U16* __restrict__ g1wT,
    U16* __restrict__ g2wT, U16* __restrict__ ff1wT, U16* __restrict__ ff2wT,
    U16* __restrict__ rb1wT, U16* __restrict__ rb2wL, float* __restrict__ qg_bias,
    const float* __restrict__ x, const float* __restrict__ ln1_g,
    const float* __restrict__ ln1_b, U16* __restrict__ xn) {
  int bid = blockIdx.x;
  if (bid >= 5868) {  // LN1
    ln_row(bid - 5868, x, ln1_g, ln1_b, xn);
    return;
  }
  if (bid >= 5856) {  // qkv_b ++ gate_b1
    int idx = (bid - 5856) * 256 + threadIdx.x;
    qg_bias[idx] = (idx < 2304) ? qkv_b[idx] : gate_b1[idx - 2304];
    return;
  }
  if (bid >= 5808) {  // rb_w2 chunk
    int idx = (bid - 5808) * 256 + threadIdx.x;
    int j = idx & 7, lane = (idx >> 3) & 63, pp = idx >> 9;
    int row = lane & 15, col = pp * 32 + ((lane >> 4) << 3) + j;
    rb2wL[idx] = (row < 12) ? f2b(rb2w[col * 12 + row]) : (U16)0;
    return;
  }
  const float* in; U16* out; int R, C, base;
  if (bid < 1728)      { in = qkv_w; out = qkv_wT; R = 768;  C = 2304; base = 0; }
  else if (bid < 2304) { in = out_w; out = out_wT; R = 768;  C = 768;  base = 1728; }
  else if (bid < 2880) { in = g1w;   out = g1wT;   R = 768;  C = 768;  base = 2304; }
  else if (bid < 3456) { in = g2w;   out = g2wT;   R = 768;  C = 768;  base = 2880; }
  else if (bid < 4608) { in = ff1w;  out = ff1wT;  R = 768;  C = 1536; base = 3456; }
  else if (bid < 5760) { in = ff2w;  out = ff2wT;  R = 1536; C = 768;  base = 4608; }
  else                 { in = rb1w;  out = rb1wT;  R = 64;   C = 768;  base = 5760; }
  int bx = bid - base, tilesx = C / 32;
  int c0 = (bx % tilesx) * 32, r0 = (bx / tilesx) * 32;
  __shared__ float tile[32][33];
  int tx = threadIdx.x & 31, ty = threadIdx.x >> 5;
#pragma unroll
  for (int yy = 0; yy < 4; ++yy)
    tile[ty + yy * 8][tx] = in[(size_t)(r0 + ty + yy * 8) * C + c0 + tx];
  __syncthreads();
#pragma unroll
  for (int yy = 0; yy < 4; ++yy)
    out[(size_t)(c0 + ty + yy * 8) * R + r0 + tx] = f2b(tile[tx][ty + yy * 8]);
}

// ---------------- double-buffered bf16-MFMA GEMM core ----------------
// EPI: 0=none 2=gelu 4=z+other(fp32 out) 5=fused qkv/gate1 6=sigmoid->bf16
template <int EPI, bool OUTF32>
__device__ __forceinline__ void gemm_core(U16* sA, U16* sB,  // each [2*2048]
                                          const U16* __restrict__ A,
                                          const U16* __restrict__ BT,
                                          const float* __restrict__ bias,
                                          const float* __restrict__ other,
                                          void* __restrict__ Cout,
                                          float* __restrict__ Cout2,
                                          int N, int K, int bx, int by) {
  int tid = threadIdx.x;
  int lane = tid & 63, wave = tid >> 6;
  int m0 = by * 64, n0 = bx * 64;
  int wm = (wave >> 1) * 32, wn = (wave & 1) * 32;
  int lm = lane & 15, lq = lane >> 4;
  int srow = tid >> 2, scol = (tid & 3) * 8;
  const U16* ag = A + (size_t)(m0 + srow) * K + scol;
  const U16* bg = BT + (size_t)(n0 + srow) * K + scol;
  int nit = K >> 5;
  load_lds16(ag, sA + tid * 8);
  load_lds16(bg, sB + tid * 8);
  f32x4_t acc[2][2] = {};
  for (int i = 0; i < nit; ++i) {
    __syncthreads();
    int cb = (i & 1) * 2048, nb = ((i + 1) & 1) * 2048;
    if (i + 1 < nit) {
      load_lds16(ag + (i + 1) * 32, sA + nb + tid * 8);
      load_lds16(bg + (i + 1) * 32, sB + nb + tid * 8);
    }
    Frag af[2], bf[2];
#pragma unroll
    for (int mt = 0; mt < 2; ++mt)
      af[mt].u4 = *(const uint4*)&sA[cb + (wm + mt * 16 + lm) * 32 + lq * 8];
#pragma unroll
    for (int nt = 0; nt < 2; ++nt)
      bf[nt].u4 = *(const uint4*)&sB[cb + (wn + nt * 16 + lm) * 32 + lq * 8];
#pragma unroll
    for (int mt = 0; mt < 2; ++mt)
#pragma unroll
      for (int nt = 0; nt < 2; ++nt)
        acc[mt][nt] = __builtin_amdgcn_mfma_f32_16x16x32_bf16(af[mt].b8, bf[nt].b8,
                                                              acc[mt][nt], 0, 0, 0);
  }
#pragma unroll
  for (int nt = 0; nt < 2; ++nt) {
    int gc = n0 + wn + nt * 16 + lm;
    float bz = bias[gc];
#pragma unroll
    for (int mt = 0; mt < 2; ++mt) {
#pragma unroll
      for (int r = 0; r < 4; ++r) {
        int gr = m0 + wm + mt * 16 + lq * 4 + r;
        float z = acc[mt][nt][r] + bz;
        if (EPI == 5) {
          if (gc < 2304) Cout2[(size_t)gr * 2304 + gc] = z;
          else ((U16*)Cout)[(size_t)gr * 768 + gc - 2304] = f2b(fast_silu(z));
          continue;
        }
        size_t idx = (size_t)gr * N + gc;
        float o;
        if (EPI == 0) o = z;
        else if (EPI == 2) o = 0.5f * z * (1.f + erff(z * 0.70710678118f));
        else if (EPI == 6) o = __builtin_amdgcn_rcpf(1.f + __expf(-z));
        else o = z + other[idx];
        if (OUTF32) ((float*)Cout)[idx] = o;
        else ((U16*)Cout)[idx] = f2b(o);
      }
    }
  }
}

template <int EPI, bool OUTF32>
__global__ __launch_bounds__(256) void gemm_bt(const U16* __restrict__ A,
                                               const U16* __restrict__ BT,
                                               const float* __restrict__ bias,
                                               const float* __restrict__ other,
                                               void* __restrict__ Cout,
                                               int N, int K) {
  __shared__ __align__(16) U16 sA[2 * 2048];
  __shared__ __align__(16) U16 sB[2 * 2048];
  gemm_core<EPI, OUTF32>(sA, sB, A, BT, bias, other, Cout, nullptr, N, K,
                         blockIdx.x, blockIdx.y);
}

// ---------------- relative-bias MLP body v8: 512 rows/block (8 groups/wave) ----------------
// Halves per-silu L1 weight-fragment traffic vs 256-row (R5-R9 plateau was L1-BW-bound).
// Layer-1 transposed (A=w1 permuted rows, B=dist); silu lands in layer-2 A-frag layout
// (mapping verified R3-R9). Weights prefetched even/odd.
__device__ void rb_body(int bid, const float* __restrict__ dist,
                        const U16* __restrict__ w1T, const float* __restrict__ b1,
                        const U16* __restrict__ w2L, const float* __restrict__ b2,
                        float* __restrict__ biasOut) {
  int tid = threadIdx.x;
  int lane = tid & 63, wave = tid >> 6;
  int lm = lane & 15, lq = lane >> 4;
  int r0 = bid * 512;
  float hb = (lm < 12) ? b2[lm] : 0.f;
  Frag bd[8][2];
#pragma unroll
  for (int g = 0; g < 8; ++g) {
    const float* ap = dist + (size_t)(r0 + (wave * 8 + g) * 16 + lm) * 64 + lq * 8;
    float4 v0 = ((const float4*)ap)[0];
    float4 v1 = ((const float4*)ap)[1];
    float4 v2 = ((const float4*)(ap + 32))[0];
    float4 v3 = ((const float4*)(ap + 32))[1];
    bd[g][0].u[0] = cvt_pk_bf16(v0.x, v0.y); bd[g][0].u[1] = cvt_pk_bf16(v0.z, v0.w);
    bd[g][0].u[2] = cvt_pk_bf16(v1.x, v1.y); bd[g][0].u[3] = cvt_pk_bf16(v1.z, v1.w);
    bd[g][1].u[0] = cvt_pk_bf16(v2.x, v2.y); bd[g][1].u[1] = cvt_pk_bf16(v2.z, v2.w);
    bd[g][1].u[2] = cvt_pk_bf16(v3.x, v3.y); bd[g][1].u[3] = cvt_pk_bf16(v3.z, v3.w);
  }
  const U16* w1p0 = w1T + (size_t)(((lm >> 2) << 3) + (lm & 3)) * 64 + lq * 8;
  const U16* w1p1 = w1p0 + 256;
  const U16* w2p = w2L + lane * 8;
  const float* b1p = b1 + lq * 8;
  f32x4_t bacc[8];
#pragma unroll
  for (int g = 0; g < 8; ++g) bacc[g] = {hb, hb, hb, hb};

  auto loadw = [&](int j, Frag& f00, Frag& f01, Frag& f10, Frag& f11, Frag& fwb,
                   float4& fb0, float4& fb1) {
    const U16* p0 = w1p0 + (size_t)j * 2048;
    const U16* p1 = w1p1 + (size_t)j * 2048;
    f00.u4 = *(const uint4*)p0;
    f01.u4 = *(const uint4*)(p0 + 32);
    f10.u4 = *(const uint4*)p1;
    f11.u4 = *(const uint4*)(p1 + 32);
    fwb.u4 = *(const uint4*)(w2p + (size_t)j * 512);
    fb0 = *(const float4*)(b1p + j * 32);
    fb1 = *(const float4*)(b1p + j * 32 + 4);
  };
  auto comp = [&](Frag& f00, Frag& f01, Frag& f10, Frag& f11, Frag& fwb,
                  float4 fb0, float4 fb1) {
    f32x4_t cz0 = {fb0.x, fb0.y, fb0.z, fb0.w};
    f32x4_t cz1 = {fb1.x, fb1.y, fb1.z, fb1.w};
#pragma unroll
    for (int g = 0; g < 8; ++g) {
      f32x4_t z0 = cz0, z1 = cz1;
      z0 = __builtin_amdgcn_mfma_f32_16x16x32_bf16(f00.b8, bd[g][0].b8, z0, 0, 0, 0);
      z0 = __builtin_amdgcn_mfma_f32_16x16x32_bf16(f01.b8, bd[g][1].b8, z0, 0, 0, 0);
      z1 = __builtin_amdgcn_mfma_f32_16x16x32_bf16(f10.b8, bd[g][0].b8, z1, 0, 0, 0);
      z1 = __builtin_amdgcn_mfma_f32_16x16x32_bf16(f11.b8, bd[g][1].b8, z1, 0, 0, 0);
      float s0 = fast_silu(z0[0]), s1 = fast_silu(z0[1]);
      float s2 = fast_silu(z0[2]), s3 = fast_silu(z0[3]);
      float t0 = fast_silu(z1[0]), t1 = fast_silu(z1[1]);
      float t2 = fast_silu(z1[2]), t3 = fast_silu(z1[3]);
      Frag af2;
      af2.u[0] = cvt_pk_bf16(s0, s1); af2.u[1] = cvt_pk_bf16(s2, s3);
      af2.u[2] = cvt_pk_bf16(t0, t1); af2.u[3] = cvt_pk_bf16(t2, t3);
      bacc[g] = __builtin_amdgcn_mfma_f32_16x16x32_bf16(af2.b8, fwb.b8, bacc[g], 0, 0, 0);
    }
  };

  Frag e00, e01, e10, e11, ewb, o00, o01, o10, o11, owb;
  float4 eb0, eb1, ob0, ob1;
  loadw(0, e00, e01, e10, e11, ewb, eb0, eb1);
  for (int pp = 0; pp < 24; pp += 2) {
    loadw(pp + 1, o00, o01, o10, o11, owb, ob0, ob1);
    comp(e00, e01, e10, e11, ewb, eb0, eb1);
    if (pp + 2 < 24) loadw(pp + 2, e00, e01, e10, e11, ewb, eb0, eb1);
    comp(o00, o01, o10, o11, owb, ob0, ob1);
  }
  if (lm < 12) {
#pragma unroll
    for (int g = 0; g < 8; ++g) {
#pragma unroll
      for (int r = 0; r < 4; ++r) {
        int gr = r0 + (wave * 8 + g) * 16 + lq * 4 + r;
        int b = gr >> 16, rem = gr & 65535, i = rem >> 8, j = rem & 255;
        biasOut[(((size_t)b * 12 + lm) * 256 + i) * 256 + j] = bacc[g][r];
      }
    }
  }
}

// ---------------- merged launch: rb (0..511, long pole first) + qkv/gate1 GEMM (512..1279) ----
__global__ __launch_bounds__(256) void qkvrb_kernel(
    const U16* __restrict__ xn, const U16* __restrict__ qg_wT,
    const float* __restrict__ qg_b, float* __restrict__ qkvb, U16* __restrict__ g1,
    const float* __restrict__ dist, const U16* __restrict__ rb1wT,
    const float* __restrict__ rb_b1, const U16* __restrict__ rb2wL,
    const float* __restrict__ rb_b2, float* __restrict__ biasB) {
  __shared__ __align__(16) U16 sA[2 * 2048];
  __shared__ __align__(16) U16 sB[2 * 2048];
  int bid = blockIdx.x;
  if (bid < 512) {
    rb_body(bid, dist, rb1wT, rb_b1, rb2wL, rb_b2, biasB);
  } else {
    int g = bid - 512;
    gemm_core<5, false>(sA, sB, xn, qg_wT, qg_b, nullptr, g1, qkvb, 3072, 768,
                        g % 48, g / 48);
  }
}

// ---------------- attention body (in-LDS K transpose; verified R8/R9) ----------------
__device__ void attn_body(unsigned char* smem, int bid,
                          const float* __restrict__ qkv,
                          const float* __restrict__ biasB,
                          const int* __restrict__ mask,
                          float* __restrict__ ctx) {
  U16* sK = (U16*)smem;                          // 64*258*2 = 33024 B
  float(*sQ)[66] = (float(*)[66])(smem + 33024); // 16*66*4 = 4224 B
  float* sP = (float*)(smem + 33024 + 4224);     // 4*4*256*4 = 16384 B
  int tid = threadIdx.x, lane = tid & 63, w = tid >> 6;
  int bh = bid >> 4, b = bh / 12, h = bh % 12;
  int i0 = (bid & 15) * 16;
  {
    int r = tid >> 4, c = (tid & 15) * 4;
    *(float4*)&sQ[r][c] =
        *(const float4*)&qkv[((size_t)(b * 256 + i0 + r)) * 2304 + h * 64 + c];
  }
  {
    const float* kr = qkv + ((size_t)(b * 256 + w * 64)) * 2304 + 768 + h * 64 + lane;
#pragma unroll 8
    for (int rr = 0; rr < 64; ++rr) {
      float kv = kr[(size_t)rr * 2304];
      sK[lane * 258 + w * 64 + rr] = (U16)cvt_pk_bf16(kv, kv);
    }
  }
  __syncthreads();
  int iw = i0 + w * 4;
  float lacc[4][4] = {};
#pragma unroll 4
  for (int d = 0; d < 64; ++d) {
    float k0 = b2f(sK[d * 258 + lane]);
    float k1 = b2f(sK[d * 258 + 64 + lane]);
    float k2 = b2f(sK[d * 258 + 128 + lane]);
    float k3 = b2f(sK[d * 258 + 192 + lane]);
#pragma unroll
    for (int qi = 0; qi < 4; ++qi) {
      float qv = sQ[w * 4 + qi][d];
      lacc[qi][0] += qv * k0;
      lacc[qi][1] += qv * k1;
      lacc[qi][2] += qv * k2;
      lacc[qi][3] += qv * k3;
    }
  }
#pragma unroll
  for (int qi = 0; qi < 4; ++qi) {
    int gi = iw + qi;
    const float* brow = biasB + (((size_t)b * 12 + h) * 256 + gi) * 256;
    const int* mrow = mask + ((size_t)b * 256 + gi) * 256;
    float lg[4];
#pragma unroll
    for (int jc = 0; jc < 4; ++jc) {
      float lv = lacc[qi][jc] * 0.125f + brow[jc * 64 + lane];
      lg[jc] = mrow[jc * 64 + lane] ? lv : -1e30f;
    }
    float mx = fmaxf(fmaxf(lg[0], lg[1]), fmaxf(lg[2], lg[3]));
#pragma unroll
    for (int m = 32; m > 0; m >>= 1) mx = fmaxf(mx, __shfl_xor(mx, m));
    float e[4], sum = 0.f;
#pragma unroll
    for (int jc = 0; jc < 4; ++jc) { e[jc] = __expf(lg[jc] - mx); sum += e[jc]; }
#pragma unroll
    for (int m = 32; m > 0; m >>= 1) sum += __shfl_xor(sum, m);
    float inv = __builtin_amdgcn_rcpf(sum);
#pragma unroll
    for (int jc = 0; jc < 4; ++jc) sP[(w * 4 + qi) * 256 + jc * 64 + lane] = e[jc] * inv;
  }
  float ca[4] = {0.f, 0.f, 0.f, 0.f};
  const float* vcol = qkv + (size_t)b * 256 * 2304 + 1536 + h * 64 + lane;
#pragma unroll 2
  for (int j4 = 0; j4 < 256; j4 += 4) {
    float4 p0 = *(const float4*)&sP[(w * 4 + 0) * 256 + j4];
    float4 p1 = *(const float4*)&sP[(w * 4 + 1) * 256 + j4];
    float4 p2 = *(const float4*)&sP[(w * 4 + 2) * 256 + j4];
    float4 p3 = *(const float4*)&sP[(w * 4 + 3) * 256 + j4];
    const float* pp0 = (const float*)&p0;
    const float* pp1 = (const float*)&p1;
    const float* pp2 = (const float*)&p2;
    const float* pp3 = (const float*)&p3;
#pragma unroll
    for (int jj = 0; jj < 4; ++jj) {
      float v = vcol[(size_t)(j4 + jj) * 2304];
      ca[0] += pp0[jj] * v;
      ca[1] += pp1[jj] * v;
      ca[2] += pp2[jj] * v;
      ca[3] += pp3[jj] * v;
    }
  }
#pragma unroll
  for (int qi = 0; qi < 4; ++qi)
    ctx[((size_t)(b * 256 + iw + qi)) * 768 + h * 64 + lane] = ca[qi];
}

// ---------------- merged: attention (0..767) + gate2' sigmoid GEMM (768..959) ----------------
__global__ __launch_bounds__(256) void attn_gate_kernel(
    const float* __restrict__ qkv, const float* __restrict__ biasB,
    const int* __restrict__ mask, float* __restrict__ ctx,
    const U16* __restrict__ g1, const U16* __restrict__ g2wT,
    const float* __restrict__ gate_b2, U16* __restrict__ sg) {
  __shared__ __align__(16) unsigned char smem[53632];
  int bid = blockIdx.x;
  if (bid < 768) {
    attn_body(smem, bid, qkv, biasB, mask, ctx);
  } else {
    int g = bid - 768;
    gemm_core<6, false>((U16*)smem, (U16*)(smem + 8192), g1, g2wT, gate_b2, nullptr,
                        sg, nullptr, 768, 768, g % 12, g / 12);
  }
}

// ---------------- out-projection with on-the-fly A = ctx .* sg ----------------
__global__ __launch_bounds__(256) void outp_kernel(const float* __restrict__ ctx,
                                                   const U16* __restrict__ sg,
                                                   const U16* __restrict__ out_wT,
                                                   const float* __restrict__ out_b,
                                                   const float* __restrict__ x,
                                                   float* __restrict__ x2) {
  __shared__ __align__(16) U16 sA[64 * 32];
  __shared__ __align__(16) U16 sB[2 * 2048];
  int tid = threadIdx.x;
  int lane = tid & 63, wave = tid >> 6;
  int m0 = blockIdx.y * 64, n0 = blockIdx.x * 64;
  int wm = (wave >> 1) * 32, wn = (wave & 1) * 32;
  int lm = lane & 15, lq = lane >> 4;
  int srow = tid >> 2, scol = (tid & 3) * 8;
  const float* cg0 = ctx + (size_t)(m0 + srow) * 768 + scol;
  const U16* sg0 = sg + (size_t)(m0 + srow) * 768 + scol;
  const U16* bg = out_wT + (size_t)(n0 + srow) * 768 + scol;
  load_lds16(bg, sB + tid * 8);
  float4 ca0 = *(const float4*)cg0;
  float4 ca1 = *(const float4*)(cg0 + 4);
  Frag sa; sa.u4 = *(const uint4*)sg0;
  f32x4_t acc[2][2] = {};
  for (int i = 0; i < 24; ++i) {
    __syncthreads();
    int cb = (i & 1) * 2048, nb = ((i + 1) & 1) * 2048;
    if (i + 1 < 24) load_lds16(bg + (i + 1) * 32, sB + nb + tid * 8);
    Frag av;
    av.u[0] = cvt_pk_bf16(ca0.x * b2f(sa.s[0]), ca0.y * b2f(sa.s[1]));
    av.u[1] = cvt_pk_bf16(ca0.z * b2f(sa.s[2]), ca0.w * b2f(sa.s[3]));
    av.u[2] = cvt_pk_bf16(ca1.x * b2f(sa.s[4]), ca1.y * b2f(sa.s[5]));
    av.u[3] = cvt_pk_bf16(ca1.z * b2f(sa.s[6]), ca1.w * b2f(sa.s[7]));
    *(uint4*)&sA[tid * 8] = av.u4;
    if (i + 1 < 24) {
      ca0 = *(const float4*)(cg0 + (i + 1) * 32);
      ca1 = *(const float4*)(cg0 + (i + 1) * 32 + 4);
      sa.u4 = *(const uint4*)(sg0 + (i + 1) * 32);
    }
    __syncthreads();
    Frag af[2], bf[2];
#pragma unroll
    for (int mt = 0; mt < 2; ++mt)
      af[mt].u4 = *(const uint4*)&sA[(wm + mt * 16 + lm) * 32 + lq * 8];
#pragma unroll
    for (int nt = 0; nt < 2; ++nt)
      bf[nt].u4 = *(const uint4*)&sB[cb + (wn + nt * 16 + lm) * 32 + lq * 8];
#pragma unroll
    for (int mt = 0; mt < 2; ++mt)
#pragma unroll
      for (int nt = 0; nt < 2; ++nt)
        acc[mt][nt] = __builtin_amdgcn_mfma_f32_16x16x32_bf16(af[mt].b8, bf[nt].b8,
                                                              acc[mt][nt], 0, 0, 0);
  }
#pragma unroll
  for (int nt = 0; nt < 2; ++nt) {
    int gc = n0 + wn + nt * 16 + lm;
    float bz = out_b[gc];
#pragma unroll
    for (int mt = 0; mt < 2; ++mt) {
#pragma unroll
      for (int r = 0; r < 4; ++r) {
        int gr = m0 + wm + mt * 16 + lq * 4 + r;
        size_t idx = (size_t)gr * 768 + gc;
        x2[idx] = acc[mt][nt][r] + bz + x[idx];
      }
    }
  }
}

// ---------------- standalone LN (LN2) ----------------
__global__ __launch_bounds__(256) void ln_kernel(const float* __restrict__ X,
                                                 const float* __restrict__ gam,
                                                 const float* __restrict__ bet,
                                                 U16* __restrict__ Y) {
  ln_row(blockIdx.x, X, gam, bet, Y);
}

// ---------------- launcher ----------------
extern "C" void kernel_launch(void* const* d_in, const int* in_sizes, int n_in,
                              void* d_out, int out_size, void* d_ws, size_t ws_size,
                              hipStream_t stream) {
  const float* x       = (const float*)d_in[0];
  const float* dist    = (const float*)d_in[1];
  const int* mask      = (const int*)d_in[2];
  const float* qkv_w   = (const float*)d_in[3];
  const float* qkv_b   = (const float*)d_in[4];
  const float* out_w   = (const float*)d_in[5];
  const float* out_b   = (const float*)d_in[6];
  const float* rb_w1   = (const float*)d_in[7];
  const float* rb_b1   = (const float*)d_in[8];
  const float* rb_w2   = (const float*)d_in[9];
  const float* rb_b2   = (const float*)d_in[10];
  const float* gate_w1 = (const float*)d_in[11];
  const float* gate_b1 = (const float*)d_in[12];
  const float* gate_w2 = (const float*)d_in[13];
  const float* gate_b2 = (const float*)d_in[14];
  const float* ff_w1   = (const float*)d_in[15];
  const float* ff_b1   = (const float*)d_in[16];
  const float* ff_w2   = (const float*)d_in[17];
  const float* ff_b2   = (const float*)d_in[18];
  const float* ln1_g   = (const float*)d_in[19];
  const float* ln1_b   = (const float*)d_in[20];
  const float* ln2_g   = (const float*)d_in[21];
  const float* ln2_b   = (const float*)d_in[22];

  char* w = (char*)d_ws;
  auto alloc = [&](size_t bytes) {
    char* p = w;
    w += (bytes + 255) & ~(size_t)255;
    return p;
  };
  U16* xn      = (U16*)alloc(1024 * 768 * 2);
  float* qkvb  = (float*)alloc((size_t)1024 * 2304 * 4);
  U16* qg_wT   = (U16*)alloc((size_t)3072 * 768 * 2);
  U16* qkv_wT  = qg_wT;
  U16* g1wT    = qg_wT + (size_t)2304 * 768;
  float* qg_b  = (float*)alloc(3072 * 4);
  U16* out_wT  = (U16*)alloc(768 * 768 * 2);
  U16* g2wT    = (U16*)alloc(768 * 768 * 2);
  U16* ff1wT   = (U16*)alloc(1536 * 768 * 2);
  U16* ff2wT   = (U16*)alloc(768 * 1536 * 2);
  U16* rb1wT   = (U16*)alloc(768 * 64 * 2);
  U16* rb2wL   = (U16*)alloc(24 * 64 * 8 * 2);
  float* biasB = (float*)alloc((size_t)4 * 12 * 256 * 256 * 4);
  float* ctx   = (float*)alloc(1024 * 768 * 4);
  U16* g1      = (U16*)alloc(1024 * 768 * 2);
  U16* sg      = (U16*)alloc(1024 * 768 * 2);
  float* x2    = (float*)alloc(1024 * 768 * 4);
  U16* y       = (U16*)alloc(1024 * 768 * 2);
  U16* f1      = (U16*)alloc(1024 * 1536 * 2);
  (void)ws_size; (void)in_sizes; (void)n_in; (void)out_size;

  // 1: weight prep + LN1
  prep_kernel<<<6892, 256, 0, stream>>>(qkv_w, out_w, gate_w1, gate_w2, ff_w1, ff_w2,
                                        rb_w1, rb_w2, qkv_b, gate_b1,
                                        qkv_wT, out_wT, g1wT, g2wT, ff1wT, ff2wT,
                                        rb1wT, rb2wL, qg_b, x, ln1_g, ln1_b, xn);
  // 2: rb bias MLP (512 blocks, first) + fused qkv/gate1 GEMM (768 blocks)
  qkvrb_kernel<<<1280, 256, 0, stream>>>(xn, qg_wT, qg_b, qkvb, g1,
                                         dist, rb1wT, rb_b1, rb2wL, rb_b2, biasB);
  // 3: attention co-scheduled with gate2' (sg = sigmoid(g1@g2w+b))
  attn_gate_kernel<<<960, 256, 0, stream>>>(qkvb, biasB, mask, ctx,
                                            g1, g2wT, gate_b2, sg);
  // 4: out projection with on-the-fly gating + residual
  outp_kernel<<<dim3(12, 16), 256, 0, stream>>>(ctx, sg, out_wT, out_b, x, x2);
  // 5: LN2
  ln_kernel<<<1024, 256, 0, stream>>>(x2, ln2_g, ln2_b, y);
  // 6: FF1 (gelu)
  gemm_bt<2, false><<<dim3(24, 16), 256, 0, stream>>>(y, ff1wT, ff_b1, nullptr, f1,
                                                      1536, 768);
  // 7: FF2 + residual -> out
  gemm_bt<4, true><<<dim3(12, 16), 256, 0, stream>>>(f1, ff2wT, ff_b2, x2, (float*)d_out,
                                                     768, 1536);
}